// Round 1
// 421.367 us; speedup vs baseline: 1.3812x; 1.3812x over previous
//
#include <hip/hip_runtime.h>
#include <hip/hip_bf16.h>
#include <stdint.h>

typedef unsigned short u16;
typedef unsigned int   u32;
typedef __attribute__((ext_vector_type(8))) short bf16x8;
typedef __attribute__((ext_vector_type(4))) float f32x4;

#define NEG_GAT 0.2f
#define NEG_ACT 0.05f
#define LN_EPS  1e-5f
#define NPARAM  15

__device__ __forceinline__ float bf2f(u32 bits16){
  union { u32 u; float f; } v; v.u = bits16 << 16; return v.f;
}
__device__ __forceinline__ u16 f2bf(float f){
  union { float f; u32 u; } v; v.f = f;
  u32 u = v.u;
  u32 r = (u + 0x7fffu + ((u >> 16) & 1u)) >> 16;
  return (u16)r;
}
__device__ __forceinline__ float lrelu(float x, float s){ return x > 0.f ? x : s * x; }

__device__ __forceinline__ int geti(const int* __restrict__ p, int i, int enc){
  return p[enc ? (2 * i) : i];
}

// ---------------- dtype detection ----------------

struct CvtParams {
  const void* src[NPARAM];
  float*      dst[NPARAM];
  int         n[NPARAM];
};

__global__ void k_detect(const u32* __restrict__ ln_g_raw, const int* __restrict__ ei_raw,
                         int* __restrict__ fflag, int* __restrict__ iflag,
                         int* __restrict__ errflag)
{
  if (threadIdx.x == 0){
    *fflag = (ln_g_raw[0] == 0x3F800000u) ? 0 : 1;
    int zeros = 0;
    for (int j = 0; j < 64; j++) if (ei_raw[2 * j + 1] == 0) zeros++;
    *iflag = (zeros >= 60) ? 1 : 0;
    *errflag = 0;
  }
}

__global__ void k_convert(CvtParams P, const int* __restrict__ flag)
{
  const int pi  = blockIdx.y;
  const int idx = blockIdx.x * 256 + threadIdx.x;
  if (idx >= P.n[pi]) return;
  if (*flag == 0) P.dst[pi][idx] = ((const float*)P.src[pi])[idx];
  else            P.dst[pi][idx] = bf2f(((const u16*)P.src[pi])[idx]);
}

// ---------------- validators ----------------

__global__ void k_check_sorted(const int* __restrict__ batch, const int* __restrict__ iflag,
                               int n, int* __restrict__ errflag)
{
  int i = blockIdx.x * 256 + threadIdx.x;
  if (i < n - 1){
    if (geti(batch, i, *iflag) > geti(batch, i + 1, *iflag)) atomicOr(errflag, 8);
  }
}

__global__ void k_check_x(const int* __restrict__ x, const int* __restrict__ iflag,
                          int n, int V, int* __restrict__ errflag)
{
  int i = blockIdx.x * 256 + threadIdx.x;
  if (i < n){
    int v = geti(x, i, *iflag);
    if ((unsigned)v >= (unsigned)V) atomicOr(errflag, 16);
  }
}

__global__ void k_check_edges(const int* __restrict__ ei, const int* __restrict__ iflag,
                              int E, int n, int* __restrict__ errflag)
{
  int e = blockIdx.x * 256 + threadIdx.x;
  if (e < E){
    int enc = *iflag;
    int s = geti(ei, e, enc);
    int d = geti(ei, E + e, enc);
    if ((unsigned)s >= (unsigned)n || (unsigned)d >= (unsigned)n) atomicOr(errflag, 32);
  }
}

// ---------------- CSR build: legacy path (fallback for huge N) ----------------

__global__ void k_hist(const int* __restrict__ ei, const int* __restrict__ iflag,
                       int* __restrict__ counts, int E, int n)
{
  int e = blockIdx.x * 256 + threadIdx.x;
  if (e < E){
    int d = geti(ei, E + e, *iflag);
    d = min(max(d, 0), n - 1);
    atomicAdd(&counts[d], 1);
  }
}

__global__ void k_scanA(const int* __restrict__ counts, int* __restrict__ rowptr,
                        int* __restrict__ bsums, int n)
{
  __shared__ int sd[1024];
  int tid = threadIdx.x;
  int gid = blockIdx.x * 1024 + tid;
  int v = (gid < n) ? counts[gid] : 0;
  sd[tid] = v;
  __syncthreads();
  for (int off = 1; off < 1024; off <<= 1){
    int t = 0;
    if (tid >= off) t = sd[tid - off];
    __syncthreads();
    if (tid >= off) sd[tid] += t;
    __syncthreads();
  }
  if (gid < n) rowptr[gid] = sd[tid] - v;
  if (tid == 1023) bsums[blockIdx.x] = sd[1023];
}

__global__ void k_scanB(const int* __restrict__ bsums, int* __restrict__ boffs, int nb)
{
  __shared__ int sd[128];
  int tid = threadIdx.x;
  int v = (tid < nb) ? bsums[tid] : 0;
  sd[tid] = v;
  __syncthreads();
  for (int off = 1; off < 128; off <<= 1){
    int t = 0;
    if (tid >= off) t = sd[tid - off];
    __syncthreads();
    if (tid >= off) sd[tid] += t;
    __syncthreads();
  }
  if (tid < nb) boffs[tid] = sd[tid] - v;
}

__global__ void k_scanC(int* __restrict__ rowptr, const int* __restrict__ boffs,
                        int* __restrict__ cursor, int n, int Etot)
{
  int gid = blockIdx.x * 1024 + threadIdx.x;
  if (gid < n){
    int v = rowptr[gid] + boffs[blockIdx.x];
    rowptr[gid] = v;
    cursor[gid] = v;
  }
  if (gid == 0) rowptr[n] = Etot;
}

__global__ void k_scatter(const int* __restrict__ ei, const int* __restrict__ iflag,
                          int* __restrict__ cursor, int* __restrict__ csr, int E, int n)
{
  int e = blockIdx.x * 256 + threadIdx.x;
  if (e < E){
    int enc = *iflag;
    int s = geti(ei, e, enc);
    int d = geti(ei, E + e, enc);
    d = min(max(d, 0), n - 1);
    int pos = atomicAdd(&cursor[d], 1);
    csr[pos] = s;
  }
}

__global__ void k_check_rows(const int* __restrict__ rowptr, const int* __restrict__ cursor,
                             int n, int* __restrict__ errflag)
{
  int i = blockIdx.x * 256 + threadIdx.x;
  if (i < n){
    if (cursor[i] != rowptr[i + 1]) atomicOr(errflag, 1);
    if (i == 0 && rowptr[0] != 0)   atomicOr(errflag, 4);
  }
}

__global__ void k_check_csr(const int* __restrict__ csr, int E, int n, int* __restrict__ errflag)
{
  int e = blockIdx.x * 256 + threadIdx.x;
  if (e < E && (unsigned)csr[e] >= (unsigned)n) atomicOr(errflag, 2);
}

// ---------------- CSR build: bucketed path ----------------
// Buckets of 512 dst nodes. Edge record packed as (s << 9) | (d & 511); valid
// while N <= 2^23 (we require nbuck <= 2048 i.e. N <= 1M).
//
// k_bhist : coarse per-bucket histogram, LDS-aggregated.
// k_bscan : 1-wave exclusive scan of bucket counts -> bucket offsets; bucket
//           offset in the binned array == its offset in csr (both group by node).
// k_bbin  : block-local bucket sort of 8192 edges in LDS, per-bucket global
//           range reservation, bucket-contiguous coalesced writes (~170B segs).
// k_bcsr  : one block per bucket: LDS node counts -> local scan -> rowptr
//           (coalesced) -> place s into the bucket's private 32KB csr window
//           (XCD-local, ~1x write amplification).

#define BSH   9
#define BSZ   512
#define BMSK  511
#define MAXB  2048
#define BINB  8192
#define BTH   512

__global__ void k_bhist(const int* __restrict__ ei, const int* __restrict__ iflag,
                        int* __restrict__ bcnt, int E, int N, int nbuck)
{
  __shared__ int h[MAXB];
  const int t = threadIdx.x;
  for (int i = t; i < nbuck; i += 256) h[i] = 0;
  __syncthreads();
  const int enc = *iflag;
  for (int e = blockIdx.x * 256 + t; e < E; e += gridDim.x * 256){
    int d = geti(ei, E + e, enc);
    d = min(max(d, 0), N - 1);
    atomicAdd(&h[d >> BSH], 1);
  }
  __syncthreads();
  for (int i = t; i < nbuck; i += 256){
    int c = h[i];
    if (c) atomicAdd(&bcnt[i], c);
  }
}

__global__ void k_bscan(const int* __restrict__ bcnt, int* __restrict__ boff,
                        int* __restrict__ gcur, int* __restrict__ rowptr,
                        int nbuck, int N, int E)
{
  __shared__ int sd[MAXB];
  const int lane = threadIdx.x;
  for (int i = lane; i < nbuck; i += 64) sd[i] = bcnt[i];
  __syncthreads();
  const int L = (nbuck + 63) >> 6;
  const int b0 = lane * L;
  int sum = 0;
  for (int j = 0; j < L; j++){ int idx = b0 + j; if (idx < nbuck) sum += sd[idx]; }
  int excl = sum;
  for (int off = 1; off < 64; off <<= 1){
    int x = __shfl_up(excl, off);
    if (lane >= off) excl += x;
  }
  excl -= sum;
  int run = excl;
  for (int j = 0; j < L; j++){
    int idx = b0 + j;
    if (idx < nbuck){ boff[idx] = run; gcur[idx] = run; run += sd[idx]; }
  }
  if (lane == 0){ boff[nbuck] = E; rowptr[N] = E; }
}

__global__ __launch_bounds__(BTH) void k_bbin(
    const int* __restrict__ ei, const int* __restrict__ iflag,
    int* __restrict__ gcur, u32* __restrict__ binned,
    int E, int N, int nbuck)
{
  __shared__ u32 stage[BINB];
  __shared__ u16 sbk[BINB];
  __shared__ int hist[MAXB];
  __shared__ int base[MAXB];
  __shared__ int gpos[MAXB];
  const int t   = threadIdx.x;
  const int e0  = blockIdx.x * BINB;
  const int cnt = min(BINB, E - e0);
  const int enc = *iflag;

  for (int i = t; i < nbuck; i += BTH) hist[i] = 0;
  __syncthreads();

  u32 pv[16]; int bk[16]; int rk[16];
  #pragma unroll
  for (int k = 0; k < 16; k++){
    bk[k] = -1;
    int lo = k * BTH + t;
    if (lo < cnt){
      int e = e0 + lo;
      int s = geti(ei, e, enc);
      int d = geti(ei, E + e, enc);
      s = min(max(s, 0), N - 1);
      d = min(max(d, 0), N - 1);
      int b = d >> BSH;
      pv[k] = ((u32)s << BSH) | (u32)(d & BMSK);
      bk[k] = b;
      rk[k] = atomicAdd(&hist[b], 1);
    }
  }
  __syncthreads();

  // exclusive scan of hist[0..nbuck) into base (wave 0)
  if (t < 64){
    const int L = (nbuck + 63) >> 6;
    const int b0 = t * L;
    int sum = 0;
    for (int j = 0; j < L; j++){ int idx = b0 + j; if (idx < nbuck) sum += hist[idx]; }
    int excl = sum;
    for (int off = 1; off < 64; off <<= 1){
      int x = __shfl_up(excl, off);
      if (t >= off) excl += x;
    }
    excl -= sum;
    int run = excl;
    for (int j = 0; j < L; j++){
      int idx = b0 + j;
      if (idx < nbuck){ base[idx] = run; run += hist[idx]; }
    }
  }
  __syncthreads();

  // reserve global ranges (one device atomic per non-empty bucket)
  for (int i = t; i < nbuck; i += BTH){
    int c = hist[i];
    gpos[i] = c ? atomicAdd(&gcur[i], c) : 0;
  }
  __syncthreads();

  // stage bucket-sorted
  #pragma unroll
  for (int k = 0; k < 16; k++){
    if (bk[k] >= 0){
      int slot = base[bk[k]] + rk[k];
      stage[slot] = pv[k];
      sbk[slot]   = (u16)bk[k];
    }
  }
  __syncthreads();

  // bucket-contiguous global writes
  for (int j = t; j < cnt; j += BTH){
    int b = sbk[j];
    binned[gpos[b] + (j - base[b])] = stage[j];
  }
}

__global__ __launch_bounds__(256) void k_bcsr(
    const u32* __restrict__ binned, const int* __restrict__ boff,
    int* __restrict__ rowptr, int* __restrict__ csr, int N, int nbuck)
{
  __shared__ int cnt[BSZ];
  __shared__ int rp[BSZ];
  __shared__ int cur[BSZ];
  const int b = blockIdx.x;
  const int t = threadIdx.x;
  const int lo = boff[b], hi = boff[b + 1];

  for (int i = t; i < BSZ; i += 256){ cnt[i] = 0; cur[i] = 0; }
  __syncthreads();

  for (int j = lo + t; j < hi; j += 256)
    atomicAdd(&cnt[binned[j] & BMSK], 1);
  __syncthreads();

  // exclusive scan of 512 node counts (wave 0)
  if (t < 64){
    const int b0 = t * 8;
    int sum = 0;
    #pragma unroll
    for (int j = 0; j < 8; j++) sum += cnt[b0 + j];
    int excl = sum;
    for (int off = 1; off < 64; off <<= 1){
      int x = __shfl_up(excl, off);
      if (t >= off) excl += x;
    }
    excl -= sum;
    int run = excl;
    #pragma unroll
    for (int j = 0; j < 8; j++){ rp[b0 + j] = run; run += cnt[b0 + j]; }
  }
  __syncthreads();

  const int node0 = b << BSH;
  for (int i = t; i < BSZ; i += 256){
    int node = node0 + i;
    if (node < N) rowptr[node] = lo + rp[i];
  }

  for (int j = lo + t; j < hi; j += 256){
    u32 pvv = binned[j];
    int dl  = pvv & BMSK;
    int pos = lo + rp[dl] + atomicAdd(&cur[dl], 1);
    csr[pos] = (int)(pvv >> BSH);
  }
}

// ---------------- stamps ----------------

__global__ void k_stamp_if(const int* __restrict__ errflag, float* __restrict__ out, int nel)
{
  int f = *errflag;
  if (f == 0) return;
  float s = 500.0f + 100.0f * (float)f;
  int i = blockIdx.x * 256 + threadIdx.x;
  if (i < nel) out[i] = s;
}

__global__ void k_stamp(float* __restrict__ out, int nel, float val)
{
  int i = blockIdx.x * 256 + threadIdx.x;
  if (i < nel) out[i] = val;
}

// ---------------- layer-1 vocab table ----------------

__global__ void k_prep(const float* __restrict__ emb,
                       const float* __restrict__ ln_g, const float* __restrict__ ln_b,
                       const float* __restrict__ W1, const float* __restrict__ a_src,
                       const float* __restrict__ a_dst,
                       u16* __restrict__ xwv, float* __restrict__ alsv, float* __restrict__ aldv)
{
  __shared__ float se[32];
  __shared__ float stats[2];
  __shared__ float sxw[128];
  const int v = blockIdx.x, t = threadIdx.x;
  if (t < 32) se[t] = emb[v * 32 + t];
  __syncthreads();
  if (t == 0){
    float s1 = 0.f, s2 = 0.f;
    for (int k = 0; k < 32; k++){ s1 += se[k]; s2 += se[k] * se[k]; }
    float mu = s1 * (1.f / 32.f);
    float var = s2 * (1.f / 32.f) - mu * mu;
    stats[0] = mu; stats[1] = rsqrtf(var + LN_EPS);
  }
  __syncthreads();
  const float mu = stats[0], rs = stats[1];
  float o = 0.f;
  for (int k = 0; k < 32; k++){
    float xe = (se[k] - mu) * rs * ln_g[k] + ln_b[k];
    o += xe * W1[k * 128 + t];
  }
  sxw[t] = o;
  xwv[v * 128 + t] = f2bf(o);
  __syncthreads();
  if (t < 2){
    float ps = 0.f, pd = 0.f;
    for (int d = 0; d < 64; d++){
      float vv = sxw[t * 64 + d];
      ps += vv * a_src[t * 64 + d];
      pd += vv * a_dst[t * 64 + d];
    }
    alsv[2 * v + t] = ps;
    aldv[2 * v + t] = pd;
  }
}

__global__ void k_lookup(const int* __restrict__ x, const int* __restrict__ iflag,
                         const u16* __restrict__ xwv, const float* __restrict__ alsv,
                         const float* __restrict__ aldv, int N, int V,
                         u16* __restrict__ xw, float* __restrict__ al_s, float* __restrict__ al_d)
{
  const int enc = *iflag;
  const int tid = threadIdx.x;
  const int c = tid & 15;
  for (int base = blockIdx.x * 16; base < N; base += gridDim.x * 16){
    int i = base + (tid >> 4);
    if (i < N){
      int v = geti(x, i, enc);
      v = min(max(v, 0), V - 1);
      uint4 row = *(const uint4*)(xwv + v * 128 + c * 8);
      *(uint4*)(xw + (size_t)i * 128 + c * 8) = row;
      if (c == 0){ float2 a = *(const float2*)(alsv + 2 * v); *(float2*)(al_s + 2 * i) = a; }
      if (c == 1){ float2 a = *(const float2*)(aldv + 2 * v); *(float2*)(al_d + 2 * i) = a; }
    }
  }
}

// ---------------- GAT: one wave per dst node ----------------

__global__ __launch_bounds__(64, 8) void k_gatw(
    const int* __restrict__ rowptr, const int* __restrict__ csr,
    const float* __restrict__ al_s, const float* __restrict__ al_d,
    const u16* __restrict__ xw, const float* __restrict__ bias,
    int apply_act, float* __restrict__ out)
{
  const int i    = blockIdx.x;
  const int lane = threadIdx.x;
  const int sub  = lane >> 4;
  const int c16  = lane & 15;
  const int r0 = rowptr[i], deg = rowptr[i + 1] - r0, total = deg + 1;
  const float ad0 = al_d[2 * i], ad1 = al_d[2 * i + 1];

  float m0 = -3.0e38f, m1 = -3.0e38f;
  for (int k = lane; k < total; k += 64){
    int s = (k < deg) ? csr[r0 + k] : i;
    float a0 = lrelu(al_s[2 * s]     + ad0, NEG_GAT);
    float a1 = lrelu(al_s[2 * s + 1] + ad1, NEG_GAT);
    m0 = fmaxf(m0, a0); m1 = fmaxf(m1, a1);
  }
  #pragma unroll
  for (int off = 32; off; off >>= 1){
    m0 = fmaxf(m0, __shfl_xor(m0, off));
    m1 = fmaxf(m1, __shfl_xor(m1, off));
  }

  float sum0 = 0.f, sum1 = 0.f;
  float acc[8];
  #pragma unroll
  for (int r = 0; r < 8; r++) acc[r] = 0.f;

  for (int base = 0; base < total; base += 64){
    int k = base + lane;
    int s = i; float ex0 = 0.f, ex1 = 0.f;
    if (k < total){
      s = (k < deg) ? csr[r0 + k] : i;
      ex0 = __expf(lrelu(al_s[2 * s]     + ad0, NEG_GAT) - m0);
      ex1 = __expf(lrelu(al_s[2 * s + 1] + ad1, NEG_GAT) - m1);
    }
    sum0 += ex0; sum1 += ex1;

    int cnt  = min(64, total - base);
    int qmax = (cnt + 3) & ~3;
    for (int q = 0; q < qmax; q += 4){
      int   j  = q + sub;
      int   sj = __shfl(s, j);
      float e0 = __shfl(ex0, j);
      float e1 = __shfl(ex1, j);
      float ej = (c16 < 8) ? e0 : e1;
      uint4 w = *(const uint4*)(xw + (size_t)sj * 128 + c16 * 8);
      acc[0] += ej * bf2f(w.x & 0xffffu); acc[1] += ej * bf2f(w.x >> 16);
      acc[2] += ej * bf2f(w.y & 0xffffu); acc[3] += ej * bf2f(w.y >> 16);
      acc[4] += ej * bf2f(w.z & 0xffffu); acc[5] += ej * bf2f(w.z >> 16);
      acc[6] += ej * bf2f(w.w & 0xffffu); acc[7] += ej * bf2f(w.w >> 16);
    }
  }
  #pragma unroll
  for (int off = 32; off; off >>= 1){
    sum0 += __shfl_xor(sum0, off);
    sum1 += __shfl_xor(sum1, off);
  }
  #pragma unroll
  for (int r = 0; r < 8; r++){
    acc[r] += __shfl_xor(acc[r], 16);
    acc[r] += __shfl_xor(acc[r], 32);
  }

  if (sub == 0){
    float inv = 1.f / ((c16 < 8) ? sum0 : sum1);
    const float4* bp = (const float4*)(bias + c16 * 8);
    float4 b0 = bp[0], b1 = bp[1];
    float4 o0, o1;
    o0.x = acc[0] * inv + b0.x; o0.y = acc[1] * inv + b0.y;
    o0.z = acc[2] * inv + b0.z; o0.w = acc[3] * inv + b0.w;
    o1.x = acc[4] * inv + b1.x; o1.y = acc[5] * inv + b1.y;
    o1.z = acc[6] * inv + b1.z; o1.w = acc[7] * inv + b1.w;
    if (apply_act){
      o0.x = lrelu(o0.x, NEG_ACT); o0.y = lrelu(o0.y, NEG_ACT);
      o0.z = lrelu(o0.z, NEG_ACT); o0.w = lrelu(o0.w, NEG_ACT);
      o1.x = lrelu(o1.x, NEG_ACT); o1.y = lrelu(o1.y, NEG_ACT);
      o1.z = lrelu(o1.z, NEG_ACT); o1.w = lrelu(o1.w, NEG_ACT);
    }
    float* op = out + (size_t)i * 128 + c16 * 8;
    *(float4*)op       = o0;
    *(float4*)(op + 4) = o1;
  }
}

// ---------------- pack weight matrix into MFMA B-fragment order ----------------

__global__ void k_packW(const float* __restrict__ W, int ncols, int ntiles,
                        u16* __restrict__ pb)
{
  const int ktile = blockIdx.x / ntiles;
  const int ntile = blockIdx.x % ntiles;
  const int lane  = threadIdx.x;
  const int n  = ntile * 16 + (lane & 15);
  const int k0 = ktile * 32 + (lane >> 4) * 8;
  u16* dst = pb + ((size_t)blockIdx.x * 64 + lane) * 8;
  #pragma unroll
  for (int j = 0; j < 8; j++)
    dst[j] = f2bf(W[(k0 + j) * ncols + n]);
}

// ---------------- layer-2 node prep: MFMA GEMM xw2 = h1 @ W2 (+ al epilogue) ----------------

__global__ __launch_bounds__(256, 2) void k_node2m(
    const float* __restrict__ h1, const u16* __restrict__ pb2,
    const float* __restrict__ a_src, const float* __restrict__ a_dst,
    int N, u16* __restrict__ xw, float* __restrict__ al_s, float* __restrict__ al_d)
{
  const int wave = threadIdx.x >> 6;
  const int lane = threadIdx.x & 63;
  const int rowbase = blockIdx.x * 64 + wave * 16;
  const int m    = lane & 15;
  const int quad = lane >> 4;

  int arow = rowbase + m; if (arow >= N) arow = N - 1;
  const float* aptr = h1 + (size_t)arow * 128 + quad * 8;

  f32x4 acc[8];
  #pragma unroll
  for (int nt = 0; nt < 8; nt++) acc[nt] = (f32x4){0.f, 0.f, 0.f, 0.f};

  #pragma unroll
  for (int kt = 0; kt < 4; kt++){
    float4 a0 = *(const float4*)(aptr + kt * 32);
    float4 a1 = *(const float4*)(aptr + kt * 32 + 4);
    bf16x8 af;
    af[0] = (short)f2bf(a0.x); af[1] = (short)f2bf(a0.y);
    af[2] = (short)f2bf(a0.z); af[3] = (short)f2bf(a0.w);
    af[4] = (short)f2bf(a1.x); af[5] = (short)f2bf(a1.y);
    af[6] = (short)f2bf(a1.z); af[7] = (short)f2bf(a1.w);
    const u16* bbase = pb2 + (((size_t)kt * 8) * 64 + lane) * 8;
    #pragma unroll
    for (int nt = 0; nt < 8; nt++){
      bf16x8 bf = *(const bf16x8*)(bbase + (size_t)nt * 64 * 8);
      acc[nt] = __builtin_amdgcn_mfma_f32_16x16x32_bf16(af, bf, acc[nt], 0, 0, 0);
    }
  }

  float asv[8], adv[8];
  #pragma unroll
  for (int nt = 0; nt < 8; nt++){
    asv[nt] = a_src[nt * 16 + m];
    adv[nt] = a_dst[nt * 16 + m];
  }
  #pragma unroll
  for (int r = 0; r < 4; r++){
    int row = rowbase + quad * 4 + r;
    bool ok = row < N;
    float s0 = 0.f, s1 = 0.f, d0 = 0.f, d1 = 0.f;
    #pragma unroll
    for (int nt = 0; nt < 8; nt++){
      float v = acc[nt][r];
      if (ok) xw[(size_t)row * 128 + nt * 16 + m] = f2bf(v);
      if (nt < 4){ s0 += v * asv[nt]; d0 += v * adv[nt]; }
      else       { s1 += v * asv[nt]; d1 += v * adv[nt]; }
    }
    #pragma unroll
    for (int off = 1; off < 16; off <<= 1){
      s0 += __shfl_xor(s0, off); s1 += __shfl_xor(s1, off);
      d0 += __shfl_xor(d0, off); d1 += __shfl_xor(d1, off);
    }
    if (ok && m == 0){
      al_s[2 * row] = s0; al_s[2 * row + 1] = s1;
      al_d[2 * row] = d0; al_d[2 * row + 1] = d1;
    }
  }
}

// ---------------- gate: MFMA GEMM t = h @ gw1, fused lrelu + dot(gw2) ----------------

__global__ __launch_bounds__(256, 2) void k_gatem(
    const float* __restrict__ h, const u16* __restrict__ pbg,
    const float* __restrict__ gb1, const float* __restrict__ gw2,
    const float* __restrict__ gb2, int N, float* __restrict__ gate)
{
  const int wave = threadIdx.x >> 6;
  const int lane = threadIdx.x & 63;
  const int rowbase = blockIdx.x * 64 + wave * 16;
  const int m    = lane & 15;
  const int quad = lane >> 4;

  int arow = rowbase + m; if (arow >= N) arow = N - 1;
  const float* aptr = h + (size_t)arow * 128 + quad * 8;

  f32x4 acc[4];
  #pragma unroll
  for (int nt = 0; nt < 4; nt++) acc[nt] = (f32x4){0.f, 0.f, 0.f, 0.f};

  #pragma unroll
  for (int kt = 0; kt < 4; kt++){
    float4 a0 = *(const float4*)(aptr + kt * 32);
    float4 a1 = *(const float4*)(aptr + kt * 32 + 4);
    bf16x8 af;
    af[0] = (short)f2bf(a0.x); af[1] = (short)f2bf(a0.y);
    af[2] = (short)f2bf(a0.z); af[3] = (short)f2bf(a0.w);
    af[4] = (short)f2bf(a1.x); af[5] = (short)f2bf(a1.y);
    af[6] = (short)f2bf(a1.z); af[7] = (short)f2bf(a1.w);
    const u16* bbase = pbg + (((size_t)kt * 4) * 64 + lane) * 8;
    #pragma unroll
    for (int nt = 0; nt < 4; nt++){
      bf16x8 bf = *(const bf16x8*)(bbase + (size_t)nt * 64 * 8);
      acc[nt] = __builtin_amdgcn_mfma_f32_16x16x32_bf16(af, bf, acc[nt], 0, 0, 0);
    }
  }

  float gbv[4], g2v[4];
  #pragma unroll
  for (int nt = 0; nt < 4; nt++){
    gbv[nt] = gb1[nt * 16 + m];
    g2v[nt] = gw2[nt * 16 + m];
  }
  const float g2b = gb2[0];
  #pragma unroll
  for (int r = 0; r < 4; r++){
    int row = rowbase + quad * 4 + r;
    float q = 0.f;
    #pragma unroll
    for (int nt = 0; nt < 4; nt++)
      q += lrelu(acc[nt][r] + gbv[nt], NEG_ACT) * g2v[nt];
    #pragma unroll
    for (int off = 1; off < 16; off <<= 1) q += __shfl_xor(q, off);
    if (row < N && m == 0) gate[row] = q + g2b;
  }
}

// ---------------- per-graph softmax pooling ----------------

__global__ void k_graphsw(const int* __restrict__ batch, const int* __restrict__ iflag,
                          const float* __restrict__ gate,
                          const float* __restrict__ h, float* __restrict__ zout, int N)
{
  __shared__ int   range[2];
  __shared__ float red[4];
  const int g = blockIdx.x, t = threadIdx.x;
  const int wave = t >> 6;
  if (t == 0){
    const int enc = *iflag;
    int lo = 0, hi = N;
    while (lo < hi){ int mid = (lo + hi) >> 1; if (geti(batch, mid, enc) < g) lo = mid + 1; else hi = mid; }
    range[0] = lo;
    hi = N;
    while (lo < hi){ int mid = (lo + hi) >> 1; if (geti(batch, mid, enc) < g + 1) lo = mid + 1; else hi = mid; }
    range[1] = lo;
  }
  __syncthreads();
  const int st = range[0], en = range[1];

  float m = -3.0e38f;
  for (int k = st + t; k < en; k += 128) m = fmaxf(m, gate[k]);
  #pragma unroll
  for (int off = 32; off; off >>= 1) m = fmaxf(m, __shfl_xor(m, off));
  if ((t & 63) == 0) red[wave] = m;
  __syncthreads();
  m = fmaxf(red[0], red[1]);

  float s = 0.f;
  for (int k = st + t; k < en; k += 128) s += __expf(gate[k] - m);
  #pragma unroll
  for (int off = 32; off; off >>= 1) s += __shfl_xor(s, off);
  if ((t & 63) == 0) red[2 + wave] = s;
  __syncthreads();
  s = red[2] + red[3];

  float z = 0.f;
  const float inv = 1.f / s;
  for (int k = st; k < en; k++){
    float wk = __expf(gate[k] - m) * inv;
    z += wk * h[(size_t)k * 128 + t];
  }
  zout[(size_t)g * 128 + t] = z;
}

// ---------------- launch ----------------

extern "C" void kernel_launch(void* const* d_in, const int* in_sizes, int n_in,
                              void* d_out, int out_size, void* d_ws, size_t ws_size,
                              hipStream_t stream)
{
  const int* x      = (const int*)d_in[0];
  const int* ei     = (const int*)d_in[1];
  const int* batch  = (const int*)d_in[2];

  const int N = in_sizes[0];
  const int E = in_sizes[1] / 2;
  const int V = in_sizes[3] / 32;
  const int G = out_size / 128 - N;

  char* p = (char*)d_ws;
  auto alloc = [&](size_t bytes) -> char* {
    char* r = p; p += (bytes + 255) & ~(size_t)255; return r;
  };
  int*   multi  = (int*)  alloc((size_t)N * 4);       // counts -> cursor -> gate
  int*   rowptr = (int*)  alloc((size_t)(N + 1) * 4);
  int*   csr    = (int*)  alloc((size_t)E * 4);
  int*   bsums  = (int*)  alloc(4096);
  int*   boffs  = (int*)  alloc(4096);
  int*   flags  = (int*)  alloc(256);
  int*   fflag  = flags;
  int*   iflag  = flags + 1;
  int*   errflg = flags + 2;
  float* al_s   = (float*)alloc((size_t)N * 2 * 4);
  float* al_d   = (float*)alloc((size_t)N * 2 * 4);
  u16*   xw     = (u16*)  alloc((size_t)N * 128 * 2);
  u16*   xwv    = (u16*)  alloc((size_t)V * 128 * 2);
  float* alsv   = (float*)alloc((size_t)V * 2 * 4);
  float* aldv   = (float*)alloc((size_t)V * 2 * 4);
  u16*   pb2    = (u16*)  alloc((size_t)128 * 128 * 2);  // W2 packed
  u16*   pbg    = (u16*)  alloc((size_t)128 * 64 * 2);   // gw1 packed

  const int nbuck = (N + BSZ - 1) >> BSH;
  int*   bcnt   = (int*)  alloc((size_t)(MAXB) * 4);
  int*   boff   = (int*)  alloc((size_t)(MAXB + 1) * 4);
  int*   gcur   = (int*)  alloc((size_t)(MAXB) * 4);
  u32*   binned = (u32*)  alloc((size_t)E * 4);

  CvtParams cp;
  float* fpar[NPARAM];
  int maxn = 0;
  for (int pi = 0; pi < NPARAM; pi++){
    int n = in_sizes[3 + pi];
    fpar[pi] = (float*)alloc((size_t)n * 4);
    cp.src[pi] = d_in[3 + pi];
    cp.dst[pi] = fpar[pi];
    cp.n[pi]   = n;
    if (n > maxn) maxn = n;
  }
  const size_t needed = (size_t)(p - (char*)d_ws);

  const float* emb    = fpar[0];
  const float* ln_g   = fpar[1];
  const float* ln_b   = fpar[2];
  const float* W1     = fpar[3];
  const float* a_src1 = fpar[4];
  const float* a_dst1 = fpar[5];
  const float* b1     = fpar[6];
  const float* W2     = fpar[7];
  const float* a_src2 = fpar[8];
  const float* a_dst2 = fpar[9];
  const float* b2     = fpar[10];
  const float* gw1    = fpar[11];
  const float* gb1    = fpar[12];
  const float* gw2    = fpar[13];
  const float* gb2    = fpar[14];
  (void)n_in;

  int ob = (out_size + 255) / 256;
  if (ws_size < needed){
    k_stamp<<<ob, 256, 0, stream>>>((float*)d_out, out_size, 9999.0f);
    return;
  }

  int*   counts = multi;
  int*   cursor = multi;
  float* gate   = (float*)multi;
  float* hbuf   = (float*)d_out;
  float* zbuf   = (float*)d_out + (size_t)N * 128;

  k_detect<<<1, 64, 0, stream>>>((const u32*)d_in[4], ei, fflag, iflag, errflg);
  dim3 cgrid((maxn + 255) / 256, NPARAM);
  k_convert<<<cgrid, 256, 0, stream>>>(cp, fflag);

  int eb = (E + 255) / 256;
  int nb = (N + 1023) / 1024;
  int nb256 = (N + 255) / 256;

  k_check_sorted<<<nb256, 256, 0, stream>>>(batch, iflag, N, errflg);
  k_check_x<<<nb256, 256, 0, stream>>>(x, iflag, N, V, errflg);
  k_check_edges<<<eb, 256, 0, stream>>>(ei, iflag, E, N, errflg);

  if (nbuck <= MAXB){
    // bucketed CSR build: coalesced writes, no device-wide random atomics
    hipMemsetAsync(bcnt, 0, (size_t)nbuck * 4, stream);
    k_bhist<<<256, 256, 0, stream>>>(ei, iflag, bcnt, E, N, nbuck);
    k_bscan<<<1, 64, 0, stream>>>(bcnt, boff, gcur, rowptr, nbuck, N, E);
    k_bbin<<<(E + BINB - 1) / BINB, BTH, 0, stream>>>(ei, iflag, gcur, binned, E, N, nbuck);
    k_bcsr<<<nbuck, 256, 0, stream>>>(binned, boff, rowptr, csr, N, nbuck);
  } else {
    // legacy path for very large N
    hipMemsetAsync(counts, 0, (size_t)N * 4, stream);
    hipMemsetAsync(csr, 0xFF, (size_t)E * 4, stream);
    k_hist<<<eb, 256, 0, stream>>>(ei, iflag, counts, E, N);
    k_scanA<<<nb, 1024, 0, stream>>>(counts, rowptr, bsums, N);
    k_scanB<<<1, 128, 0, stream>>>(bsums, boffs, nb);
    k_scanC<<<nb, 1024, 0, stream>>>(rowptr, boffs, cursor, N, E);
    k_scatter<<<eb, 256, 0, stream>>>(ei, iflag, cursor, csr, E, N);
    k_check_rows<<<nb256, 256, 0, stream>>>(rowptr, cursor, N, errflg);
    k_check_csr<<<eb, 256, 0, stream>>>(csr, E, N, errflg);
  }

  // pack weights for MFMA
  k_packW<<<32, 64, 0, stream>>>(W2, 128, 8, pb2);
  k_packW<<<16, 64, 0, stream>>>(gw1, 64, 4, pbg);

  // layer 1 via vocab table
  k_prep<<<V, 128, 0, stream>>>(emb, ln_g, ln_b, W1, a_src1, a_dst1, xwv, alsv, aldv);
  k_lookup<<<1024, 256, 0, stream>>>(x, iflag, xwv, alsv, aldv, N, V, xw, al_s, al_d);

  k_gatw<<<N, 64, 0, stream>>>(rowptr, csr, al_s, al_d, xw, b1, 1, hbuf);

  const int gblk = (N + 63) / 64;
  k_node2m<<<gblk, 256, 0, stream>>>(hbuf, pb2, a_src2, a_dst2, N, xw, al_s, al_d);

  k_gatw<<<N, 64, 0, stream>>>(rowptr, csr, al_s, al_d, xw, b2, 0, hbuf);

  k_gatem<<<gblk, 256, 0, stream>>>(hbuf, pbg, gb1, gw2, gb2, N, gate);
  k_graphsw<<<G, 128, 0, stream>>>(batch, iflag, gate, hbuf, zbuf, N);

  k_stamp_if<<<ob, 256, 0, stream>>>(errflg, (float*)d_out, out_size);
}

// Round 2
// 398.425 us; speedup vs baseline: 1.4607x; 1.0576x over previous
//
#include <hip/hip_runtime.h>
#include <hip/hip_bf16.h>
#include <stdint.h>

typedef unsigned short u16;
typedef unsigned int   u32;
typedef __attribute__((ext_vector_type(8))) short bf16x8;
typedef __attribute__((ext_vector_type(4))) float f32x4;

#define NEG_GAT 0.2f
#define NEG_ACT 0.05f
#define LN_EPS  1e-5f
#define NPARAM  15

__device__ __forceinline__ float bf2f(u32 bits16){
  union { u32 u; float f; } v; v.u = bits16 << 16; return v.f;
}
__device__ __forceinline__ u16 f2bf(float f){
  union { float f; u32 u; } v; v.f = f;
  u32 u = v.u;
  u32 r = (u + 0x7fffu + ((u >> 16) & 1u)) >> 16;
  return (u16)r;
}
// valid for slope in (0,1): max(x, s*x) == leaky_relu(x, s)
__device__ __forceinline__ float lrelu(float x, float s){ return fmaxf(x, s * x); }

__device__ __forceinline__ int geti(const int* __restrict__ p, int i, int enc){
  return p[enc ? (2 * i) : i];
}

// ---------------- dtype detection ----------------

struct CvtParams {
  const void* src[NPARAM];
  float*      dst[NPARAM];
  int         n[NPARAM];
};

__global__ void k_detect(const u32* __restrict__ ln_g_raw, const int* __restrict__ ei_raw,
                         int* __restrict__ fflag, int* __restrict__ iflag,
                         int* __restrict__ errflag)
{
  if (threadIdx.x == 0){
    *fflag = (ln_g_raw[0] == 0x3F800000u) ? 0 : 1;
    int zeros = 0;
    for (int j = 0; j < 64; j++) if (ei_raw[2 * j + 1] == 0) zeros++;
    *iflag = (zeros >= 60) ? 1 : 0;
    *errflag = 0;
  }
}

__global__ void k_convert(CvtParams P, const int* __restrict__ flag)
{
  const int pi  = blockIdx.y;
  const int idx = blockIdx.x * 256 + threadIdx.x;
  if (idx >= P.n[pi]) return;
  if (*flag == 0) P.dst[pi][idx] = ((const float*)P.src[pi])[idx];
  else            P.dst[pi][idx] = bf2f(((const u16*)P.src[pi])[idx]);
}

// ---------------- validators ----------------

__global__ void k_check_sorted(const int* __restrict__ batch, const int* __restrict__ iflag,
                               int n, int* __restrict__ errflag)
{
  int i = blockIdx.x * 256 + threadIdx.x;
  if (i < n - 1){
    if (geti(batch, i, *iflag) > geti(batch, i + 1, *iflag)) atomicOr(errflag, 8);
  }
}

__global__ void k_check_x(const int* __restrict__ x, const int* __restrict__ iflag,
                          int n, int V, int* __restrict__ errflag)
{
  int i = blockIdx.x * 256 + threadIdx.x;
  if (i < n){
    int v = geti(x, i, *iflag);
    if ((unsigned)v >= (unsigned)V) atomicOr(errflag, 16);
  }
}

__global__ void k_check_edges(const int* __restrict__ ei, const int* __restrict__ iflag,
                              int E, int n, int* __restrict__ errflag)
{
  int e = blockIdx.x * 256 + threadIdx.x;
  if (e < E){
    int enc = *iflag;
    int s = geti(ei, e, enc);
    int d = geti(ei, E + e, enc);
    if ((unsigned)s >= (unsigned)n || (unsigned)d >= (unsigned)n) atomicOr(errflag, 32);
  }
}

// ---------------- CSR build: legacy path (fallback for huge N) ----------------

__global__ void k_hist(const int* __restrict__ ei, const int* __restrict__ iflag,
                       int* __restrict__ counts, int E, int n)
{
  int e = blockIdx.x * 256 + threadIdx.x;
  if (e < E){
    int d = geti(ei, E + e, *iflag);
    d = min(max(d, 0), n - 1);
    atomicAdd(&counts[d], 1);
  }
}

__global__ void k_scanA(const int* __restrict__ counts, int* __restrict__ rowptr,
                        int* __restrict__ bsums, int n)
{
  __shared__ int sd[1024];
  int tid = threadIdx.x;
  int gid = blockIdx.x * 1024 + tid;
  int v = (gid < n) ? counts[gid] : 0;
  sd[tid] = v;
  __syncthreads();
  for (int off = 1; off < 1024; off <<= 1){
    int t = 0;
    if (tid >= off) t = sd[tid - off];
    __syncthreads();
    if (tid >= off) sd[tid] += t;
    __syncthreads();
  }
  if (gid < n) rowptr[gid] = sd[tid] - v;
  if (tid == 1023) bsums[blockIdx.x] = sd[1023];
}

__global__ void k_scanB(const int* __restrict__ bsums, int* __restrict__ boffs, int nb)
{
  __shared__ int sd[128];
  int tid = threadIdx.x;
  int v = (tid < nb) ? bsums[tid] : 0;
  sd[tid] = v;
  __syncthreads();
  for (int off = 1; off < 128; off <<= 1){
    int t = 0;
    if (tid >= off) t = sd[tid - off];
    __syncthreads();
    if (tid >= off) sd[tid] += t;
    __syncthreads();
  }
  if (tid < nb) boffs[tid] = sd[tid] - v;
}

__global__ void k_scanC(int* __restrict__ rowptr, const int* __restrict__ boffs,
                        int* __restrict__ cursor, int n, int Etot)
{
  int gid = blockIdx.x * 1024 + threadIdx.x;
  if (gid < n){
    int v = rowptr[gid] + boffs[blockIdx.x];
    rowptr[gid] = v;
    cursor[gid] = v;
  }
  if (gid == 0) rowptr[n] = Etot;
}

__global__ void k_scatter(const int* __restrict__ ei, const int* __restrict__ iflag,
                          int* __restrict__ cursor, int* __restrict__ csr, int E, int n)
{
  int e = blockIdx.x * 256 + threadIdx.x;
  if (e < E){
    int enc = *iflag;
    int s = geti(ei, e, enc);
    int d = geti(ei, E + e, enc);
    d = min(max(d, 0), n - 1);
    int pos = atomicAdd(&cursor[d], 1);
    csr[pos] = s;
  }
}

__global__ void k_check_rows(const int* __restrict__ rowptr, const int* __restrict__ cursor,
                             int n, int* __restrict__ errflag)
{
  int i = blockIdx.x * 256 + threadIdx.x;
  if (i < n){
    if (cursor[i] != rowptr[i + 1]) atomicOr(errflag, 1);
    if (i == 0 && rowptr[0] != 0)   atomicOr(errflag, 4);
  }
}

__global__ void k_check_csr(const int* __restrict__ csr, int E, int n, int* __restrict__ errflag)
{
  int e = blockIdx.x * 256 + threadIdx.x;
  if (e < E && (unsigned)csr[e] >= (unsigned)n) atomicOr(errflag, 2);
}

// ---------------- CSR build: bucketed path ----------------

#define BSH   9
#define BSZ   512
#define BMSK  511
#define MAXB  2048
#define BINB  8192
#define BTH   512

__global__ void k_bhist(const int* __restrict__ ei, const int* __restrict__ iflag,
                        int* __restrict__ bcnt, int E, int N, int nbuck)
{
  __shared__ int h[MAXB];
  const int t = threadIdx.x;
  for (int i = t; i < nbuck; i += 256) h[i] = 0;
  __syncthreads();
  const int enc = *iflag;
  for (int e = blockIdx.x * 256 + t; e < E; e += gridDim.x * 256){
    int d = geti(ei, E + e, enc);
    d = min(max(d, 0), N - 1);
    atomicAdd(&h[d >> BSH], 1);
  }
  __syncthreads();
  for (int i = t; i < nbuck; i += 256){
    int c = h[i];
    if (c) atomicAdd(&bcnt[i], c);
  }
}

__global__ void k_bscan(const int* __restrict__ bcnt, int* __restrict__ boff,
                        int* __restrict__ gcur, int* __restrict__ rowptr,
                        int nbuck, int N, int E)
{
  __shared__ int sd[MAXB];
  const int lane = threadIdx.x;
  for (int i = lane; i < nbuck; i += 64) sd[i] = bcnt[i];
  __syncthreads();
  const int L = (nbuck + 63) >> 6;
  const int b0 = lane * L;
  int sum = 0;
  for (int j = 0; j < L; j++){ int idx = b0 + j; if (idx < nbuck) sum += sd[idx]; }
  int excl = sum;
  for (int off = 1; off < 64; off <<= 1){
    int x = __shfl_up(excl, off);
    if (lane >= off) excl += x;
  }
  excl -= sum;
  int run = excl;
  for (int j = 0; j < L; j++){
    int idx = b0 + j;
    if (idx < nbuck){ boff[idx] = run; gcur[idx] = run; run += sd[idx]; }
  }
  if (lane == 0){ boff[nbuck] = E; rowptr[N] = E; }
}

__global__ __launch_bounds__(BTH) void k_bbin(
    const int* __restrict__ ei, const int* __restrict__ iflag,
    int* __restrict__ gcur, u32* __restrict__ binned,
    int E, int N, int nbuck)
{
  __shared__ u32 stage[BINB];
  __shared__ u16 sbk[BINB];
  __shared__ int hist[MAXB];
  __shared__ int base[MAXB];
  __shared__ int gpos[MAXB];
  const int t   = threadIdx.x;
  const int e0  = blockIdx.x * BINB;
  const int cnt = min(BINB, E - e0);
  const int enc = *iflag;

  for (int i = t; i < nbuck; i += BTH) hist[i] = 0;
  __syncthreads();

  u32 pv[16]; int bk[16]; int rk[16];
  #pragma unroll
  for (int k = 0; k < 16; k++){
    bk[k] = -1;
    int lo = k * BTH + t;
    if (lo < cnt){
      int e = e0 + lo;
      int s = geti(ei, e, enc);
      int d = geti(ei, E + e, enc);
      s = min(max(s, 0), N - 1);
      d = min(max(d, 0), N - 1);
      int b = d >> BSH;
      pv[k] = ((u32)s << BSH) | (u32)(d & BMSK);
      bk[k] = b;
      rk[k] = atomicAdd(&hist[b], 1);
    }
  }
  __syncthreads();

  if (t < 64){
    const int L = (nbuck + 63) >> 6;
    const int b0 = t * L;
    int sum = 0;
    for (int j = 0; j < L; j++){ int idx = b0 + j; if (idx < nbuck) sum += hist[idx]; }
    int excl = sum;
    for (int off = 1; off < 64; off <<= 1){
      int x = __shfl_up(excl, off);
      if (t >= off) excl += x;
    }
    excl -= sum;
    int run = excl;
    for (int j = 0; j < L; j++){
      int idx = b0 + j;
      if (idx < nbuck){ base[idx] = run; run += hist[idx]; }
    }
  }
  __syncthreads();

  for (int i = t; i < nbuck; i += BTH){
    int c = hist[i];
    gpos[i] = c ? atomicAdd(&gcur[i], c) : 0;
  }
  __syncthreads();

  #pragma unroll
  for (int k = 0; k < 16; k++){
    if (bk[k] >= 0){
      int slot = base[bk[k]] + rk[k];
      stage[slot] = pv[k];
      sbk[slot]   = (u16)bk[k];
    }
  }
  __syncthreads();

  for (int j = t; j < cnt; j += BTH){
    int b = sbk[j];
    binned[gpos[b] + (j - base[b])] = stage[j];
  }
}

__global__ __launch_bounds__(256) void k_bcsr(
    const u32* __restrict__ binned, const int* __restrict__ boff,
    int* __restrict__ rowptr, int* __restrict__ csr, int N, int nbuck)
{
  __shared__ int cnt[BSZ];
  __shared__ int rp[BSZ];
  __shared__ int cur[BSZ];
  const int b = blockIdx.x;
  const int t = threadIdx.x;
  const int lo = boff[b], hi = boff[b + 1];

  for (int i = t; i < BSZ; i += 256){ cnt[i] = 0; cur[i] = 0; }
  __syncthreads();

  for (int j = lo + t; j < hi; j += 256)
    atomicAdd(&cnt[binned[j] & BMSK], 1);
  __syncthreads();

  if (t < 64){
    const int b0 = t * 8;
    int sum = 0;
    #pragma unroll
    for (int j = 0; j < 8; j++) sum += cnt[b0 + j];
    int excl = sum;
    for (int off = 1; off < 64; off <<= 1){
      int x = __shfl_up(excl, off);
      if (t >= off) excl += x;
    }
    excl -= sum;
    int run = excl;
    #pragma unroll
    for (int j = 0; j < 8; j++){ rp[b0 + j] = run; run += cnt[b0 + j]; }
  }
  __syncthreads();

  const int node0 = b << BSH;
  for (int i = t; i < BSZ; i += 256){
    int node = node0 + i;
    if (node < N) rowptr[node] = lo + rp[i];
  }

  for (int j = lo + t; j < hi; j += 256){
    u32 pvv = binned[j];
    int dl  = pvv & BMSK;
    int pos = lo + rp[dl] + atomicAdd(&cur[dl], 1);
    csr[pos] = (int)(pvv >> BSH);
  }
}

// ---------------- stamps ----------------

__global__ void k_stamp_if(const int* __restrict__ errflag, float* __restrict__ out, int nel)
{
  int f = *errflag;
  if (f == 0) return;
  float s = 500.0f + 100.0f * (float)f;
  int i = blockIdx.x * 256 + threadIdx.x;
  if (i < nel) out[i] = s;
}

__global__ void k_stamp(float* __restrict__ out, int nel, float val)
{
  int i = blockIdx.x * 256 + threadIdx.x;
  if (i < nel) out[i] = val;
}

// ---------------- layer-1 vocab table ----------------

__global__ void k_prep(const float* __restrict__ emb,
                       const float* __restrict__ ln_g, const float* __restrict__ ln_b,
                       const float* __restrict__ W1, const float* __restrict__ a_src,
                       const float* __restrict__ a_dst,
                       u16* __restrict__ xwv, float* __restrict__ alsv, float* __restrict__ aldv)
{
  __shared__ float se[32];
  __shared__ float stats[2];
  __shared__ float sxw[128];
  const int v = blockIdx.x, t = threadIdx.x;
  if (t < 32) se[t] = emb[v * 32 + t];
  __syncthreads();
  if (t == 0){
    float s1 = 0.f, s2 = 0.f;
    for (int k = 0; k < 32; k++){ s1 += se[k]; s2 += se[k] * se[k]; }
    float mu = s1 * (1.f / 32.f);
    float var = s2 * (1.f / 32.f) - mu * mu;
    stats[0] = mu; stats[1] = rsqrtf(var + LN_EPS);
  }
  __syncthreads();
  const float mu = stats[0], rs = stats[1];
  float o = 0.f;
  for (int k = 0; k < 32; k++){
    float xe = (se[k] - mu) * rs * ln_g[k] + ln_b[k];
    o += xe * W1[k * 128 + t];
  }
  sxw[t] = o;
  xwv[v * 128 + t] = f2bf(o);
  __syncthreads();
  if (t < 2){
    float ps = 0.f, pd = 0.f;
    for (int d = 0; d < 64; d++){
      float vv = sxw[t * 64 + d];
      ps += vv * a_src[t * 64 + d];
      pd += vv * a_dst[t * 64 + d];
    }
    alsv[2 * v + t] = ps;
    aldv[2 * v + t] = pd;
  }
}

// ---------------- GAT layer 1: vocab-table edition (no materialized xw) ----------------
// xw[i] == xwv[x[i]] (13KB, L1-resident); al_s[i] == alsv[x[i]] (408B).
// Only the x[src] gather (<=800KB, L2-resident) touches a large array.

__global__ __launch_bounds__(64, 8) void k_gatw1(
    const int* __restrict__ rowptr, const int* __restrict__ csr,
    const int* __restrict__ x, const int* __restrict__ iflag,
    const float* __restrict__ alsv, const float* __restrict__ aldv,
    const u16* __restrict__ xwv, const float* __restrict__ bias,
    int V, float* __restrict__ out)
{
  const int i    = blockIdx.x;
  const int lane = threadIdx.x;
  const int sub  = lane >> 4;
  const int c16  = lane & 15;
  const int enc  = *iflag;
  const int r0 = rowptr[i], deg = rowptr[i + 1] - r0, total = deg + 1;
  int vi = geti(x, i, enc); vi = min(max(vi, 0), V - 1);
  const float ad0 = aldv[2 * vi], ad1 = aldv[2 * vi + 1];

  float sum0 = 0.f, sum1 = 0.f;
  float acc[8];
  #pragma unroll
  for (int r = 0; r < 8; r++) acc[r] = 0.f;

  if (total <= 64){
    // single-pass: register-cache src vocab id + logits
    int vs = vi;
    float a0 = -3.0e38f, a1 = -3.0e38f;
    if (lane < total){
      int s = (lane < deg) ? csr[r0 + lane] : i;
      int v = geti(x, s, enc);
      vs = min(max(v, 0), V - 1);
      float2 as = *(const float2*)(alsv + 2 * vs);
      a0 = lrelu(as.x + ad0, NEG_GAT);
      a1 = lrelu(as.y + ad1, NEG_GAT);
    }
    float m0 = a0, m1 = a1;
    #pragma unroll
    for (int off = 32; off; off >>= 1){
      m0 = fmaxf(m0, __shfl_xor(m0, off));
      m1 = fmaxf(m1, __shfl_xor(m1, off));
    }
    float ex0 = 0.f, ex1 = 0.f;
    if (lane < total){ ex0 = __expf(a0 - m0); ex1 = __expf(a1 - m1); }
    sum0 = ex0; sum1 = ex1;
    int qmax = (total + 3) & ~3;
    for (int q = 0; q < qmax; q += 4){
      int   j  = q + sub;
      int   vj = __shfl(vs, j);
      float e0 = __shfl(ex0, j);
      float e1 = __shfl(ex1, j);
      float ej = (c16 < 8) ? e0 : e1;
      uint4 w = *(const uint4*)(xwv + (size_t)vj * 128 + c16 * 8);
      acc[0] += ej * bf2f(w.x & 0xffffu); acc[1] += ej * bf2f(w.x >> 16);
      acc[2] += ej * bf2f(w.y & 0xffffu); acc[3] += ej * bf2f(w.y >> 16);
      acc[4] += ej * bf2f(w.z & 0xffffu); acc[5] += ej * bf2f(w.z >> 16);
      acc[6] += ej * bf2f(w.w & 0xffffu); acc[7] += ej * bf2f(w.w >> 16);
    }
  } else {
    // fallback two-pass for deg >= 64
    float m0 = -3.0e38f, m1 = -3.0e38f;
    for (int k = lane; k < total; k += 64){
      int s = (k < deg) ? csr[r0 + k] : i;
      int v = geti(x, s, enc); v = min(max(v, 0), V - 1);
      float2 as = *(const float2*)(alsv + 2 * v);
      m0 = fmaxf(m0, lrelu(as.x + ad0, NEG_GAT));
      m1 = fmaxf(m1, lrelu(as.y + ad1, NEG_GAT));
    }
    #pragma unroll
    for (int off = 32; off; off >>= 1){
      m0 = fmaxf(m0, __shfl_xor(m0, off));
      m1 = fmaxf(m1, __shfl_xor(m1, off));
    }
    for (int base = 0; base < total; base += 64){
      int k = base + lane;
      int vs = vi; float ex0 = 0.f, ex1 = 0.f;
      if (k < total){
        int s = (k < deg) ? csr[r0 + k] : i;
        int v = geti(x, s, enc); vs = min(max(v, 0), V - 1);
        float2 as = *(const float2*)(alsv + 2 * vs);
        ex0 = __expf(lrelu(as.x + ad0, NEG_GAT) - m0);
        ex1 = __expf(lrelu(as.y + ad1, NEG_GAT) - m1);
      }
      sum0 += ex0; sum1 += ex1;
      int cnt = min(64, total - base);
      int qmax = (cnt + 3) & ~3;
      for (int q = 0; q < qmax; q += 4){
        int   j  = q + sub;
        int   vj = __shfl(vs, j);
        float e0 = __shfl(ex0, j);
        float e1 = __shfl(ex1, j);
        float ej = (c16 < 8) ? e0 : e1;
        uint4 w = *(const uint4*)(xwv + (size_t)vj * 128 + c16 * 8);
        acc[0] += ej * bf2f(w.x & 0xffffu); acc[1] += ej * bf2f(w.x >> 16);
        acc[2] += ej * bf2f(w.y & 0xffffu); acc[3] += ej * bf2f(w.y >> 16);
        acc[4] += ej * bf2f(w.z & 0xffffu); acc[5] += ej * bf2f(w.z >> 16);
        acc[6] += ej * bf2f(w.w & 0xffffu); acc[7] += ej * bf2f(w.w >> 16);
      }
    }
  }

  #pragma unroll
  for (int off = 32; off; off >>= 1){
    sum0 += __shfl_xor(sum0, off);
    sum1 += __shfl_xor(sum1, off);
  }
  #pragma unroll
  for (int r = 0; r < 8; r++){
    acc[r] += __shfl_xor(acc[r], 16);
    acc[r] += __shfl_xor(acc[r], 32);
  }

  if (sub == 0){
    float inv = 1.f / ((c16 < 8) ? sum0 : sum1);
    const float4* bp = (const float4*)(bias + c16 * 8);
    float4 b0 = bp[0], b1 = bp[1];
    float4 o0, o1;
    o0.x = lrelu(acc[0] * inv + b0.x, NEG_ACT); o0.y = lrelu(acc[1] * inv + b0.y, NEG_ACT);
    o0.z = lrelu(acc[2] * inv + b0.z, NEG_ACT); o0.w = lrelu(acc[3] * inv + b0.w, NEG_ACT);
    o1.x = lrelu(acc[4] * inv + b1.x, NEG_ACT); o1.y = lrelu(acc[5] * inv + b1.y, NEG_ACT);
    o1.z = lrelu(acc[6] * inv + b1.z, NEG_ACT); o1.w = lrelu(acc[7] * inv + b1.w, NEG_ACT);
    float* op = out + (size_t)i * 128 + c16 * 8;
    *(float4*)op       = o0;
    *(float4*)(op + 4) = o1;
  }
}

// ---------------- GAT layer 2: materialized-feature edition ----------------
// Single-pass fast path (total<=64): register-cache s/logits/exp from max phase.

__global__ __launch_bounds__(64, 8) void k_gatw2(
    const int* __restrict__ rowptr, const int* __restrict__ csr,
    const float* __restrict__ al_s, const float* __restrict__ al_d,
    const u16* __restrict__ xw, const float* __restrict__ bias,
    int apply_act, float* __restrict__ out)
{
  const int i    = blockIdx.x;
  const int lane = threadIdx.x;
  const int sub  = lane >> 4;
  const int c16  = lane & 15;
  const int r0 = rowptr[i], deg = rowptr[i + 1] - r0, total = deg + 1;
  const float2 ad = *(const float2*)(al_d + 2 * i);

  float sum0 = 0.f, sum1 = 0.f;
  float acc[8];
  #pragma unroll
  for (int r = 0; r < 8; r++) acc[r] = 0.f;

  if (total <= 64){
    int s = i;
    float a0 = -3.0e38f, a1 = -3.0e38f;
    if (lane < total){
      s = (lane < deg) ? csr[r0 + lane] : i;
      float2 as = *(const float2*)(al_s + 2 * s);
      a0 = lrelu(as.x + ad.x, NEG_GAT);
      a1 = lrelu(as.y + ad.y, NEG_GAT);
    }
    float m0 = a0, m1 = a1;
    #pragma unroll
    for (int off = 32; off; off >>= 1){
      m0 = fmaxf(m0, __shfl_xor(m0, off));
      m1 = fmaxf(m1, __shfl_xor(m1, off));
    }
    float ex0 = 0.f, ex1 = 0.f;
    if (lane < total){ ex0 = __expf(a0 - m0); ex1 = __expf(a1 - m1); }
    sum0 = ex0; sum1 = ex1;
    int qmax = (total + 3) & ~3;
    for (int q = 0; q < qmax; q += 4){
      int   j  = q + sub;
      int   sj = __shfl(s, j);
      float e0 = __shfl(ex0, j);
      float e1 = __shfl(ex1, j);
      float ej = (c16 < 8) ? e0 : e1;
      uint4 w = *(const uint4*)(xw + (size_t)sj * 128 + c16 * 8);
      acc[0] += ej * bf2f(w.x & 0xffffu); acc[1] += ej * bf2f(w.x >> 16);
      acc[2] += ej * bf2f(w.y & 0xffffu); acc[3] += ej * bf2f(w.y >> 16);
      acc[4] += ej * bf2f(w.z & 0xffffu); acc[5] += ej * bf2f(w.z >> 16);
      acc[6] += ej * bf2f(w.w & 0xffffu); acc[7] += ej * bf2f(w.w >> 16);
    }
  } else {
    float m0 = -3.0e38f, m1 = -3.0e38f;
    for (int k = lane; k < total; k += 64){
      int s = (k < deg) ? csr[r0 + k] : i;
      float2 as = *(const float2*)(al_s + 2 * s);
      m0 = fmaxf(m0, lrelu(as.x + ad.x, NEG_GAT));
      m1 = fmaxf(m1, lrelu(as.y + ad.y, NEG_GAT));
    }
    #pragma unroll
    for (int off = 32; off; off >>= 1){
      m0 = fmaxf(m0, __shfl_xor(m0, off));
      m1 = fmaxf(m1, __shfl_xor(m1, off));
    }
    for (int base = 0; base < total; base += 64){
      int k = base + lane;
      int s = i; float ex0 = 0.f, ex1 = 0.f;
      if (k < total){
        s = (k < deg) ? csr[r0 + k] : i;
        float2 as = *(const float2*)(al_s + 2 * s);
        ex0 = __expf(lrelu(as.x + ad.x, NEG_GAT) - m0);
        ex1 = __expf(lrelu(as.y + ad.y, NEG_GAT) - m1);
      }
      sum0 += ex0; sum1 += ex1;
      int cnt = min(64, total - base);
      int qmax = (cnt + 3) & ~3;
      for (int q = 0; q < qmax; q += 4){
        int   j  = q + sub;
        int   sj = __shfl(s, j);
        float e0 = __shfl(ex0, j);
        float e1 = __shfl(ex1, j);
        float ej = (c16 < 8) ? e0 : e1;
        uint4 w = *(const uint4*)(xw + (size_t)sj * 128 + c16 * 8);
        acc[0] += ej * bf2f(w.x & 0xffffu); acc[1] += ej * bf2f(w.x >> 16);
        acc[2] += ej * bf2f(w.y & 0xffffu); acc[3] += ej * bf2f(w.y >> 16);
        acc[4] += ej * bf2f(w.z & 0xffffu); acc[5] += ej * bf2f(w.z >> 16);
        acc[6] += ej * bf2f(w.w & 0xffffu); acc[7] += ej * bf2f(w.w >> 16);
      }
    }
  }

  #pragma unroll
  for (int off = 32; off; off >>= 1){
    sum0 += __shfl_xor(sum0, off);
    sum1 += __shfl_xor(sum1, off);
  }
  #pragma unroll
  for (int r = 0; r < 8; r++){
    acc[r] += __shfl_xor(acc[r], 16);
    acc[r] += __shfl_xor(acc[r], 32);
  }

  if (sub == 0){
    float inv = 1.f / ((c16 < 8) ? sum0 : sum1);
    const float4* bp = (const float4*)(bias + c16 * 8);
    float4 b0 = bp[0], b1 = bp[1];
    float4 o0, o1;
    o0.x = acc[0] * inv + b0.x; o0.y = acc[1] * inv + b0.y;
    o0.z = acc[2] * inv + b0.z; o0.w = acc[3] * inv + b0.w;
    o1.x = acc[4] * inv + b1.x; o1.y = acc[5] * inv + b1.y;
    o1.z = acc[6] * inv + b1.z; o1.w = acc[7] * inv + b1.w;
    if (apply_act){
      o0.x = lrelu(o0.x, NEG_ACT); o0.y = lrelu(o0.y, NEG_ACT);
      o0.z = lrelu(o0.z, NEG_ACT); o0.w = lrelu(o0.w, NEG_ACT);
      o1.x = lrelu(o1.x, NEG_ACT); o1.y = lrelu(o1.y, NEG_ACT);
      o1.z = lrelu(o1.z, NEG_ACT); o1.w = lrelu(o1.w, NEG_ACT);
    }
    float* op = out + (size_t)i * 128 + c16 * 8;
    *(float4*)op       = o0;
    *(float4*)(op + 4) = o1;
  }
}

// ---------------- pack weight matrix into MFMA B-fragment order ----------------

__global__ void k_packW(const float* __restrict__ W, int ncols, int ntiles,
                        u16* __restrict__ pb)
{
  const int ktile = blockIdx.x / ntiles;
  const int ntile = blockIdx.x % ntiles;
  const int lane  = threadIdx.x;
  const int n  = ntile * 16 + (lane & 15);
  const int k0 = ktile * 32 + (lane >> 4) * 8;
  u16* dst = pb + ((size_t)blockIdx.x * 64 + lane) * 8;
  #pragma unroll
  for (int j = 0; j < 8; j++)
    dst[j] = f2bf(W[(k0 + j) * ncols + n]);
}

// ---------------- layer-2 node prep: MFMA GEMM xw2 = h1 @ W2 (+ al epilogue) ----------------

__global__ __launch_bounds__(256, 2) void k_node2m(
    const float* __restrict__ h1, const u16* __restrict__ pb2,
    const float* __restrict__ a_src, const float* __restrict__ a_dst,
    int N, u16* __restrict__ xw, float* __restrict__ al_s, float* __restrict__ al_d)
{
  const int wave = threadIdx.x >> 6;
  const int lane = threadIdx.x & 63;
  const int rowbase = blockIdx.x * 64 + wave * 16;
  const int m    = lane & 15;
  const int quad = lane >> 4;

  int arow = rowbase + m; if (arow >= N) arow = N - 1;
  const float* aptr = h1 + (size_t)arow * 128 + quad * 8;

  f32x4 acc[8];
  #pragma unroll
  for (int nt = 0; nt < 8; nt++) acc[nt] = (f32x4){0.f, 0.f, 0.f, 0.f};

  #pragma unroll
  for (int kt = 0; kt < 4; kt++){
    float4 a0 = *(const float4*)(aptr + kt * 32);
    float4 a1 = *(const float4*)(aptr + kt * 32 + 4);
    bf16x8 af;
    af[0] = (short)f2bf(a0.x); af[1] = (short)f2bf(a0.y);
    af[2] = (short)f2bf(a0.z); af[3] = (short)f2bf(a0.w);
    af[4] = (short)f2bf(a1.x); af[5] = (short)f2bf(a1.y);
    af[6] = (short)f2bf(a1.z); af[7] = (short)f2bf(a1.w);
    const u16* bbase = pb2 + (((size_t)kt * 8) * 64 + lane) * 8;
    #pragma unroll
    for (int nt = 0; nt < 8; nt++){
      bf16x8 bf = *(const bf16x8*)(bbase + (size_t)nt * 64 * 8);
      acc[nt] = __builtin_amdgcn_mfma_f32_16x16x32_bf16(af, bf, acc[nt], 0, 0, 0);
    }
  }

  float asv[8], adv[8];
  #pragma unroll
  for (int nt = 0; nt < 8; nt++){
    asv[nt] = a_src[nt * 16 + m];
    adv[nt] = a_dst[nt * 16 + m];
  }
  #pragma unroll
  for (int r = 0; r < 4; r++){
    int row = rowbase + quad * 4 + r;
    bool ok = row < N;
    float s0 = 0.f, s1 = 0.f, d0 = 0.f, d1 = 0.f;
    #pragma unroll
    for (int nt = 0; nt < 8; nt++){
      float v = acc[nt][r];
      if (ok) xw[(size_t)row * 128 + nt * 16 + m] = f2bf(v);
      if (nt < 4){ s0 += v * asv[nt]; d0 += v * adv[nt]; }
      else       { s1 += v * asv[nt]; d1 += v * adv[nt]; }
    }
    #pragma unroll
    for (int off = 1; off < 16; off <<= 1){
      s0 += __shfl_xor(s0, off); s1 += __shfl_xor(s1, off);
      d0 += __shfl_xor(d0, off); d1 += __shfl_xor(d1, off);
    }
    if (ok && m == 0){
      al_s[2 * row] = s0; al_s[2 * row + 1] = s1;
      al_d[2 * row] = d0; al_d[2 * row + 1] = d1;
    }
  }
}

// ---------------- gate: MFMA GEMM t = h @ gw1, fused lrelu + dot(gw2) ----------------

__global__ __launch_bounds__(256, 2) void k_gatem(
    const float* __restrict__ h, const u16* __restrict__ pbg,
    const float* __restrict__ gb1, const float* __restrict__ gw2,
    const float* __restrict__ gb2, int N, float* __restrict__ gate)
{
  const int wave = threadIdx.x >> 6;
  const int lane = threadIdx.x & 63;
  const int rowbase = blockIdx.x * 64 + wave * 16;
  const int m    = lane & 15;
  const int quad = lane >> 4;

  int arow = rowbase + m; if (arow >= N) arow = N - 1;
  const float* aptr = h + (size_t)arow * 128 + quad * 8;

  f32x4 acc[4];
  #pragma unroll
  for (int nt = 0; nt < 4; nt++) acc[nt] = (f32x4){0.f, 0.f, 0.f, 0.f};

  #pragma unroll
  for (int kt = 0; kt < 4; kt++){
    float4 a0 = *(const float4*)(aptr + kt * 32);
    float4 a1 = *(const float4*)(aptr + kt * 32 + 4);
    bf16x8 af;
    af[0] = (short)f2bf(a0.x); af[1] = (short)f2bf(a0.y);
    af[2] = (short)f2bf(a0.z); af[3] = (short)f2bf(a0.w);
    af[4] = (short)f2bf(a1.x); af[5] = (short)f2bf(a1.y);
    af[6] = (short)f2bf(a1.z); af[7] = (short)f2bf(a1.w);
    const u16* bbase = pbg + (((size_t)kt * 4) * 64 + lane) * 8;
    #pragma unroll
    for (int nt = 0; nt < 4; nt++){
      bf16x8 bf = *(const bf16x8*)(bbase + (size_t)nt * 64 * 8);
      acc[nt] = __builtin_amdgcn_mfma_f32_16x16x32_bf16(af, bf, acc[nt], 0, 0, 0);
    }
  }

  float gbv[4], g2v[4];
  #pragma unroll
  for (int nt = 0; nt < 4; nt++){
    gbv[nt] = gb1[nt * 16 + m];
    g2v[nt] = gw2[nt * 16 + m];
  }
  const float g2b = gb2[0];
  #pragma unroll
  for (int r = 0; r < 4; r++){
    int row = rowbase + quad * 4 + r;
    float q = 0.f;
    #pragma unroll
    for (int nt = 0; nt < 4; nt++)
      q += lrelu(acc[nt][r] + gbv[nt], NEG_ACT) * g2v[nt];
    #pragma unroll
    for (int off = 1; off < 16; off <<= 1) q += __shfl_xor(q, off);
    if (row < N && m == 0) gate[row] = q + g2b;
  }
}

// ---------------- per-graph softmax pooling ----------------

__global__ void k_graphsw(const int* __restrict__ batch, const int* __restrict__ iflag,
                          const float* __restrict__ gate,
                          const float* __restrict__ h, float* __restrict__ zout, int N)
{
  __shared__ int   range[2];
  __shared__ float red[4];
  const int g = blockIdx.x, t = threadIdx.x;
  const int wave = t >> 6;
  if (t == 0){
    const int enc = *iflag;
    int lo = 0, hi = N;
    while (lo < hi){ int mid = (lo + hi) >> 1; if (geti(batch, mid, enc) < g) lo = mid + 1; else hi = mid; }
    range[0] = lo;
    hi = N;
    while (lo < hi){ int mid = (lo + hi) >> 1; if (geti(batch, mid, enc) < g + 1) lo = mid + 1; else hi = mid; }
    range[1] = lo;
  }
  __syncthreads();
  const int st = range[0], en = range[1];

  float m = -3.0e38f;
  for (int k = st + t; k < en; k += 128) m = fmaxf(m, gate[k]);
  #pragma unroll
  for (int off = 32; off; off >>= 1) m = fmaxf(m, __shfl_xor(m, off));
  if ((t & 63) == 0) red[wave] = m;
  __syncthreads();
  m = fmaxf(red[0], red[1]);

  float s = 0.f;
  for (int k = st + t; k < en; k += 128) s += __expf(gate[k] - m);
  #pragma unroll
  for (int off = 32; off; off >>= 1) s += __shfl_xor(s, off);
  if ((t & 63) == 0) red[2 + wave] = s;
  __syncthreads();
  s = red[2] + red[3];

  float z = 0.f;
  const float inv = 1.f / s;
  for (int k = st; k < en; k++){
    float wk = __expf(gate[k] - m) * inv;
    z += wk * h[(size_t)k * 128 + t];
  }
  zout[(size_t)g * 128 + t] = z;
}

// ---------------- launch ----------------

extern "C" void kernel_launch(void* const* d_in, const int* in_sizes, int n_in,
                              void* d_out, int out_size, void* d_ws, size_t ws_size,
                              hipStream_t stream)
{
  const int* x      = (const int*)d_in[0];
  const int* ei     = (const int*)d_in[1];
  const int* batch  = (const int*)d_in[2];

  const int N = in_sizes[0];
  const int E = in_sizes[1] / 2;
  const int V = in_sizes[3] / 32;
  const int G = out_size / 128 - N;

  char* p = (char*)d_ws;
  auto alloc = [&](size_t bytes) -> char* {
    char* r = p; p += (bytes + 255) & ~(size_t)255; return r;
  };
  int*   multi  = (int*)  alloc((size_t)N * 4);       // counts -> cursor -> gate
  int*   rowptr = (int*)  alloc((size_t)(N + 1) * 4);
  int*   csr    = (int*)  alloc((size_t)E * 4);
  int*   bsums  = (int*)  alloc(4096);
  int*   boffs  = (int*)  alloc(4096);
  int*   flags  = (int*)  alloc(256);
  int*   fflag  = flags;
  int*   iflag  = flags + 1;
  int*   errflg = flags + 2;
  float* al_s   = (float*)alloc((size_t)N * 2 * 4);
  float* al_d   = (float*)alloc((size_t)N * 2 * 4);
  u16*   xw     = (u16*)  alloc((size_t)N * 128 * 2);
  u16*   xwv    = (u16*)  alloc((size_t)V * 128 * 2);
  float* alsv   = (float*)alloc((size_t)V * 2 * 4);
  float* aldv   = (float*)alloc((size_t)V * 2 * 4);
  u16*   pb2    = (u16*)  alloc((size_t)128 * 128 * 2);  // W2 packed
  u16*   pbg    = (u16*)  alloc((size_t)128 * 64 * 2);   // gw1 packed

  const int nbuck = (N + BSZ - 1) >> BSH;
  int*   bcnt   = (int*)  alloc((size_t)(MAXB) * 4);
  int*   boff   = (int*)  alloc((size_t)(MAXB + 1) * 4);
  int*   gcur   = (int*)  alloc((size_t)(MAXB) * 4);
  u32*   binned = (u32*)  alloc((size_t)E * 4);

  CvtParams cp;
  float* fpar[NPARAM];
  int maxn = 0;
  for (int pi = 0; pi < NPARAM; pi++){
    int n = in_sizes[3 + pi];
    fpar[pi] = (float*)alloc((size_t)n * 4);
    cp.src[pi] = d_in[3 + pi];
    cp.dst[pi] = fpar[pi];
    cp.n[pi]   = n;
    if (n > maxn) maxn = n;
  }
  const size_t needed = (size_t)(p - (char*)d_ws);

  const float* emb    = fpar[0];
  const float* ln_g   = fpar[1];
  const float* ln_b   = fpar[2];
  const float* W1     = fpar[3];
  const float* a_src1 = fpar[4];
  const float* a_dst1 = fpar[5];
  const float* b1     = fpar[6];
  const float* W2     = fpar[7];
  const float* a_src2 = fpar[8];
  const float* a_dst2 = fpar[9];
  const float* b2     = fpar[10];
  const float* gw1    = fpar[11];
  const float* gb1    = fpar[12];
  const float* gw2    = fpar[13];
  const float* gb2    = fpar[14];
  (void)n_in;

  int ob = (out_size + 255) / 256;
  if (ws_size < needed){
    k_stamp<<<ob, 256, 0, stream>>>((float*)d_out, out_size, 9999.0f);
    return;
  }

  int*   counts = multi;
  int*   cursor = multi;
  float* gate   = (float*)multi;
  float* hbuf   = (float*)d_out;
  float* zbuf   = (float*)d_out + (size_t)N * 128;

  k_detect<<<1, 64, 0, stream>>>((const u32*)d_in[4], ei, fflag, iflag, errflg);
  dim3 cgrid((maxn + 255) / 256, NPARAM);
  k_convert<<<cgrid, 256, 0, stream>>>(cp, fflag);

  int eb = (E + 255) / 256;
  int nb = (N + 1023) / 1024;
  int nb256 = (N + 255) / 256;

  k_check_sorted<<<nb256, 256, 0, stream>>>(batch, iflag, N, errflg);
  k_check_x<<<nb256, 256, 0, stream>>>(x, iflag, N, V, errflg);
  k_check_edges<<<eb, 256, 0, stream>>>(ei, iflag, E, N, errflg);

  if (nbuck <= MAXB){
    hipMemsetAsync(bcnt, 0, (size_t)nbuck * 4, stream);
    k_bhist<<<256, 256, 0, stream>>>(ei, iflag, bcnt, E, N, nbuck);
    k_bscan<<<1, 64, 0, stream>>>(bcnt, boff, gcur, rowptr, nbuck, N, E);
    k_bbin<<<(E + BINB - 1) / BINB, BTH, 0, stream>>>(ei, iflag, gcur, binned, E, N, nbuck);
    k_bcsr<<<nbuck, 256, 0, stream>>>(binned, boff, rowptr, csr, N, nbuck);
  } else {
    hipMemsetAsync(counts, 0, (size_t)N * 4, stream);
    hipMemsetAsync(csr, 0xFF, (size_t)E * 4, stream);
    k_hist<<<eb, 256, 0, stream>>>(ei, iflag, counts, E, N);
    k_scanA<<<nb, 1024, 0, stream>>>(counts, rowptr, bsums, N);
    k_scanB<<<1, 128, 0, stream>>>(bsums, boffs, nb);
    k_scanC<<<nb, 1024, 0, stream>>>(rowptr, boffs, cursor, N, E);
    k_scatter<<<eb, 256, 0, stream>>>(ei, iflag, cursor, csr, E, N);
    k_check_rows<<<nb256, 256, 0, stream>>>(rowptr, cursor, N, errflg);
    k_check_csr<<<eb, 256, 0, stream>>>(csr, E, N, errflg);
  }

  // pack weights for MFMA
  k_packW<<<32, 64, 0, stream>>>(W2, 128, 8, pb2);
  k_packW<<<16, 64, 0, stream>>>(gw1, 64, 4, pbg);

  // layer 1: vocab tables, no materialized xw / al_s / al_d
  k_prep<<<V, 128, 0, stream>>>(emb, ln_g, ln_b, W1, a_src1, a_dst1, xwv, alsv, aldv);
  k_gatw1<<<N, 64, 0, stream>>>(rowptr, csr, x, iflag, alsv, aldv, xwv, b1, V, hbuf);

  const int gblk = (N + 63) / 64;
  k_node2m<<<gblk, 256, 0, stream>>>(hbuf, pb2, a_src2, a_dst2, N, xw, al_s, al_d);

  k_gatw2<<<N, 64, 0, stream>>>(rowptr, csr, al_s, al_d, xw, b2, 0, hbuf);

  k_gatem<<<gblk, 256, 0, stream>>>(hbuf, pbg, gb1, gw2, gb2, N, gate);
  k_graphsw<<<G, 128, 0, stream>>>(batch, iflag, gate, hbuf, zbuf, N);

  k_stamp_if<<<ob, 256, 0, stream>>>(errflg, (float*)d_out, out_size);
}

// Round 3
// 381.541 us; speedup vs baseline: 1.5253x; 1.0443x over previous
//
#include <hip/hip_runtime.h>
#include <hip/hip_bf16.h>
#include <stdint.h>

typedef unsigned short u16;
typedef unsigned int   u32;
typedef __attribute__((ext_vector_type(8))) short bf16x8;
typedef __attribute__((ext_vector_type(4))) float f32x4;

#define NEG_GAT 0.2f
#define NEG_ACT 0.05f
#define LN_EPS  1e-5f
#define NPARAM  15

__device__ __forceinline__ float bf2f(u32 bits16){
  union { u32 u; float f; } v; v.u = bits16 << 16; return v.f;
}
__device__ __forceinline__ u16 f2bf(float f){
  union { float f; u32 u; } v; v.f = f;
  u32 u = v.u;
  u32 r = (u + 0x7fffu + ((u >> 16) & 1u)) >> 16;
  return (u16)r;
}
// valid for slope in (0,1): max(x, s*x) == leaky_relu(x, s)
__device__ __forceinline__ float lrelu(float x, float s){ return fmaxf(x, s * x); }

__device__ __forceinline__ int geti(const int* __restrict__ p, int i, int enc){
  return p[enc ? (2 * i) : i];
}

// ---------------- dtype detection ----------------

struct CvtParams {
  const void* src[NPARAM];
  float*      dst[NPARAM];
  int         n[NPARAM];
};

__global__ void k_detect(const u32* __restrict__ ln_g_raw, const int* __restrict__ ei_raw,
                         int* __restrict__ fflag, int* __restrict__ iflag,
                         int* __restrict__ errflag)
{
  if (threadIdx.x == 0){
    *fflag = (ln_g_raw[0] == 0x3F800000u) ? 0 : 1;
    int zeros = 0;
    for (int j = 0; j < 64; j++) if (ei_raw[2 * j + 1] == 0) zeros++;
    *iflag = (zeros >= 60) ? 1 : 0;
    *errflag = 0;
  }
}

__global__ void k_convert(CvtParams P, const int* __restrict__ flag)
{
  const int pi  = blockIdx.y;
  const int idx = blockIdx.x * 256 + threadIdx.x;
  if (idx >= P.n[pi]) return;
  if (*flag == 0) P.dst[pi][idx] = ((const float*)P.src[pi])[idx];
  else            P.dst[pi][idx] = bf2f(((const u16*)P.src[pi])[idx]);
}

// ---------------- validators ----------------

__global__ void k_check_sorted(const int* __restrict__ batch, const int* __restrict__ iflag,
                               int n, int* __restrict__ errflag)
{
  int i = blockIdx.x * 256 + threadIdx.x;
  if (i < n - 1){
    if (geti(batch, i, *iflag) > geti(batch, i + 1, *iflag)) atomicOr(errflag, 8);
  }
}

__global__ void k_check_x(const int* __restrict__ x, const int* __restrict__ iflag,
                          int n, int V, int* __restrict__ errflag)
{
  int i = blockIdx.x * 256 + threadIdx.x;
  if (i < n){
    int v = geti(x, i, *iflag);
    if ((unsigned)v >= (unsigned)V) atomicOr(errflag, 16);
  }
}

__global__ void k_check_edges(const int* __restrict__ ei, const int* __restrict__ iflag,
                              int E, int n, int* __restrict__ errflag)
{
  int e = blockIdx.x * 256 + threadIdx.x;
  if (e < E){
    int enc = *iflag;
    int s = geti(ei, e, enc);
    int d = geti(ei, E + e, enc);
    if ((unsigned)s >= (unsigned)n || (unsigned)d >= (unsigned)n) atomicOr(errflag, 32);
  }
}

// ---------------- CSR build: legacy path (fallback for huge N) ----------------

__global__ void k_hist(const int* __restrict__ ei, const int* __restrict__ iflag,
                       int* __restrict__ counts, int E, int n)
{
  int e = blockIdx.x * 256 + threadIdx.x;
  if (e < E){
    int d = geti(ei, E + e, *iflag);
    d = min(max(d, 0), n - 1);
    atomicAdd(&counts[d], 1);
  }
}

__global__ void k_scanA(const int* __restrict__ counts, int* __restrict__ rowptr,
                        int* __restrict__ bsums, int n)
{
  __shared__ int sd[1024];
  int tid = threadIdx.x;
  int gid = blockIdx.x * 1024 + tid;
  int v = (gid < n) ? counts[gid] : 0;
  sd[tid] = v;
  __syncthreads();
  for (int off = 1; off < 1024; off <<= 1){
    int t = 0;
    if (tid >= off) t = sd[tid - off];
    __syncthreads();
    if (tid >= off) sd[tid] += t;
    __syncthreads();
  }
  if (gid < n) rowptr[gid] = sd[tid] - v;
  if (tid == 1023) bsums[blockIdx.x] = sd[1023];
}

__global__ void k_scanB(const int* __restrict__ bsums, int* __restrict__ boffs, int nb)
{
  __shared__ int sd[128];
  int tid = threadIdx.x;
  int v = (tid < nb) ? bsums[tid] : 0;
  sd[tid] = v;
  __syncthreads();
  for (int off = 1; off < 128; off <<= 1){
    int t = 0;
    if (tid >= off) t = sd[tid - off];
    __syncthreads();
    if (tid >= off) sd[tid] += t;
    __syncthreads();
  }
  if (tid < nb) boffs[tid] = sd[tid] - v;
}

__global__ void k_scanC(int* __restrict__ rowptr, const int* __restrict__ boffs,
                        int* __restrict__ cursor, int n, int Etot)
{
  int gid = blockIdx.x * 1024 + threadIdx.x;
  if (gid < n){
    int v = rowptr[gid] + boffs[blockIdx.x];
    rowptr[gid] = v;
    cursor[gid] = v;
  }
  if (gid == 0) rowptr[n] = Etot;
}

__global__ void k_scatter(const int* __restrict__ ei, const int* __restrict__ iflag,
                          int* __restrict__ cursor, int* __restrict__ csr, int E, int n)
{
  int e = blockIdx.x * 256 + threadIdx.x;
  if (e < E){
    int enc = *iflag;
    int s = geti(ei, e, enc);
    int d = geti(ei, E + e, enc);
    d = min(max(d, 0), n - 1);
    int pos = atomicAdd(&cursor[d], 1);
    csr[pos] = s;
  }
}

__global__ void k_check_rows(const int* __restrict__ rowptr, const int* __restrict__ cursor,
                             int n, int* __restrict__ errflag)
{
  int i = blockIdx.x * 256 + threadIdx.x;
  if (i < n){
    if (cursor[i] != rowptr[i + 1]) atomicOr(errflag, 1);
    if (i == 0 && rowptr[0] != 0)   atomicOr(errflag, 4);
  }
}

__global__ void k_check_csr(const int* __restrict__ csr, int E, int n, int* __restrict__ errflag)
{
  int e = blockIdx.x * 256 + threadIdx.x;
  if (e < E && (unsigned)csr[e] >= (unsigned)n) atomicOr(errflag, 2);
}

// ---------------- CSR build: bucketed path ----------------

#define BSH   9
#define BSZ   512
#define BMSK  511
#define MAXB  2048
#define BINB  8192
#define BTH   512

__global__ void k_bhist(const int* __restrict__ ei, const int* __restrict__ iflag,
                        int* __restrict__ bcnt, int E, int N, int nbuck)
{
  __shared__ int h[MAXB];
  const int t = threadIdx.x;
  for (int i = t; i < nbuck; i += 256) h[i] = 0;
  __syncthreads();
  const int enc = *iflag;
  for (int e = blockIdx.x * 256 + t; e < E; e += gridDim.x * 256){
    int d = geti(ei, E + e, enc);
    d = min(max(d, 0), N - 1);
    atomicAdd(&h[d >> BSH], 1);
  }
  __syncthreads();
  for (int i = t; i < nbuck; i += 256){
    int c = h[i];
    if (c) atomicAdd(&bcnt[i], c);
  }
}

__global__ void k_bscan(const int* __restrict__ bcnt, int* __restrict__ boff,
                        int* __restrict__ gcur, int* __restrict__ rowptr,
                        int nbuck, int N, int E)
{
  __shared__ int sd[MAXB];
  const int lane = threadIdx.x;
  for (int i = lane; i < nbuck; i += 64) sd[i] = bcnt[i];
  __syncthreads();
  const int L = (nbuck + 63) >> 6;
  const int b0 = lane * L;
  int sum = 0;
  for (int j = 0; j < L; j++){ int idx = b0 + j; if (idx < nbuck) sum += sd[idx]; }
  int excl = sum;
  for (int off = 1; off < 64; off <<= 1){
    int x = __shfl_up(excl, off);
    if (lane >= off) excl += x;
  }
  excl -= sum;
  int run = excl;
  for (int j = 0; j < L; j++){
    int idx = b0 + j;
    if (idx < nbuck){ boff[idx] = run; gcur[idx] = run; run += sd[idx]; }
  }
  if (lane == 0){ boff[nbuck] = E; rowptr[N] = E; }
}

__global__ __launch_bounds__(BTH) void k_bbin(
    const int* __restrict__ ei, const int* __restrict__ iflag,
    int* __restrict__ gcur, u32* __restrict__ binned,
    int E, int N, int nbuck)
{
  __shared__ u32 stage[BINB];
  __shared__ u16 sbk[BINB];
  __shared__ int hist[MAXB];
  __shared__ int base[MAXB];
  __shared__ int gpos[MAXB];
  const int t   = threadIdx.x;
  const int e0  = blockIdx.x * BINB;
  const int cnt = min(BINB, E - e0);
  const int enc = *iflag;

  for (int i = t; i < nbuck; i += BTH) hist[i] = 0;
  __syncthreads();

  u32 pv[16]; int bk[16]; int rk[16];
  #pragma unroll
  for (int k = 0; k < 16; k++){
    bk[k] = -1;
    int lo = k * BTH + t;
    if (lo < cnt){
      int e = e0 + lo;
      int s = geti(ei, e, enc);
      int d = geti(ei, E + e, enc);
      s = min(max(s, 0), N - 1);
      d = min(max(d, 0), N - 1);
      int b = d >> BSH;
      pv[k] = ((u32)s << BSH) | (u32)(d & BMSK);
      bk[k] = b;
      rk[k] = atomicAdd(&hist[b], 1);
    }
  }
  __syncthreads();

  if (t < 64){
    const int L = (nbuck + 63) >> 6;
    const int b0 = t * L;
    int sum = 0;
    for (int j = 0; j < L; j++){ int idx = b0 + j; if (idx < nbuck) sum += hist[idx]; }
    int excl = sum;
    for (int off = 1; off < 64; off <<= 1){
      int x = __shfl_up(excl, off);
      if (t >= off) excl += x;
    }
    excl -= sum;
    int run = excl;
    for (int j = 0; j < L; j++){
      int idx = b0 + j;
      if (idx < nbuck){ base[idx] = run; run += hist[idx]; }
    }
  }
  __syncthreads();

  for (int i = t; i < nbuck; i += BTH){
    int c = hist[i];
    gpos[i] = c ? atomicAdd(&gcur[i], c) : 0;
  }
  __syncthreads();

  #pragma unroll
  for (int k = 0; k < 16; k++){
    if (bk[k] >= 0){
      int slot = base[bk[k]] + rk[k];
      stage[slot] = pv[k];
      sbk[slot]   = (u16)bk[k];
    }
  }
  __syncthreads();

  for (int j = t; j < cnt; j += BTH){
    int b = sbk[j];
    binned[gpos[b] + (j - base[b])] = stage[j];
  }
}

__global__ __launch_bounds__(256) void k_bcsr(
    const u32* __restrict__ binned, const int* __restrict__ boff,
    int* __restrict__ rowptr, int* __restrict__ csr, int N, int nbuck)
{
  __shared__ int cnt[BSZ];
  __shared__ int rp[BSZ];
  __shared__ int cur[BSZ];
  const int b = blockIdx.x;
  const int t = threadIdx.x;
  const int lo = boff[b], hi = boff[b + 1];

  for (int i = t; i < BSZ; i += 256){ cnt[i] = 0; cur[i] = 0; }
  __syncthreads();

  for (int j = lo + t; j < hi; j += 256)
    atomicAdd(&cnt[binned[j] & BMSK], 1);
  __syncthreads();

  if (t < 64){
    const int b0 = t * 8;
    int sum = 0;
    #pragma unroll
    for (int j = 0; j < 8; j++) sum += cnt[b0 + j];
    int excl = sum;
    for (int off = 1; off < 64; off <<= 1){
      int x = __shfl_up(excl, off);
      if (t >= off) excl += x;
    }
    excl -= sum;
    int run = excl;
    #pragma unroll
    for (int j = 0; j < 8; j++){ rp[b0 + j] = run; run += cnt[b0 + j]; }
  }
  __syncthreads();

  const int node0 = b << BSH;
  for (int i = t; i < BSZ; i += 256){
    int node = node0 + i;
    if (node < N) rowptr[node] = lo + rp[i];
  }

  for (int j = lo + t; j < hi; j += 256){
    u32 pvv = binned[j];
    int dl  = pvv & BMSK;
    int pos = lo + rp[dl] + atomicAdd(&cur[dl], 1);
    csr[pos] = (int)(pvv >> BSH);
  }
}

// ---------------- stamps ----------------

__global__ void k_stamp_if(const int* __restrict__ errflag, float* __restrict__ out, int nel)
{
  int f = *errflag;
  if (f == 0) return;
  float s = 500.0f + 100.0f * (float)f;
  int i = blockIdx.x * 256 + threadIdx.x;
  if (i < nel) out[i] = s;
}

__global__ void k_stamp(float* __restrict__ out, int nel, float val)
{
  int i = blockIdx.x * 256 + threadIdx.x;
  if (i < nel) out[i] = val;
}

// ---------------- layer-1 vocab table ----------------

__global__ void k_prep(const float* __restrict__ emb,
                       const float* __restrict__ ln_g, const float* __restrict__ ln_b,
                       const float* __restrict__ W1, const float* __restrict__ a_src,
                       const float* __restrict__ a_dst,
                       u16* __restrict__ xwv, float* __restrict__ alsv, float* __restrict__ aldv)
{
  __shared__ float se[32];
  __shared__ float stats[2];
  __shared__ float sxw[128];
  const int v = blockIdx.x, t = threadIdx.x;
  if (t < 32) se[t] = emb[v * 32 + t];
  __syncthreads();
  if (t == 0){
    float s1 = 0.f, s2 = 0.f;
    for (int k = 0; k < 32; k++){ s1 += se[k]; s2 += se[k] * se[k]; }
    float mu = s1 * (1.f / 32.f);
    float var = s2 * (1.f / 32.f) - mu * mu;
    stats[0] = mu; stats[1] = rsqrtf(var + LN_EPS);
  }
  __syncthreads();
  const float mu = stats[0], rs = stats[1];
  float o = 0.f;
  for (int k = 0; k < 32; k++){
    float xe = (se[k] - mu) * rs * ln_g[k] + ln_b[k];
    o += xe * W1[k * 128 + t];
  }
  sxw[t] = o;
  xwv[v * 128 + t] = f2bf(o);
  __syncthreads();
  if (t < 2){
    float ps = 0.f, pd = 0.f;
    for (int d = 0; d < 64; d++){
      float vv = sxw[t * 64 + d];
      ps += vv * a_src[t * 64 + d];
      pd += vv * a_dst[t * 64 + d];
    }
    alsv[2 * v + t] = ps;
    aldv[2 * v + t] = pd;
  }
}

// ---------------- GAT layer 1: LDS vocab table, multi-wave grid-stride ----------------
// smem layout: [ xwv : V*128 u16 | alsv : V float2 | aldv : V float2 | stage : 4*64 float4 ]

__global__ __launch_bounds__(256, 4) void k_gatw1(
    const int* __restrict__ rowptr, const int* __restrict__ csr,
    const int* __restrict__ x, const int* __restrict__ iflag,
    const float* __restrict__ alsv, const float* __restrict__ aldv,
    const u16* __restrict__ xwv, const float* __restrict__ bias,
    int N, int V, float* __restrict__ out)
{
  extern __shared__ char smem[];
  u16*    sxwv  = (u16*)smem;
  float2* sals  = (float2*)(smem + (size_t)V * 256);
  float2* sald  = sals + V;
  float4* sedge = (float4*)(smem + (size_t)V * 256 + (size_t)V * 16);

  const int tid = threadIdx.x;
  const int enc = *iflag;

  {
    const uint4* gx = (const uint4*)xwv;
    uint4* lx = (uint4*)sxwv;
    for (int idx = tid; idx < V * 16; idx += 256) lx[idx] = gx[idx];
    const float2* ga = (const float2*)alsv;
    const float2* gd = (const float2*)aldv;
    for (int idx = tid; idx < V; idx += 256){ sals[idx] = ga[idx]; sald[idx] = gd[idx]; }
  }
  __syncthreads();

  const int wave = tid >> 6;
  const int lane = tid & 63;
  const int sub  = lane >> 4;
  const int c16  = lane & 15;
  float4* mst = sedge + wave * 64;

  for (int i = blockIdx.x * 4 + wave; i < N; i += gridDim.x * 4){
    const int r0 = rowptr[i], deg = rowptr[i + 1] - r0, total = deg + 1;
    int vi = geti(x, i, enc); vi = min(max(vi, 0), V - 1);
    const float2 ad = sald[vi];

    float sum0 = 0.f, sum1 = 0.f;
    float acc[8];
    #pragma unroll
    for (int r = 0; r < 8; r++) acc[r] = 0.f;

    if (total <= 64){
      int vs = vi;
      float a0 = -3.0e38f, a1 = -3.0e38f;
      if (lane < total){
        int s = (lane < deg) ? csr[r0 + lane] : i;
        int v = geti(x, s, enc);
        vs = min(max(v, 0), V - 1);
        float2 as = sals[vs];
        a0 = lrelu(as.x + ad.x, NEG_GAT);
        a1 = lrelu(as.y + ad.y, NEG_GAT);
      }
      float m0 = a0, m1 = a1;
      #pragma unroll
      for (int off = 32; off; off >>= 1){
        m0 = fmaxf(m0, __shfl_xor(m0, off));
        m1 = fmaxf(m1, __shfl_xor(m1, off));
      }
      float ex0 = 0.f, ex1 = 0.f;
      if (lane < total){ ex0 = __expf(a0 - m0); ex1 = __expf(a1 - m1); }
      sum0 = ex0; sum1 = ex1;
      mst[lane] = make_float4(__int_as_float(vs), ex0, ex1, 0.f);
      int qmax = (total + 3) & ~3;
      for (int q = 0; q < qmax; q += 4){
        float4 md = mst[q + sub];
        int   vj = __float_as_int(md.x);
        float ej = (c16 < 8) ? md.y : md.z;
        uint4 w = *(const uint4*)(sxwv + vj * 128 + c16 * 8);
        acc[0] += ej * bf2f(w.x & 0xffffu); acc[1] += ej * bf2f(w.x >> 16);
        acc[2] += ej * bf2f(w.y & 0xffffu); acc[3] += ej * bf2f(w.y >> 16);
        acc[4] += ej * bf2f(w.z & 0xffffu); acc[5] += ej * bf2f(w.z >> 16);
        acc[6] += ej * bf2f(w.w & 0xffffu); acc[7] += ej * bf2f(w.w >> 16);
      }
    } else {
      float m0 = -3.0e38f, m1 = -3.0e38f;
      for (int k = lane; k < total; k += 64){
        int s = (k < deg) ? csr[r0 + k] : i;
        int v = geti(x, s, enc); v = min(max(v, 0), V - 1);
        float2 as = sals[v];
        m0 = fmaxf(m0, lrelu(as.x + ad.x, NEG_GAT));
        m1 = fmaxf(m1, lrelu(as.y + ad.y, NEG_GAT));
      }
      #pragma unroll
      for (int off = 32; off; off >>= 1){
        m0 = fmaxf(m0, __shfl_xor(m0, off));
        m1 = fmaxf(m1, __shfl_xor(m1, off));
      }
      for (int base = 0; base < total; base += 64){
        int k = base + lane;
        int vs = vi; float ex0 = 0.f, ex1 = 0.f;
        if (k < total){
          int s = (k < deg) ? csr[r0 + k] : i;
          int v = geti(x, s, enc); vs = min(max(v, 0), V - 1);
          float2 as = sals[vs];
          ex0 = __expf(lrelu(as.x + ad.x, NEG_GAT) - m0);
          ex1 = __expf(lrelu(as.y + ad.y, NEG_GAT) - m1);
        }
        sum0 += ex0; sum1 += ex1;
        mst[lane] = make_float4(__int_as_float(vs), ex0, ex1, 0.f);
        int cnt = min(64, total - base);
        int qmax = (cnt + 3) & ~3;
        for (int q = 0; q < qmax; q += 4){
          float4 md = mst[q + sub];
          int   vj = __float_as_int(md.x);
          float ej = (c16 < 8) ? md.y : md.z;
          uint4 w = *(const uint4*)(sxwv + vj * 128 + c16 * 8);
          acc[0] += ej * bf2f(w.x & 0xffffu); acc[1] += ej * bf2f(w.x >> 16);
          acc[2] += ej * bf2f(w.y & 0xffffu); acc[3] += ej * bf2f(w.y >> 16);
          acc[4] += ej * bf2f(w.z & 0xffffu); acc[5] += ej * bf2f(w.z >> 16);
          acc[6] += ej * bf2f(w.w & 0xffffu); acc[7] += ej * bf2f(w.w >> 16);
        }
      }
    }

    #pragma unroll
    for (int off = 32; off; off >>= 1){
      sum0 += __shfl_xor(sum0, off);
      sum1 += __shfl_xor(sum1, off);
    }
    #pragma unroll
    for (int r = 0; r < 8; r++){
      acc[r] += __shfl_xor(acc[r], 16);
      acc[r] += __shfl_xor(acc[r], 32);
    }

    if (sub == 0){
      float inv = 1.f / ((c16 < 8) ? sum0 : sum1);
      const float4* bp = (const float4*)(bias + c16 * 8);
      float4 b0 = bp[0], b1 = bp[1];
      float4 o0, o1;
      o0.x = lrelu(acc[0] * inv + b0.x, NEG_ACT); o0.y = lrelu(acc[1] * inv + b0.y, NEG_ACT);
      o0.z = lrelu(acc[2] * inv + b0.z, NEG_ACT); o0.w = lrelu(acc[3] * inv + b0.w, NEG_ACT);
      o1.x = lrelu(acc[4] * inv + b1.x, NEG_ACT); o1.y = lrelu(acc[5] * inv + b1.y, NEG_ACT);
      o1.z = lrelu(acc[6] * inv + b1.z, NEG_ACT); o1.w = lrelu(acc[7] * inv + b1.w, NEG_ACT);
      float* op = out + (size_t)i * 128 + c16 * 8;
      *(float4*)op       = o0;
      *(float4*)(op + 4) = o1;
    }
  }
}

// fallback (large V): previous single-wave global-table version
__global__ __launch_bounds__(64, 8) void k_gatw1g(
    const int* __restrict__ rowptr, const int* __restrict__ csr,
    const int* __restrict__ x, const int* __restrict__ iflag,
    const float* __restrict__ alsv, const float* __restrict__ aldv,
    const u16* __restrict__ xwv, const float* __restrict__ bias,
    int V, float* __restrict__ out)
{
  const int i    = blockIdx.x;
  const int lane = threadIdx.x;
  const int sub  = lane >> 4;
  const int c16  = lane & 15;
  const int enc  = *iflag;
  const int r0 = rowptr[i], deg = rowptr[i + 1] - r0, total = deg + 1;
  int vi = geti(x, i, enc); vi = min(max(vi, 0), V - 1);
  const float ad0 = aldv[2 * vi], ad1 = aldv[2 * vi + 1];

  float sum0 = 0.f, sum1 = 0.f;
  float acc[8];
  #pragma unroll
  for (int r = 0; r < 8; r++) acc[r] = 0.f;

  float m0 = -3.0e38f, m1 = -3.0e38f;
  for (int k = lane; k < total; k += 64){
    int s = (k < deg) ? csr[r0 + k] : i;
    int v = geti(x, s, enc); v = min(max(v, 0), V - 1);
    float2 as = *(const float2*)(alsv + 2 * v);
    m0 = fmaxf(m0, lrelu(as.x + ad0, NEG_GAT));
    m1 = fmaxf(m1, lrelu(as.y + ad1, NEG_GAT));
  }
  #pragma unroll
  for (int off = 32; off; off >>= 1){
    m0 = fmaxf(m0, __shfl_xor(m0, off));
    m1 = fmaxf(m1, __shfl_xor(m1, off));
  }
  for (int base = 0; base < total; base += 64){
    int k = base + lane;
    int vs = vi; float ex0 = 0.f, ex1 = 0.f;
    if (k < total){
      int s = (k < deg) ? csr[r0 + k] : i;
      int v = geti(x, s, enc); vs = min(max(v, 0), V - 1);
      float2 as = *(const float2*)(alsv + 2 * vs);
      ex0 = __expf(lrelu(as.x + ad0, NEG_GAT) - m0);
      ex1 = __expf(lrelu(as.y + ad1, NEG_GAT) - m1);
    }
    sum0 += ex0; sum1 += ex1;
    int cnt = min(64, total - base);
    int qmax = (cnt + 3) & ~3;
    for (int q = 0; q < qmax; q += 4){
      int   j  = q + sub;
      int   vj = __shfl(vs, j);
      float e0 = __shfl(ex0, j);
      float e1 = __shfl(ex1, j);
      float ej = (c16 < 8) ? e0 : e1;
      uint4 w = *(const uint4*)(xwv + (size_t)vj * 128 + c16 * 8);
      acc[0] += ej * bf2f(w.x & 0xffffu); acc[1] += ej * bf2f(w.x >> 16);
      acc[2] += ej * bf2f(w.y & 0xffffu); acc[3] += ej * bf2f(w.y >> 16);
      acc[4] += ej * bf2f(w.z & 0xffffu); acc[5] += ej * bf2f(w.z >> 16);
      acc[6] += ej * bf2f(w.w & 0xffffu); acc[7] += ej * bf2f(w.w >> 16);
    }
  }

  #pragma unroll
  for (int off = 32; off; off >>= 1){
    sum0 += __shfl_xor(sum0, off);
    sum1 += __shfl_xor(sum1, off);
  }
  #pragma unroll
  for (int r = 0; r < 8; r++){
    acc[r] += __shfl_xor(acc[r], 16);
    acc[r] += __shfl_xor(acc[r], 32);
  }

  if (sub == 0){
    float inv = 1.f / ((c16 < 8) ? sum0 : sum1);
    const float4* bp = (const float4*)(bias + c16 * 8);
    float4 b0 = bp[0], b1 = bp[1];
    float4 o0, o1;
    o0.x = lrelu(acc[0] * inv + b0.x, NEG_ACT); o0.y = lrelu(acc[1] * inv + b0.y, NEG_ACT);
    o0.z = lrelu(acc[2] * inv + b0.z, NEG_ACT); o0.w = lrelu(acc[3] * inv + b0.w, NEG_ACT);
    o1.x = lrelu(acc[4] * inv + b1.x, NEG_ACT); o1.y = lrelu(acc[5] * inv + b1.y, NEG_ACT);
    o1.z = lrelu(acc[6] * inv + b1.z, NEG_ACT); o1.w = lrelu(acc[7] * inv + b1.w, NEG_ACT);
    float* op = out + (size_t)i * 128 + c16 * 8;
    *(float4*)op       = o0;
    *(float4*)(op + 4) = o1;
  }
}

// ---------------- GAT layer 2: multi-wave, LDS metadata, pipelined row gather ----------------

__global__ __launch_bounds__(256, 4) void k_gatw2(
    const int* __restrict__ rowptr, const int* __restrict__ csr,
    const float* __restrict__ al_s, const float* __restrict__ al_d,
    const u16* __restrict__ xw, const float* __restrict__ bias,
    int apply_act, int N, float* __restrict__ out)
{
  __shared__ float4 sedge[4][64];
  const int tid  = threadIdx.x;
  const int wave = tid >> 6;
  const int lane = tid & 63;
  const int sub  = lane >> 4;
  const int c16  = lane & 15;
  float4* mst = sedge[wave];

  for (int i = blockIdx.x * 4 + wave; i < N; i += gridDim.x * 4){
    const int r0 = rowptr[i], deg = rowptr[i + 1] - r0, total = deg + 1;
    const float2 ad = *(const float2*)(al_d + 2 * i);

    float sum0 = 0.f, sum1 = 0.f;
    float acc[8];
    #pragma unroll
    for (int r = 0; r < 8; r++) acc[r] = 0.f;

    if (total <= 64){
      int s = i;
      float a0 = -3.0e38f, a1 = -3.0e38f;
      if (lane < total){
        s = (lane < deg) ? csr[r0 + lane] : i;
        float2 as = *(const float2*)(al_s + 2 * s);
        a0 = lrelu(as.x + ad.x, NEG_GAT);
        a1 = lrelu(as.y + ad.y, NEG_GAT);
      }
      float m0 = a0, m1 = a1;
      #pragma unroll
      for (int off = 32; off; off >>= 1){
        m0 = fmaxf(m0, __shfl_xor(m0, off));
        m1 = fmaxf(m1, __shfl_xor(m1, off));
      }
      float ex0 = 0.f, ex1 = 0.f;
      if (lane < total){ ex0 = __expf(a0 - m0); ex1 = __expf(a1 - m1); }
      sum0 = ex0; sum1 = ex1;
      mst[lane] = make_float4(__int_as_float(s), ex0, ex1, 0.f);
      int qmax = (total + 3) & ~3;
      // 2-deep pipelined gather
      float4 md = mst[sub];
      uint4  w  = *(const uint4*)(xw + (size_t)__float_as_int(md.x) * 128 + c16 * 8);
      for (int q = 0; q < qmax; q += 4){
        float ej = (c16 < 8) ? md.y : md.z;
        uint4 wc = w;
        if (q + 4 < qmax){
          md = mst[q + 4 + sub];
          w  = *(const uint4*)(xw + (size_t)__float_as_int(md.x) * 128 + c16 * 8);
        }
        acc[0] += ej * bf2f(wc.x & 0xffffu); acc[1] += ej * bf2f(wc.x >> 16);
        acc[2] += ej * bf2f(wc.y & 0xffffu); acc[3] += ej * bf2f(wc.y >> 16);
        acc[4] += ej * bf2f(wc.z & 0xffffu); acc[5] += ej * bf2f(wc.z >> 16);
        acc[6] += ej * bf2f(wc.w & 0xffffu); acc[7] += ej * bf2f(wc.w >> 16);
      }
    } else {
      float m0 = -3.0e38f, m1 = -3.0e38f;
      for (int k = lane; k < total; k += 64){
        int s = (k < deg) ? csr[r0 + k] : i;
        float2 as = *(const float2*)(al_s + 2 * s);
        m0 = fmaxf(m0, lrelu(as.x + ad.x, NEG_GAT));
        m1 = fmaxf(m1, lrelu(as.y + ad.y, NEG_GAT));
      }
      #pragma unroll
      for (int off = 32; off; off >>= 1){
        m0 = fmaxf(m0, __shfl_xor(m0, off));
        m1 = fmaxf(m1, __shfl_xor(m1, off));
      }
      for (int base = 0; base < total; base += 64){
        int k = base + lane;
        int s = i; float ex0 = 0.f, ex1 = 0.f;
        if (k < total){
          s = (k < deg) ? csr[r0 + k] : i;
          float2 as = *(const float2*)(al_s + 2 * s);
          ex0 = __expf(lrelu(as.x + ad.x, NEG_GAT) - m0);
          ex1 = __expf(lrelu(as.y + ad.y, NEG_GAT) - m1);
        }
        sum0 += ex0; sum1 += ex1;
        mst[lane] = make_float4(__int_as_float(s), ex0, ex1, 0.f);
        int cnt = min(64, total - base);
        int qmax = (cnt + 3) & ~3;
        for (int q = 0; q < qmax; q += 4){
          float4 md = mst[q + sub];
          float ej = (c16 < 8) ? md.y : md.z;
          uint4 w = *(const uint4*)(xw + (size_t)__float_as_int(md.x) * 128 + c16 * 8);
          acc[0] += ej * bf2f(w.x & 0xffffu); acc[1] += ej * bf2f(w.x >> 16);
          acc[2] += ej * bf2f(w.y & 0xffffu); acc[3] += ej * bf2f(w.y >> 16);
          acc[4] += ej * bf2f(w.z & 0xffffu); acc[5] += ej * bf2f(w.z >> 16);
          acc[6] += ej * bf2f(w.w & 0xffffu); acc[7] += ej * bf2f(w.w >> 16);
        }
      }
    }

    #pragma unroll
    for (int off = 32; off; off >>= 1){
      sum0 += __shfl_xor(sum0, off);
      sum1 += __shfl_xor(sum1, off);
    }
    #pragma unroll
    for (int r = 0; r < 8; r++){
      acc[r] += __shfl_xor(acc[r], 16);
      acc[r] += __shfl_xor(acc[r], 32);
    }

    if (sub == 0){
      float inv = 1.f / ((c16 < 8) ? sum0 : sum1);
      const float4* bp = (const float4*)(bias + c16 * 8);
      float4 b0 = bp[0], b1 = bp[1];
      float4 o0, o1;
      o0.x = acc[0] * inv + b0.x; o0.y = acc[1] * inv + b0.y;
      o0.z = acc[2] * inv + b0.z; o0.w = acc[3] * inv + b0.w;
      o1.x = acc[4] * inv + b1.x; o1.y = acc[5] * inv + b1.y;
      o1.z = acc[6] * inv + b1.z; o1.w = acc[7] * inv + b1.w;
      if (apply_act){
        o0.x = lrelu(o0.x, NEG_ACT); o0.y = lrelu(o0.y, NEG_ACT);
        o0.z = lrelu(o0.z, NEG_ACT); o0.w = lrelu(o0.w, NEG_ACT);
        o1.x = lrelu(o1.x, NEG_ACT); o1.y = lrelu(o1.y, NEG_ACT);
        o1.z = lrelu(o1.z, NEG_ACT); o1.w = lrelu(o1.w, NEG_ACT);
      }
      float* op = out + (size_t)i * 128 + c16 * 8;
      *(float4*)op       = o0;
      *(float4*)(op + 4) = o1;
    }
  }
}

// ---------------- pack weight matrix into MFMA B-fragment order ----------------

__global__ void k_packW(const float* __restrict__ W, int ncols, int ntiles,
                        u16* __restrict__ pb)
{
  const int ktile = blockIdx.x / ntiles;
  const int ntile = blockIdx.x % ntiles;
  const int lane  = threadIdx.x;
  const int n  = ntile * 16 + (lane & 15);
  const int k0 = ktile * 32 + (lane >> 4) * 8;
  u16* dst = pb + ((size_t)blockIdx.x * 64 + lane) * 8;
  #pragma unroll
  for (int j = 0; j < 8; j++)
    dst[j] = f2bf(W[(k0 + j) * ncols + n]);
}

// ---------------- layer-2 node prep: MFMA GEMM xw2 = h1 @ W2 (+ al epilogue) ----------------

__global__ __launch_bounds__(256, 2) void k_node2m(
    const float* __restrict__ h1, const u16* __restrict__ pb2,
    const float* __restrict__ a_src, const float* __restrict__ a_dst,
    int N, u16* __restrict__ xw, float* __restrict__ al_s, float* __restrict__ al_d)
{
  const int wave = threadIdx.x >> 6;
  const int lane = threadIdx.x & 63;
  const int rowbase = blockIdx.x * 64 + wave * 16;
  const int m    = lane & 15;
  const int quad = lane >> 4;

  int arow = rowbase + m; if (arow >= N) arow = N - 1;
  const float* aptr = h1 + (size_t)arow * 128 + quad * 8;

  f32x4 acc[8];
  #pragma unroll
  for (int nt = 0; nt < 8; nt++) acc[nt] = (f32x4){0.f, 0.f, 0.f, 0.f};

  #pragma unroll
  for (int kt = 0; kt < 4; kt++){
    float4 a0 = *(const float4*)(aptr + kt * 32);
    float4 a1 = *(const float4*)(aptr + kt * 32 + 4);
    bf16x8 af;
    af[0] = (short)f2bf(a0.x); af[1] = (short)f2bf(a0.y);
    af[2] = (short)f2bf(a0.z); af[3] = (short)f2bf(a0.w);
    af[4] = (short)f2bf(a1.x); af[5] = (short)f2bf(a1.y);
    af[6] = (short)f2bf(a1.z); af[7] = (short)f2bf(a1.w);
    const u16* bbase = pb2 + (((size_t)kt * 8) * 64 + lane) * 8;
    #pragma unroll
    for (int nt = 0; nt < 8; nt++){
      bf16x8 bf = *(const bf16x8*)(bbase + (size_t)nt * 64 * 8);
      acc[nt] = __builtin_amdgcn_mfma_f32_16x16x32_bf16(af, bf, acc[nt], 0, 0, 0);
    }
  }

  float asv[8], adv[8];
  #pragma unroll
  for (int nt = 0; nt < 8; nt++){
    asv[nt] = a_src[nt * 16 + m];
    adv[nt] = a_dst[nt * 16 + m];
  }
  #pragma unroll
  for (int r = 0; r < 4; r++){
    int row = rowbase + quad * 4 + r;
    bool ok = row < N;
    float s0 = 0.f, s1 = 0.f, d0 = 0.f, d1 = 0.f;
    #pragma unroll
    for (int nt = 0; nt < 8; nt++){
      float v = acc[nt][r];
      if (ok) xw[(size_t)row * 128 + nt * 16 + m] = f2bf(v);
      if (nt < 4){ s0 += v * asv[nt]; d0 += v * adv[nt]; }
      else       { s1 += v * asv[nt]; d1 += v * adv[nt]; }
    }
    #pragma unroll
    for (int off = 1; off < 16; off <<= 1){
      s0 += __shfl_xor(s0, off); s1 += __shfl_xor(s1, off);
      d0 += __shfl_xor(d0, off); d1 += __shfl_xor(d1, off);
    }
    if (ok && m == 0){
      al_s[2 * row] = s0; al_s[2 * row + 1] = s1;
      al_d[2 * row] = d0; al_d[2 * row + 1] = d1;
    }
  }
}

// ---------------- gate: MFMA GEMM t = h @ gw1, fused lrelu + dot(gw2) ----------------

__global__ __launch_bounds__(256, 2) void k_gatem(
    const float* __restrict__ h, const u16* __restrict__ pbg,
    const float* __restrict__ gb1, const float* __restrict__ gw2,
    const float* __restrict__ gb2, int N, float* __restrict__ gate)
{
  const int wave = threadIdx.x >> 6;
  const int lane = threadIdx.x & 63;
  const int rowbase = blockIdx.x * 64 + wave * 16;
  const int m    = lane & 15;
  const int quad = lane >> 4;

  int arow = rowbase + m; if (arow >= N) arow = N - 1;
  const float* aptr = h + (size_t)arow * 128 + quad * 8;

  f32x4 acc[4];
  #pragma unroll
  for (int nt = 0; nt < 4; nt++) acc[nt] = (f32x4){0.f, 0.f, 0.f, 0.f};

  #pragma unroll
  for (int kt = 0; kt < 4; kt++){
    float4 a0 = *(const float4*)(aptr + kt * 32);
    float4 a1 = *(const float4*)(aptr + kt * 32 + 4);
    bf16x8 af;
    af[0] = (short)f2bf(a0.x); af[1] = (short)f2bf(a0.y);
    af[2] = (short)f2bf(a0.z); af[3] = (short)f2bf(a0.w);
    af[4] = (short)f2bf(a1.x); af[5] = (short)f2bf(a1.y);
    af[6] = (short)f2bf(a1.z); af[7] = (short)f2bf(a1.w);
    const u16* bbase = pbg + (((size_t)kt * 4) * 64 + lane) * 8;
    #pragma unroll
    for (int nt = 0; nt < 4; nt++){
      bf16x8 bf = *(const bf16x8*)(bbase + (size_t)nt * 64 * 8);
      acc[nt] = __builtin_amdgcn_mfma_f32_16x16x32_bf16(af, bf, acc[nt], 0, 0, 0);
    }
  }

  float gbv[4], g2v[4];
  #pragma unroll
  for (int nt = 0; nt < 4; nt++){
    gbv[nt] = gb1[nt * 16 + m];
    g2v[nt] = gw2[nt * 16 + m];
  }
  const float g2b = gb2[0];
  #pragma unroll
  for (int r = 0; r < 4; r++){
    int row = rowbase + quad * 4 + r;
    float q = 0.f;
    #pragma unroll
    for (int nt = 0; nt < 4; nt++)
      q += lrelu(acc[nt][r] + gbv[nt], NEG_ACT) * g2v[nt];
    #pragma unroll
    for (int off = 1; off < 16; off <<= 1) q += __shfl_xor(q, off);
    if (row < N && m == 0) gate[row] = q + g2b;
  }
}

// ---------------- per-graph softmax pooling (256 threads, 2-way k-parallel) ----------------

__global__ __launch_bounds__(256) void k_graphsw(
    const int* __restrict__ batch, const int* __restrict__ iflag,
    const float* __restrict__ gate,
    const float* __restrict__ h, float* __restrict__ zout, int N)
{
  __shared__ int   range[2];
  __shared__ float red[8];
  __shared__ float sz[128];
  const int g = blockIdx.x, t = threadIdx.x;
  const int wave = t >> 6, lane = t & 63;
  if (t == 0){
    const int enc = *iflag;
    int lo = 0, hi = N;
    while (lo < hi){ int mid = (lo + hi) >> 1; if (geti(batch, mid, enc) < g) lo = mid + 1; else hi = mid; }
    range[0] = lo;
    hi = N;
    while (lo < hi){ int mid = (lo + hi) >> 1; if (geti(batch, mid, enc) < g + 1) lo = mid + 1; else hi = mid; }
    range[1] = lo;
  }
  __syncthreads();
  const int st = range[0], en = range[1];

  float m = -3.0e38f;
  for (int k = st + t; k < en; k += 256) m = fmaxf(m, gate[k]);
  #pragma unroll
  for (int off = 32; off; off >>= 1) m = fmaxf(m, __shfl_xor(m, off));
  if (lane == 0) red[wave] = m;
  __syncthreads();
  m = fmaxf(fmaxf(red[0], red[1]), fmaxf(red[2], red[3]));

  float s = 0.f;
  for (int k = st + t; k < en; k += 256) s += __expf(gate[k] - m);
  #pragma unroll
  for (int off = 32; off; off >>= 1) s += __shfl_xor(s, off);
  if (lane == 0) red[4 + wave] = s;
  __syncthreads();
  s = (red[4] + red[5]) + (red[6] + red[7]);

  const float inv = 1.f / s;
  const int half = t >> 7, t2 = t & 127;
  float z = 0.f;
  for (int k = st + half; k < en; k += 2){
    float wk = __expf(gate[k] - m) * inv;
    z += wk * h[(size_t)k * 128 + t2];
  }
  if (half == 1) sz[t2] = z;
  __syncthreads();
  if (half == 0) zout[(size_t)g * 128 + t2] = z + sz[t2];
}

// ---------------- launch ----------------

extern "C" void kernel_launch(void* const* d_in, const int* in_sizes, int n_in,
                              void* d_out, int out_size, void* d_ws, size_t ws_size,
                              hipStream_t stream)
{
  const int* x      = (const int*)d_in[0];
  const int* ei     = (const int*)d_in[1];
  const int* batch  = (const int*)d_in[2];

  const int N = in_sizes[0];
  const int E = in_sizes[1] / 2;
  const int V = in_sizes[3] / 32;
  const int G = out_size / 128 - N;

  char* p = (char*)d_ws;
  auto alloc = [&](size_t bytes) -> char* {
    char* r = p; p += (bytes + 255) & ~(size_t)255; return r;
  };
  int*   multi  = (int*)  alloc((size_t)N * 4);       // counts -> cursor -> gate
  int*   rowptr = (int*)  alloc((size_t)(N + 1) * 4);
  int*   csr    = (int*)  alloc((size_t)E * 4);
  int*   bsums  = (int*)  alloc(4096);
  int*   boffs  = (int*)  alloc(4096);
  int*   flags  = (int*)  alloc(256);
  int*   fflag  = flags;
  int*   iflag  = flags + 1;
  int*   errflg = flags + 2;
  float* al_s   = (float*)alloc((size_t)N * 2 * 4);
  float* al_d   = (float*)alloc((size_t)N * 2 * 4);
  u16*   xw     = (u16*)  alloc((size_t)N * 128 * 2);
  u16*   xwv    = (u16*)  alloc((size_t)V * 128 * 2);
  float* alsv   = (float*)alloc((size_t)V * 2 * 4);
  float* aldv   = (float*)alloc((size_t)V * 2 * 4);
  u16*   pb2    = (u16*)  alloc((size_t)128 * 128 * 2);  // W2 packed
  u16*   pbg    = (u16*)  alloc((size_t)128 * 64 * 2);   // gw1 packed

  const int nbuck = (N + BSZ - 1) >> BSH;
  int*   bcnt   = (int*)  alloc((size_t)(MAXB) * 4);
  int*   boff   = (int*)  alloc((size_t)(MAXB + 1) * 4);
  int*   gcur   = (int*)  alloc((size_t)(MAXB) * 4);
  u32*   binned = (u32*)  alloc((size_t)E * 4);

  CvtParams cp;
  float* fpar[NPARAM];
  int maxn = 0;
  for (int pi = 0; pi < NPARAM; pi++){
    int n = in_sizes[3 + pi];
    fpar[pi] = (float*)alloc((size_t)n * 4);
    cp.src[pi] = d_in[3 + pi];
    cp.dst[pi] = fpar[pi];
    cp.n[pi]   = n;
    if (n > maxn) maxn = n;
  }
  const size_t needed = (size_t)(p - (char*)d_ws);

  const float* emb    = fpar[0];
  const float* ln_g   = fpar[1];
  const float* ln_b   = fpar[2];
  const float* W1     = fpar[3];
  const float* a_src1 = fpar[4];
  const float* a_dst1 = fpar[5];
  const float* b1     = fpar[6];
  const float* W2     = fpar[7];
  const float* a_src2 = fpar[8];
  const float* a_dst2 = fpar[9];
  const float* b2     = fpar[10];
  const float* gw1    = fpar[11];
  const float* gb1    = fpar[12];
  const float* gw2    = fpar[13];
  const float* gb2    = fpar[14];
  (void)n_in;

  int ob = (out_size + 255) / 256;
  if (ws_size < needed){
    k_stamp<<<ob, 256, 0, stream>>>((float*)d_out, out_size, 9999.0f);
    return;
  }

  int*   counts = multi;
  int*   cursor = multi;
  float* gate   = (float*)multi;
  float* hbuf   = (float*)d_out;
  float* zbuf   = (float*)d_out + (size_t)N * 128;

  k_detect<<<1, 64, 0, stream>>>((const u32*)d_in[4], ei, fflag, iflag, errflg);
  dim3 cgrid((maxn + 255) / 256, NPARAM);
  k_convert<<<cgrid, 256, 0, stream>>>(cp, fflag);

  int eb = (E + 255) / 256;
  int nb = (N + 1023) / 1024;
  int nb256 = (N + 255) / 256;

  k_check_sorted<<<nb256, 256, 0, stream>>>(batch, iflag, N, errflg);
  k_check_x<<<nb256, 256, 0, stream>>>(x, iflag, N, V, errflg);
  k_check_edges<<<eb, 256, 0, stream>>>(ei, iflag, E, N, errflg);

  if (nbuck <= MAXB){
    hipMemsetAsync(bcnt, 0, (size_t)nbuck * 4, stream);
    k_bhist<<<256, 256, 0, stream>>>(ei, iflag, bcnt, E, N, nbuck);
    k_bscan<<<1, 64, 0, stream>>>(bcnt, boff, gcur, rowptr, nbuck, N, E);
    k_bbin<<<(E + BINB - 1) / BINB, BTH, 0, stream>>>(ei, iflag, gcur, binned, E, N, nbuck);
    k_bcsr<<<nbuck, 256, 0, stream>>>(binned, boff, rowptr, csr, N, nbuck);
  } else {
    hipMemsetAsync(counts, 0, (size_t)N * 4, stream);
    hipMemsetAsync(csr, 0xFF, (size_t)E * 4, stream);
    k_hist<<<eb, 256, 0, stream>>>(ei, iflag, counts, E, N);
    k_scanA<<<nb, 1024, 0, stream>>>(counts, rowptr, bsums, N);
    k_scanB<<<1, 128, 0, stream>>>(bsums, boffs, nb);
    k_scanC<<<nb, 1024, 0, stream>>>(rowptr, boffs, cursor, N, E);
    k_scatter<<<eb, 256, 0, stream>>>(ei, iflag, cursor, csr, E, N);
    k_check_rows<<<nb256, 256, 0, stream>>>(rowptr, cursor, N, errflg);
    k_check_csr<<<eb, 256, 0, stream>>>(csr, E, N, errflg);
  }

  // pack weights for MFMA
  k_packW<<<32, 64, 0, stream>>>(W2, 128, 8, pb2);
  k_packW<<<16, 64, 0, stream>>>(gw1, 64, 4, pbg);

  // layer 1: vocab tables in LDS
  k_prep<<<V, 128, 0, stream>>>(emb, ln_g, ln_b, W1, a_src1, a_dst1, xwv, alsv, aldv);

  const int gwb = min(2048, (N + 3) / 4);
  const size_t smem1 = (size_t)V * 272 + 4096;
  if (smem1 <= 64 * 1024){
    k_gatw1<<<gwb, 256, smem1, stream>>>(rowptr, csr, x, iflag, alsv, aldv, xwv, b1, N, V, hbuf);
  } else {
    k_gatw1g<<<N, 64, 0, stream>>>(rowptr, csr, x, iflag, alsv, aldv, xwv, b1, V, hbuf);
  }

  const int gblk = (N + 63) / 64;
  k_node2m<<<gblk, 256, 0, stream>>>(hbuf, pb2, a_src2, a_dst2, N, xw, al_s, al_d);

  k_gatw2<<<gwb, 256, 0, stream>>>(rowptr, csr, al_s, al_d, xw, b2, 0, N, hbuf);

  k_gatem<<<gblk, 256, 0, stream>>>(hbuf, pbg, gb1, gw2, gb2, N, gate);
  k_graphsw<<<G, 256, 0, stream>>>(batch, iflag, gate, hbuf, zbuf, N);

  k_stamp_if<<<ob, 256, 0, stream>>>(errflg, (float*)d_out, out_size);
}

// Round 6
// 375.706 us; speedup vs baseline: 1.5490x; 1.0155x over previous
//
#include <hip/hip_runtime.h>
#include <hip/hip_bf16.h>
#include <stdint.h>

typedef unsigned short u16;
typedef unsigned int   u32;
typedef __attribute__((ext_vector_type(8))) short bf16x8;
typedef __attribute__((ext_vector_type(4))) float f32x4;

#define NEG_GAT 0.2f
#define NEG_ACT 0.05f
#define LN_EPS  1e-5f
#define NPARAM  15

__device__ __forceinline__ float bf2f(u32 bits16){
  union { u32 u; float f; } v; v.u = bits16 << 16; return v.f;
}
__device__ __forceinline__ u16 f2bf(float f){
  union { float f; u32 u; } v; v.f = f;
  u32 u = v.u;
  u32 r = (u + 0x7fffu + ((u >> 16) & 1u)) >> 16;
  return (u16)r;
}
// valid for slope in (0,1): max(x, s*x) == leaky_relu(x, s)
__device__ __forceinline__ float lrelu(float x, float s){ return fmaxf(x, s * x); }

__device__ __forceinline__ int geti(const int* __restrict__ p, int i, int enc){
  return p[enc ? (2 * i) : i];
}

// ---------------- dtype detection + zero scratch ----------------

struct CvtParams {
  const void* src[NPARAM];
  float*      dst[NPARAM];
  int         n[NPARAM];
};

#define MAXB  2048

__global__ void k_detect(const u32* __restrict__ ln_g_raw, const int* __restrict__ ei_raw,
                         int* __restrict__ flags, int* __restrict__ bcnt)
{
  const int t = threadIdx.x;
  for (int i = t; i < MAXB; i += 256) bcnt[i] = 0;
  if (t == 0){
    flags[0] = (ln_g_raw[0] == 0x3F800000u) ? 0 : 1;   // fflag
    int zeros = 0;
    for (int j = 0; j < 64; j++) if (ei_raw[2 * j + 1] == 0) zeros++;
    flags[1] = (zeros >= 60) ? 1 : 0;                  // iflag
    flags[2] = 0;                                      // errflag
    flags[3] = 0;                                      // (unused)
  }
}

__global__ void k_convert(CvtParams P, const int* __restrict__ flag)
{
  const int pi  = blockIdx.y;
  const int idx = blockIdx.x * 256 + threadIdx.x;
  if (idx >= P.n[pi]) return;
  if (*flag == 0) P.dst[pi][idx] = ((const float*)P.src[pi])[idx];
  else            P.dst[pi][idx] = bf2f(((const u16*)P.src[pi])[idx]);
}

// ---------------- validators ----------------

__global__ void k_checks(const int* __restrict__ batch, const int* __restrict__ x,
                         const int* __restrict__ iflag,
                         int n, int V, int* __restrict__ errflag)
{
  int i = blockIdx.x * 256 + threadIdx.x;
  const int enc = *iflag;
  if (i < n){
    int v = geti(x, i, enc);
    if ((unsigned)v >= (unsigned)V) atomicOr(errflag, 16);
    if (i < n - 1 && geti(batch, i, enc) > geti(batch, i + 1, enc)) atomicOr(errflag, 8);
  }
}

__global__ void k_check_edges(const int* __restrict__ ei, const int* __restrict__ iflag,
                              int E, int n, int* __restrict__ errflag)
{
  int e = blockIdx.x * 256 + threadIdx.x;
  if (e < E){
    int enc = *iflag;
    int s = geti(ei, e, enc);
    int d = geti(ei, E + e, enc);
    if ((unsigned)s >= (unsigned)n || (unsigned)d >= (unsigned)n) atomicOr(errflag, 32);
  }
}

// ---------------- CSR build: legacy path (fallback for huge N) ----------------

__global__ void k_hist(const int* __restrict__ ei, const int* __restrict__ iflag,
                       int* __restrict__ counts, int E, int n)
{
  int e = blockIdx.x * 256 + threadIdx.x;
  if (e < E){
    int d = geti(ei, E + e, *iflag);
    d = min(max(d, 0), n - 1);
    atomicAdd(&counts[d], 1);
  }
}

__global__ void k_scanA(const int* __restrict__ counts, int* __restrict__ rowptr,
                        int* __restrict__ bsums, int n)
{
  __shared__ int sd[1024];
  int tid = threadIdx.x;
  int gid = blockIdx.x * 1024 + tid;
  int v = (gid < n) ? counts[gid] : 0;
  sd[tid] = v;
  __syncthreads();
  for (int off = 1; off < 1024; off <<= 1){
    int t = 0;
    if (tid >= off) t = sd[tid - off];
    __syncthreads();
    if (tid >= off) sd[tid] += t;
    __syncthreads();
  }
  if (gid < n) rowptr[gid] = sd[tid] - v;
  if (tid == 1023) bsums[blockIdx.x] = sd[1023];
}

__global__ void k_scanB(const int* __restrict__ bsums, int* __restrict__ boffs, int nb)
{
  __shared__ int sd[128];
  int tid = threadIdx.x;
  int v = (tid < nb) ? bsums[tid] : 0;
  sd[tid] = v;
  __syncthreads();
  for (int off = 1; off < 128; off <<= 1){
    int t = 0;
    if (tid >= off) t = sd[tid - off];
    __syncthreads();
    if (tid >= off) sd[tid] += t;
    __syncthreads();
  }
  if (tid < nb) boffs[tid] = sd[tid] - v;
}

__global__ void k_scanC(int* __restrict__ rowptr, const int* __restrict__ boffs,
                        int* __restrict__ cursor, int n, int Etot)
{
  int gid = blockIdx.x * 1024 + threadIdx.x;
  if (gid < n){
    int v = rowptr[gid] + boffs[blockIdx.x];
    rowptr[gid] = v;
    cursor[gid] = v;
  }
  if (gid == 0) rowptr[n] = Etot;
}

__global__ void k_scatter(const int* __restrict__ ei, const int* __restrict__ iflag,
                          int* __restrict__ cursor, int* __restrict__ csr, int E, int n)
{
  int e = blockIdx.x * 256 + threadIdx.x;
  if (e < E){
    int enc = *iflag;
    int s = geti(ei, e, enc);
    int d = geti(ei, E + e, enc);
    d = min(max(d, 0), n - 1);
    int pos = atomicAdd(&cursor[d], 1);
    csr[pos] = s;
  }
}

__global__ void k_check_rows(const int* __restrict__ rowptr, const int* __restrict__ cursor,
                             int n, int* __restrict__ errflag)
{
  int i = blockIdx.x * 256 + threadIdx.x;
  if (i < n){
    if (cursor[i] != rowptr[i + 1]) atomicOr(errflag, 1);
    if (i == 0 && rowptr[0] != 0)   atomicOr(errflag, 4);
  }
}

__global__ void k_check_csr(const int* __restrict__ csr, int E, int n, int* __restrict__ errflag)
{
  int e = blockIdx.x * 256 + threadIdx.x;
  if (e < E && (unsigned)csr[e] >= (unsigned)n) atomicOr(errflag, 2);
}

// ---------------- CSR build: bucketed path (round-3 proven) ----------------

#define BSH   9
#define BSZ   512
#define BMSK  511
#define BINB  8192
#define BTH   512

__global__ void k_bhist(const int* __restrict__ ei, const int* __restrict__ iflag,
                        int* __restrict__ bcnt, int E, int N, int nbuck)
{
  __shared__ int h[MAXB];
  const int t = threadIdx.x;
  for (int i = t; i < nbuck; i += 256) h[i] = 0;
  __syncthreads();
  const int enc = *iflag;
  for (int e = blockIdx.x * 256 + t; e < E; e += gridDim.x * 256){
    int d = geti(ei, E + e, enc);
    d = min(max(d, 0), N - 1);
    atomicAdd(&h[d >> BSH], 1);
  }
  __syncthreads();
  for (int i = t; i < nbuck; i += 256){
    int c = h[i];
    if (c) atomicAdd(&bcnt[i], c);
  }
}

__global__ void k_bscan(const int* __restrict__ bcnt, int* __restrict__ boff,
                        int* __restrict__ gcur, int* __restrict__ rowptr,
                        int nbuck, int N, int E)
{
  __shared__ int sd[MAXB];
  const int lane = threadIdx.x;
  for (int i = lane; i < nbuck; i += 64) sd[i] = bcnt[i];
  __syncthreads();
  const int L = (nbuck + 63) >> 6;
  const int b0 = lane * L;
  int sum = 0;
  for (int j = 0; j < L; j++){ int idx = b0 + j; if (idx < nbuck) sum += sd[idx]; }
  int excl = sum;
  for (int off = 1; off < 64; off <<= 1){
    int x = __shfl_up(excl, off);
    if (lane >= off) excl += x;
  }
  excl -= sum;
  int run = excl;
  for (int j = 0; j < L; j++){
    int idx = b0 + j;
    if (idx < nbuck){ boff[idx] = run; gcur[idx] = run; run += sd[idx]; }
  }
  if (lane == 0){ boff[nbuck] = E; rowptr[N] = E; }
}

__global__ __launch_bounds__(BTH) void k_bbin(
    const int* __restrict__ ei, const int* __restrict__ iflag,
    int* __restrict__ gcur, u32* __restrict__ binned,
    int E, int N, int nbuck, int* __restrict__ errflag)
{
  __shared__ u32 stage[BINB];
  __shared__ u16 sbk[BINB];
  __shared__ int hist[MAXB];
  __shared__ int base[MAXB];
  __shared__ int gpos[MAXB];
  const int t   = threadIdx.x;
  const int e0  = blockIdx.x * BINB;
  const int cnt = min(BINB, E - e0);
  const int enc = *iflag;

  for (int i = t; i < nbuck; i += BTH) hist[i] = 0;
  __syncthreads();

  u32 pv[16]; int bk[16]; int rk[16];
  int bad = 0;
  #pragma unroll
  for (int k = 0; k < 16; k++){
    bk[k] = -1;
    int lo = k * BTH + t;
    if (lo < cnt){
      int e = e0 + lo;
      int s = geti(ei, e, enc);
      int d = geti(ei, E + e, enc);
      if ((unsigned)s >= (unsigned)N || (unsigned)d >= (unsigned)N) bad = 1;
      s = min(max(s, 0), N - 1);
      d = min(max(d, 0), N - 1);
      int b = d >> BSH;
      pv[k] = ((u32)s << BSH) | (u32)(d & BMSK);
      bk[k] = b;
      rk[k] = atomicAdd(&hist[b], 1);
    }
  }
  if (bad) atomicOr(errflag, 32);
  __syncthreads();

  if (t < 64){
    const int L = (nbuck + 63) >> 6;
    const int b0 = t * L;
    int sum = 0;
    for (int j = 0; j < L; j++){ int idx = b0 + j; if (idx < nbuck) sum += hist[idx]; }
    int excl = sum;
    for (int off = 1; off < 64; off <<= 1){
      int x = __shfl_up(excl, off);
      if (t >= off) excl += x;
    }
    excl -= sum;
    int run = excl;
    for (int j = 0; j < L; j++){
      int idx = b0 + j;
      if (idx < nbuck){ base[idx] = run; run += hist[idx]; }
    }
  }
  __syncthreads();

  for (int i = t; i < nbuck; i += BTH){
    int c = hist[i];
    gpos[i] = c ? atomicAdd(&gcur[i], c) : 0;
  }
  __syncthreads();

  #pragma unroll
  for (int k = 0; k < 16; k++){
    if (bk[k] >= 0){
      int slot = base[bk[k]] + rk[k];
      stage[slot] = pv[k];
      sbk[slot]   = (u16)bk[k];
    }
  }
  __syncthreads();

  for (int j = t; j < cnt; j += BTH){
    int b = sbk[j];
    binned[gpos[b] + (j - base[b])] = stage[j];
  }
}

__global__ __launch_bounds__(256) void k_bcsr(
    const u32* __restrict__ binned, const int* __restrict__ boff,
    int* __restrict__ rowptr, int* __restrict__ csr, int N, int nbuck)
{
  __shared__ int cnt[BSZ];
  __shared__ int rp[BSZ];
  __shared__ int cur[BSZ];
  const int b = blockIdx.x;
  const int t = threadIdx.x;
  const int lo = boff[b], hi = boff[b + 1];

  for (int i = t; i < BSZ; i += 256){ cnt[i] = 0; cur[i] = 0; }
  __syncthreads();

  for (int j = lo + t; j < hi; j += 256)
    atomicAdd(&cnt[binned[j] & BMSK], 1);
  __syncthreads();

  if (t < 64){
    const int b0 = t * 8;
    int sum = 0;
    #pragma unroll
    for (int j = 0; j < 8; j++) sum += cnt[b0 + j];
    int excl = sum;
    for (int off = 1; off < 64; off <<= 1){
      int x = __shfl_up(excl, off);
      if (t >= off) excl += x;
    }
    excl -= sum;
    int run = excl;
    #pragma unroll
    for (int j = 0; j < 8; j++){ rp[b0 + j] = run; run += cnt[b0 + j]; }
  }
  __syncthreads();

  const int node0 = b << BSH;
  for (int i = t; i < BSZ; i += 256){
    int node = node0 + i;
    if (node < N) rowptr[node] = lo + rp[i];
  }

  for (int j = lo + t; j < hi; j += 256){
    u32 pvv = binned[j];
    int dl  = pvv & BMSK;
    int pos = lo + rp[dl] + atomicAdd(&cur[dl], 1);
    csr[pos] = (int)(pvv >> BSH);
  }
}

// ---------------- stamps ----------------

__global__ void k_stamp_if(const int* __restrict__ errflag, float* __restrict__ out, int nel)
{
  int f = *errflag;
  if (f == 0) return;
  float s = 500.0f + 100.0f * (float)f;
  int i = blockIdx.x * 256 + threadIdx.x;
  if (i < nel) out[i] = s;
}

__global__ void k_stamp(float* __restrict__ out, int nel, float val)
{
  int i = blockIdx.x * 256 + threadIdx.x;
  if (i < nel) out[i] = val;
}

// ---------------- fused tables: vocab prep + MFMA weight packs ----------------
// blocks [0,V)        : per-vocab LN+W1 row + al dot products (128 thr)
// blocks [V, V+32)    : pack W2 (128 cols, 8 ntiles), 64 thr active
// blocks [V+32, V+48) : pack gw1 (64 cols, 4 ntiles), 64 thr active

__global__ __launch_bounds__(128) void k_tables(
    const float* __restrict__ emb,
    const float* __restrict__ ln_g, const float* __restrict__ ln_b,
    const float* __restrict__ W1, const float* __restrict__ a_src,
    const float* __restrict__ a_dst,
    const float* __restrict__ W2, const float* __restrict__ gw1,
    int V,
    u16* __restrict__ xwv, float* __restrict__ alsv, float* __restrict__ aldv,
    u16* __restrict__ pb2, u16* __restrict__ pbg)
{
  const int bid = blockIdx.x;
  const int t   = threadIdx.x;

  if (bid >= V){
    if (t >= 64) return;
    int pw = bid - V;
    const float* W; int ncols, ntiles, blk; u16* pb;
    if (pw < 32){ W = W2; ncols = 128; ntiles = 8; blk = pw;      pb = pb2; }
    else        { W = gw1; ncols = 64;  ntiles = 4; blk = pw - 32; pb = pbg; }
    const int ktile = blk / ntiles;
    const int ntile = blk % ntiles;
    const int n  = ntile * 16 + (t & 15);
    const int k0 = ktile * 32 + (t >> 4) * 8;
    u16* dst = pb + ((size_t)blk * 64 + t) * 8;
    #pragma unroll
    for (int j = 0; j < 8; j++)
      dst[j] = f2bf(W[(k0 + j) * ncols + n]);
    return;
  }

  __shared__ float se[32];
  __shared__ float stats[2];
  __shared__ float sxw[128];
  const int v = bid;
  if (t < 32) se[t] = emb[v * 32 + t];
  __syncthreads();
  if (t == 0){
    float s1 = 0.f, s2 = 0.f;
    for (int k = 0; k < 32; k++){ s1 += se[k]; s2 += se[k] * se[k]; }
    float mu = s1 * (1.f / 32.f);
    float var = s2 * (1.f / 32.f) - mu * mu;
    stats[0] = mu; stats[1] = rsqrtf(var + LN_EPS);
  }
  __syncthreads();
  const float mu = stats[0], rs = stats[1];
  float o = 0.f;
  for (int k = 0; k < 32; k++){
    float xe = (se[k] - mu) * rs * ln_g[k] + ln_b[k];
    o += xe * W1[k * 128 + t];
  }
  sxw[t] = o;
  xwv[v * 128 + t] = f2bf(o);
  __syncthreads();
  if (t < 2){
    float ps = 0.f, pd = 0.f;
    for (int d = 0; d < 64; d++){
      float vv = sxw[t * 64 + d];
      ps += vv * a_src[t * 64 + d];
      pd += vv * a_dst[t * 64 + d];
    }
    alsv[2 * v + t] = ps;
    aldv[2 * v + t] = pd;
  }
}

// ---------------- GAT layer 1: LDS vocab table, multi-wave grid-stride (round-3 proven) ----------------
// smem layout: [ xwv : V*128 u16 | alsv : V float2 | aldv : V float2 | stage : 4*64 float4 ]

__global__ __launch_bounds__(256, 4) void k_gatw1(
    const int* __restrict__ rowptr, const int* __restrict__ csr,
    const int* __restrict__ x, const int* __restrict__ iflag,
    const float* __restrict__ alsv, const float* __restrict__ aldv,
    const u16* __restrict__ xwv, const float* __restrict__ bias,
    int N, int V, float* __restrict__ out)
{
  extern __shared__ char smem[];
  u16*    sxwv  = (u16*)smem;
  float2* sals  = (float2*)(smem + (size_t)V * 256);
  float2* sald  = sals + V;
  float4* sedge = (float4*)(smem + (size_t)V * 256 + (size_t)V * 16);

  const int tid = threadIdx.x;
  const int enc = *iflag;

  {
    const uint4* gx = (const uint4*)xwv;
    uint4* lx = (uint4*)sxwv;
    for (int idx = tid; idx < V * 16; idx += 256) lx[idx] = gx[idx];
    const float2* ga = (const float2*)alsv;
    const float2* gd = (const float2*)aldv;
    for (int idx = tid; idx < V; idx += 256){ sals[idx] = ga[idx]; sald[idx] = gd[idx]; }
  }
  __syncthreads();

  const int wave = tid >> 6;
  const int lane = tid & 63;
  const int sub  = lane >> 4;
  const int c16  = lane & 15;
  float4* mst = sedge + wave * 64;

  for (int i = blockIdx.x * 4 + wave; i < N; i += gridDim.x * 4){
    const int r0 = rowptr[i], deg = rowptr[i + 1] - r0, total = deg + 1;
    int vi = geti(x, i, enc); vi = min(max(vi, 0), V - 1);
    const float2 ad = sald[vi];

    float sum0 = 0.f, sum1 = 0.f;
    float acc[8];
    #pragma unroll
    for (int r = 0; r < 8; r++) acc[r] = 0.f;

    if (total <= 64){
      int vs = vi;
      float a0 = -3.0e38f, a1 = -3.0e38f;
      if (lane < total){
        int s = (lane < deg) ? csr[r0 + lane] : i;
        int v = geti(x, s, enc);
        vs = min(max(v, 0), V - 1);
        float2 as = sals[vs];
        a0 = lrelu(as.x + ad.x, NEG_GAT);
        a1 = lrelu(as.y + ad.y, NEG_GAT);
      }
      float m0 = a0, m1 = a1;
      #pragma unroll
      for (int off = 32; off; off >>= 1){
        m0 = fmaxf(m0, __shfl_xor(m0, off));
        m1 = fmaxf(m1, __shfl_xor(m1, off));
      }
      float ex0 = 0.f, ex1 = 0.f;
      if (lane < total){ ex0 = __expf(a0 - m0); ex1 = __expf(a1 - m1); }
      sum0 = ex0; sum1 = ex1;
      mst[lane] = make_float4(__int_as_float(vs), ex0, ex1, 0.f);
      int qmax = (total + 3) & ~3;
      for (int q = 0; q < qmax; q += 4){
        float4 md = mst[q + sub];
        int   vj = __float_as_int(md.x);
        float ej = (c16 < 8) ? md.y : md.z;
        uint4 w = *(const uint4*)(sxwv + vj * 128 + c16 * 8);
        acc[0] += ej * bf2f(w.x & 0xffffu); acc[1] += ej * bf2f(w.x >> 16);
        acc[2] += ej * bf2f(w.y & 0xffffu); acc[3] += ej * bf2f(w.y >> 16);
        acc[4] += ej * bf2f(w.z & 0xffffu); acc[5] += ej * bf2f(w.z >> 16);
        acc[6] += ej * bf2f(w.w & 0xffffu); acc[7] += ej * bf2f(w.w >> 16);
      }
    } else {
      float m0 = -3.0e38f, m1 = -3.0e38f;
      for (int k = lane; k < total; k += 64){
        int s = (k < deg) ? csr[r0 + k] : i;
        int v = geti(x, s, enc); v = min(max(v, 0), V - 1);
        float2 as = sals[v];
        m0 = fmaxf(m0, lrelu(as.x + ad.x, NEG_GAT));
        m1 = fmaxf(m1, lrelu(as.y + ad.y, NEG_GAT));
      }
      #pragma unroll
      for (int off = 32; off; off >>= 1){
        m0 = fmaxf(m0, __shfl_xor(m0, off));
        m1 = fmaxf(m1, __shfl_xor(m1, off));
      }
      for (int base = 0; base < total; base += 64){
        int k = base + lane;
        int vs = vi; float ex0 = 0.f, ex1 = 0.f;
        if (k < total){
          int s = (k < deg) ? csr[r0 + k] : i;
          int v = geti(x, s, enc); vs = min(max(v, 0), V - 1);
          float2 as = sals[vs];
          ex0 = __expf(lrelu(as.x + ad.x, NEG_GAT) - m0);
          ex1 = __expf(lrelu(as.y + ad.y, NEG_GAT) - m1);
        }
        sum0 += ex0; sum1 += ex1;
        mst[lane] = make_float4(__int_as_float(vs), ex0, ex1, 0.f);
        int cnt = min(64, total - base);
        int qmax = (cnt + 3) & ~3;
        for (int q = 0; q < qmax; q += 4){
          float4 md = mst[q + sub];
          int   vj = __float_as_int(md.x);
          float ej = (c16 < 8) ? md.y : md.z;
          uint4 w = *(const uint4*)(sxwv + vj * 128 + c16 * 8);
          acc[0] += ej * bf2f(w.x & 0xffffu); acc[1] += ej * bf2f(w.x >> 16);
          acc[2] += ej * bf2f(w.y & 0xffffu); acc[3] += ej * bf2f(w.y >> 16);
          acc[4] += ej * bf2f(w.z & 0xffffu); acc[5] += ej * bf2f(w.z >> 16);
          acc[6] += ej * bf2f(w.w & 0xffffu); acc[7] += ej * bf2f(w.w >> 16);
        }
      }
    }

    #pragma unroll
    for (int off = 32; off; off >>= 1){
      sum0 += __shfl_xor(sum0, off);
      sum1 += __shfl_xor(sum1, off);
    }
    #pragma unroll
    for (int r = 0; r < 8; r++){
      acc[r] += __shfl_xor(acc[r], 16);
      acc[r] += __shfl_xor(acc[r], 32);
    }

    if (sub == 0){
      float inv = 1.f / ((c16 < 8) ? sum0 : sum1);
      const float4* bp = (const float4*)(bias + c16 * 8);
      float4 b0 = bp[0], b1 = bp[1];
      float4 o0, o1;
      o0.x = lrelu(acc[0] * inv + b0.x, NEG_ACT); o0.y = lrelu(acc[1] * inv + b0.y, NEG_ACT);
      o0.z = lrelu(acc[2] * inv + b0.z, NEG_ACT); o0.w = lrelu(acc[3] * inv + b0.w, NEG_ACT);
      o1.x = lrelu(acc[4] * inv + b1.x, NEG_ACT); o1.y = lrelu(acc[5] * inv + b1.y, NEG_ACT);
      o1.z = lrelu(acc[6] * inv + b1.z, NEG_ACT); o1.w = lrelu(acc[7] * inv + b1.w, NEG_ACT);
      float* op = out + (size_t)i * 128 + c16 * 8;
      *(float4*)op       = o0;
      *(float4*)(op + 4) = o1;
    }
  }
}

// fallback (large V): single-wave global-table version
__global__ __launch_bounds__(64, 8) void k_gatw1g(
    const int* __restrict__ rowptr, const int* __restrict__ csr,
    const int* __restrict__ x, const int* __restrict__ iflag,
    const float* __restrict__ alsv, const float* __restrict__ aldv,
    const u16* __restrict__ xwv, const float* __restrict__ bias,
    int V, float* __restrict__ out)
{
  const int i    = blockIdx.x;
  const int lane = threadIdx.x;
  const int sub  = lane >> 4;
  const int c16  = lane & 15;
  const int enc  = *iflag;
  const int r0 = rowptr[i], deg = rowptr[i + 1] - r0, total = deg + 1;
  int vi = geti(x, i, enc); vi = min(max(vi, 0), V - 1);
  const float ad0 = aldv[2 * vi], ad1 = aldv[2 * vi + 1];

  float sum0 = 0.f, sum1 = 0.f;
  float acc[8];
  #pragma unroll
  for (int r = 0; r < 8; r++) acc[r] = 0.f;

  float m0 = -3.0e38f, m1 = -3.0e38f;
  for (int k = lane; k < total; k += 64){
    int s = (k < deg) ? csr[r0 + k] : i;
    int v = geti(x, s, enc); v = min(max(v, 0), V - 1);
    float2 as = *(const float2*)(alsv + 2 * v);
    m0 = fmaxf(m0, lrelu(as.x + ad0, NEG_GAT));
    m1 = fmaxf(m1, lrelu(as.y + ad1, NEG_GAT));
  }
  #pragma unroll
  for (int off = 32; off; off >>= 1){
    m0 = fmaxf(m0, __shfl_xor(m0, off));
    m1 = fmaxf(m1, __shfl_xor(m1, off));
  }
  for (int base = 0; base < total; base += 64){
    int k = base + lane;
    int vs = vi; float ex0 = 0.f, ex1 = 0.f;
    if (k < total){
      int s = (k < deg) ? csr[r0 + k] : i;
      int v = geti(x, s, enc); vs = min(max(v, 0), V - 1);
      float2 as = *(const float2*)(alsv + 2 * vs);
      ex0 = __expf(lrelu(as.x + ad0, NEG_GAT) - m0);
      ex1 = __expf(lrelu(as.y + ad1, NEG_GAT) - m1);
    }
    sum0 += ex0; sum1 += ex1;
    int cnt = min(64, total - base);
    int qmax = (cnt + 3) & ~3;
    for (int q = 0; q < qmax; q += 4){
      int   j  = q + sub;
      int   vj = __shfl(vs, j);
      float e0 = __shfl(ex0, j);
      float e1 = __shfl(ex1, j);
      float ej = (c16 < 8) ? e0 : e1;
      uint4 w = *(const uint4*)(xwv + (size_t)vj * 128 + c16 * 8);
      acc[0] += ej * bf2f(w.x & 0xffffu); acc[1] += ej * bf2f(w.x >> 16);
      acc[2] += ej * bf2f(w.y & 0xffffu); acc[3] += ej * bf2f(w.y >> 16);
      acc[4] += ej * bf2f(w.z & 0xffffu); acc[5] += ej * bf2f(w.z >> 16);
      acc[6] += ej * bf2f(w.w & 0xffffu); acc[7] += ej * bf2f(w.w >> 16);
    }
  }

  #pragma unroll
  for (int off = 32; off; off >>= 1){
    sum0 += __shfl_xor(sum0, off);
    sum1 += __shfl_xor(sum1, off);
  }
  #pragma unroll
  for (int r = 0; r < 8; r++){
    acc[r] += __shfl_xor(acc[r], 16);
    acc[r] += __shfl_xor(acc[r], 32);
  }

  if (sub == 0){
    float inv = 1.f / ((c16 < 8) ? sum0 : sum1);
    const float4* bp = (const float4*)(bias + c16 * 8);
    float4 b0 = bp[0], b1 = bp[1];
    float4 o0, o1;
    o0.x = lrelu(acc[0] * inv + b0.x, NEG_ACT); o0.y = lrelu(acc[1] * inv + b0.y, NEG_ACT);
    o0.z = lrelu(acc[2] * inv + b0.z, NEG_ACT); o0.w = lrelu(acc[3] * inv + b0.w, NEG_ACT);
    o1.x = lrelu(acc[4] * inv + b1.x, NEG_ACT); o1.y = lrelu(acc[5] * inv + b1.y, NEG_ACT);
    o1.z = lrelu(acc[6] * inv + b1.z, NEG_ACT); o1.w = lrelu(acc[7] * inv + b1.w, NEG_ACT);
    float* op = out + (size_t)i * 128 + c16 * 8;
    *(float4*)op       = o0;
    *(float4*)(op + 4) = o1;
  }
}

// ---------------- GAT layer 2: single-wave per dst (round-2 proven, fastest) ----------------

__global__ __launch_bounds__(64, 8) void k_gatw2(
    const int* __restrict__ rowptr, const int* __restrict__ csr,
    const float* __restrict__ al_s, const float* __restrict__ al_d,
    const u16* __restrict__ xw, const float* __restrict__ bias,
    int apply_act, float* __restrict__ out)
{
  const int i    = blockIdx.x;
  const int lane = threadIdx.x;
  const int sub  = lane >> 4;
  const int c16  = lane & 15;
  const int r0 = rowptr[i], deg = rowptr[i + 1] - r0, total = deg + 1;
  const float2 ad = *(const float2*)(al_d + 2 * i);

  float sum0 = 0.f, sum1 = 0.f;
  float acc[8];
  #pragma unroll
  for (int r = 0; r < 8; r++) acc[r] = 0.f;

  if (total <= 64){
    int s = i;
    float a0 = -3.0e38f, a1 = -3.0e38f;
    if (lane < total){
      s = (lane < deg) ? csr[r0 + lane] : i;
      float2 as = *(const float2*)(al_s + 2 * s);
      a0 = lrelu(as.x + ad.x, NEG_GAT);
      a1 = lrelu(as.y + ad.y, NEG_GAT);
    }
    float m0 = a0, m1 = a1;
    #pragma unroll
    for (int off = 32; off; off >>= 1){
      m0 = fmaxf(m0, __shfl_xor(m0, off));
      m1 = fmaxf(m1, __shfl_xor(m1, off));
    }
    float ex0 = 0.f, ex1 = 0.f;
    if (lane < total){ ex0 = __expf(a0 - m0); ex1 = __expf(a1 - m1); }
    sum0 = ex0; sum1 = ex1;
    int qmax = (total + 3) & ~3;
    for (int q = 0; q < qmax; q += 4){
      int   j  = q + sub;
      int   sj = __shfl(s, j);
      float e0 = __shfl(ex0, j);
      float e1 = __shfl(ex1, j);
      float ej = (c16 < 8) ? e0 : e1;
      uint4 w = *(const uint4*)(xw + (size_t)sj * 128 + c16 * 8);
      acc[0] += ej * bf2f(w.x & 0xffffu); acc[1] += ej * bf2f(w.x >> 16);
      acc[2] += ej * bf2f(w.y & 0xffffu); acc[3] += ej * bf2f(w.y >> 16);
      acc[4] += ej * bf2f(w.z & 0xffffu); acc[5] += ej * bf2f(w.z >> 16);
      acc[6] += ej * bf2f(w.w & 0xffffu); acc[7] += ej * bf2f(w.w >> 16);
    }
  } else {
    float m0 = -3.0e38f, m1 = -3.0e38f;
    for (int k = lane; k < total; k += 64){
      int s = (k < deg) ? csr[r0 + k] : i;
      float2 as = *(const float2*)(al_s + 2 * s);
      m0 = fmaxf(m0, lrelu(as.x + ad.x, NEG_GAT));
      m1 = fmaxf(m1, lrelu(as.y + ad.y, NEG_GAT));
    }
    #pragma unroll
    for (int off = 32; off; off >>= 1){
      m0 = fmaxf(m0, __shfl_xor(m0, off));
      m1 = fmaxf(m1, __shfl_xor(m1, off));
    }
    for (int base = 0; base < total; base += 64){
      int k = base + lane;
      int s = i; float ex0 = 0.f, ex1 = 0.f;
      if (k < total){
        s = (k < deg) ? csr[r0 + k] : i;
        float2 as = *(const float2*)(al_s + 2 * s);
        ex0 = __expf(lrelu(as.x + ad.x, NEG_GAT) - m0);
        ex1 = __expf(lrelu(as.y + ad.y, NEG_GAT) - m1);
      }
      sum0 += ex0; sum1 += ex1;
      int cnt = min(64, total - base);
      int qmax = (cnt + 3) & ~3;
      for (int q = 0; q < qmax; q += 4){
        int   j  = q + sub;
        int   sj = __shfl(s, j);
        float e0 = __shfl(ex0, j);
        float e1 = __shfl(ex1, j);
        float ej = (c16 < 8) ? e0 : e1;
        uint4 w = *(const uint4*)(xw + (size_t)sj * 128 + c16 * 8);
        acc[0] += ej * bf2f(w.x & 0xffffu); acc[1] += ej * bf2f(w.x >> 16);
        acc[2] += ej * bf2f(w.y & 0xffffu); acc[3] += ej * bf2f(w.y >> 16);
        acc[4] += ej * bf2f(w.z & 0xffffu); acc[5] += ej * bf2f(w.z >> 16);
        acc[6] += ej * bf2f(w.w & 0xffffu); acc[7] += ej * bf2f(w.w >> 16);
      }
    }
  }

  #pragma unroll
  for (int off = 32; off; off >>= 1){
    sum0 += __shfl_xor(sum0, off);
    sum1 += __shfl_xor(sum1, off);
  }
  #pragma unroll
  for (int r = 0; r < 8; r++){
    acc[r] += __shfl_xor(acc[r], 16);
    acc[r] += __shfl_xor(acc[r], 32);
  }

  if (sub == 0){
    float inv = 1.f / ((c16 < 8) ? sum0 : sum1);
    const float4* bp = (const float4*)(bias + c16 * 8);
    float4 b0 = bp[0], b1 = bp[1];
    float4 o0, o1;
    o0.x = acc[0] * inv + b0.x; o0.y = acc[1] * inv + b0.y;
    o0.z = acc[2] * inv + b0.z; o0.w = acc[3] * inv + b0.w;
    o1.x = acc[4] * inv + b1.x; o1.y = acc[5] * inv + b1.y;
    o1.z = acc[6] * inv + b1.z; o1.w = acc[7] * inv + b1.w;
    if (apply_act){
      o0.x = lrelu(o0.x, NEG_ACT); o0.y = lrelu(o0.y, NEG_ACT);
      o0.z = lrelu(o0.z, NEG_ACT); o0.w = lrelu(o0.w, NEG_ACT);
      o1.x = lrelu(o1.x, NEG_ACT); o1.y = lrelu(o1.y, NEG_ACT);
      o1.z = lrelu(o1.z, NEG_ACT); o1.w = lrelu(o1.w, NEG_ACT);
    }
    float* op = out + (size_t)i * 128 + c16 * 8;
    *(float4*)op       = o0;
    *(float4*)(op + 4) = o1;
  }
}

// ---------------- layer-2 node prep: MFMA GEMM xw2 = h1 @ W2 (+ al epilogue) ----------------

__global__ __launch_bounds__(256, 2) void k_node2m(
    const float* __restrict__ h1, const u16* __restrict__ pb2,
    const float* __restrict__ a_src, const float* __restrict__ a_dst,
    int N, u16* __restrict__ xw, float* __restrict__ al_s, float* __restrict__ al_d)
{
  const int wave = threadIdx.x >> 6;
  const int lane = threadIdx.x & 63;
  const int rowbase = blockIdx.x * 64 + wave * 16;
  const int m    = lane & 15;
  const int quad = lane >> 4;

  int arow = rowbase + m; if (arow >= N) arow = N - 1;
  const float* aptr = h1 + (size_t)arow * 128 + quad * 8;

  f32x4 acc[8];
  #pragma unroll
  for (int nt = 0; nt < 8; nt++) acc[nt] = (f32x4){0.f, 0.f, 0.f, 0.f};

  #pragma unroll
  for (int kt = 0; kt < 4; kt++){
    float4 a0 = *(const float4*)(aptr + kt * 32);
    float4 a1 = *(const float4*)(aptr + kt * 32 + 4);
    bf16x8 af;
    af[0] = (short)f2bf(a0.x); af[1] = (short)f2bf(a0.y);
    af[2] = (short)f2bf(a0.z); af[3] = (short)f2bf(a0.w);
    af[4] = (short)f2bf(a1.x); af[5] = (short)f2bf(a1.y);
    af[6] = (short)f2bf(a1.z); af[7] = (short)f2bf(a1.w);
    const u16* bbase = pb2 + (((size_t)kt * 8) * 64 + lane) * 8;
    #pragma unroll
    for (int nt = 0; nt < 8; nt++){
      bf16x8 bf = *(const bf16x8*)(bbase + (size_t)nt * 64 * 8);
      acc[nt] = __builtin_amdgcn_mfma_f32_16x16x32_bf16(af, bf, acc[nt], 0, 0, 0);
    }
  }

  float asv[8], adv[8];
  #pragma unroll
  for (int nt = 0; nt < 8; nt++){
    asv[nt] = a_src[nt * 16 + m];
    adv[nt] = a_dst[nt * 16 + m];
  }
  #pragma unroll
  for (int r = 0; r < 4; r++){
    int row = rowbase + quad * 4 + r;
    bool ok = row < N;
    float s0 = 0.f, s1 = 0.f, d0 = 0.f, d1 = 0.f;
    #pragma unroll
    for (int nt = 0; nt < 8; nt++){
      float v = acc[nt][r];
      if (ok) xw[(size_t)row * 128 + nt * 16 + m] = f2bf(v);
      if (nt < 4){ s0 += v * asv[nt]; d0 += v * adv[nt]; }
      else       { s1 += v * asv[nt]; d1 += v * adv[nt]; }
    }
    #pragma unroll
    for (int off = 1; off < 16; off <<= 1){
      s0 += __shfl_xor(s0, off); s1 += __shfl_xor(s1, off);
      d0 += __shfl_xor(d0, off); d1 += __shfl_xor(d1, off);
    }
    if (ok && m == 0){
      al_s[2 * row] = s0; al_s[2 * row + 1] = s1;
      al_d[2 * row] = d0; al_d[2 * row + 1] = d1;
    }
  }
}

// ---------------- gate: MFMA GEMM t = h @ gw1, fused lrelu + dot(gw2) ----------------

__global__ __launch_bounds__(256, 2) void k_gatem(
    const float* __restrict__ h, const u16* __restrict__ pbg,
    const float* __restrict__ gb1, const float* __restrict__ gw2,
    const float* __restrict__ gb2, int N, float* __restrict__ gate)
{
  const int wave = threadIdx.x >> 6;
  const int lane = threadIdx.x & 63;
  const int rowbase = blockIdx.x * 64 + wave * 16;
  const int m    = lane & 15;
  const int quad = lane >> 4;

  int arow = rowbase + m; if (arow >= N) arow = N - 1;
  const float* aptr = h + (size_t)arow * 128 + quad * 8;

  f32x4 acc[4];
  #pragma unroll
  for (int nt = 0; nt < 4; nt++) acc[nt] = (f32x4){0.f, 0.f, 0.f, 0.f};

  #pragma unroll
  for (int kt = 0; kt < 4; kt++){
    float4 a0 = *(const float4*)(aptr + kt * 32);
    float4 a1 = *(const float4*)(aptr + kt * 32 + 4);
    bf16x8 af;
    af[0] = (short)f2bf(a0.x); af[1] = (short)f2bf(a0.y);
    af[2] = (short)f2bf(a0.z); af[3] = (short)f2bf(a0.w);
    af[4] = (short)f2bf(a1.x); af[5] = (short)f2bf(a1.y);
    af[6] = (short)f2bf(a1.z); af[7] = (short)f2bf(a1.w);
    const u16* bbase = pbg + (((size_t)kt * 4) * 64 + lane) * 8;
    #pragma unroll
    for (int nt = 0; nt < 4; nt++){
      bf16x8 bf = *(const bf16x8*)(bbase + (size_t)nt * 64 * 8);
      acc[nt] = __builtin_amdgcn_mfma_f32_16x16x32_bf16(af, bf, acc[nt], 0, 0, 0);
    }
  }

  float gbv[4], g2v[4];
  #pragma unroll
  for (int nt = 0; nt < 4; nt++){
    gbv[nt] = gb1[nt * 16 + m];
    g2v[nt] = gw2[nt * 16 + m];
  }
  const float g2b = gb2[0];
  #pragma unroll
  for (int r = 0; r < 4; r++){
    int row = rowbase + quad * 4 + r;
    float q = 0.f;
    #pragma unroll
    for (int nt = 0; nt < 4; nt++)
      q += lrelu(acc[nt][r] + gbv[nt], NEG_ACT) * g2v[nt];
    #pragma unroll
    for (int off = 1; off < 16; off <<= 1) q += __shfl_xor(q, off);
    if (row < N && m == 0) gate[row] = q + g2b;
  }
}

// ---------------- per-graph softmax pooling (256 threads, 2-way k-parallel) ----------------

__global__ __launch_bounds__(256) void k_graphsw(
    const int* __restrict__ batch, const int* __restrict__ iflag,
    const float* __restrict__ gate,
    const float* __restrict__ h, float* __restrict__ zout, int N)
{
  __shared__ int   range[2];
  __shared__ float red[8];
  __shared__ float sz[128];
  const int g = blockIdx.x, t = threadIdx.x;
  const int wave = t >> 6, lane = t & 63;
  if (t == 0){
    const int enc = *iflag;
    int lo = 0, hi = N;
    while (lo < hi){ int mid = (lo + hi) >> 1; if (geti(batch, mid, enc) < g) lo = mid + 1; else hi = mid; }
    range[0] = lo;
    hi = N;
    while (lo < hi){ int mid = (lo + hi) >> 1; if (geti(batch, mid, enc) < g + 1) lo = mid + 1; else hi = mid; }
    range[1] = lo;
  }
  __syncthreads();
  const int st = range[0], en = range[1];

  float m = -3.0e38f;
  for (int k = st + t; k < en; k += 256) m = fmaxf(m, gate[k]);
  #pragma unroll
  for (int off = 32; off; off >>= 1) m = fmaxf(m, __shfl_xor(m, off));
  if (lane == 0) red[wave] = m;
  __syncthreads();
  m = fmaxf(fmaxf(red[0], red[1]), fmaxf(red[2], red[3]));

  float s = 0.f;
  for (int k = st + t; k < en; k += 256) s += __expf(gate[k] - m);
  #pragma unroll
  for (int off = 32; off; off >>= 1) s += __shfl_xor(s, off);
  if (lane == 0) red[4 + wave] = s;
  __syncthreads();
  s = (red[4] + red[5]) + (red[6] + red[7]);

  const float inv = 1.f / s;
  const int half = t >> 7, t2 = t & 127;
  float z = 0.f;
  for (int k = st + half; k < en; k += 2){
    float wk = __expf(gate[k] - m) * inv;
    z += wk * h[(size_t)k * 128 + t2];
  }
  if (half == 1) sz[t2] = z;
  __syncthreads();
  if (half == 0) zout[(size_t)g * 128 + t2] = z + sz[t2];
}

// ---------------- launch ----------------

extern "C" void kernel_launch(void* const* d_in, const int* in_sizes, int n_in,
                              void* d_out, int out_size, void* d_ws, size_t ws_size,
                              hipStream_t stream)
{
  const int* x      = (const int*)d_in[0];
  const int* ei     = (const int*)d_in[1];
  const int* batch  = (const int*)d_in[2];

  const int N = in_sizes[0];
  const int E = in_sizes[1] / 2;
  const int V = in_sizes[3] / 32;
  const int G = out_size / 128 - N;

  char* p = (char*)d_ws;
  auto alloc = [&](size_t bytes) -> char* {
    char* r = p; p += (bytes + 255) & ~(size_t)255; return r;
  };
  int*   multi  = (int*)  alloc((size_t)N * 4);       // counts -> cursor -> gate
  int*   rowptr = (int*)  alloc((size_t)(N + 1) * 4);
  int*   csr    = (int*)  alloc((size_t)E * 4);
  int*   bsums  = (int*)  alloc(4096);
  int*   boffs  = (int*)  alloc(4096);
  int*   flags  = (int*)  alloc(256);
  int*   fflag  = flags;
  int*   iflag  = flags + 1;
  int*   errflg = flags + 2;
  float* al_s   = (float*)alloc((size_t)N * 2 * 4);
  float* al_d   = (float*)alloc((size_t)N * 2 * 4);
  u16*   xw     = (u16*)  alloc((size_t)N * 128 * 2);
  u16*   xwv    = (u16*)  alloc((size_t)V * 128 * 2);
  float* alsv   = (float*)alloc((size_t)V * 2 * 4);
  float* aldv   = (float*)alloc((size_t)V * 2 * 4);
  u16*   pb2    = (u16*)  alloc((size_t)128 * 128 * 2);  // W2 packed
  u16*   pbg    = (u16*)  alloc((size_t)128 * 64 * 2);   // gw1 packed

  const int nbuck = (N + BSZ - 1) >> BSH;
  int*   bcnt   = (int*)  alloc((size_t)(MAXB) * 4);
  int*   boff   = (int*)  alloc((size_t)(MAXB + 1) * 4);
  int*   gcur   = (int*)  alloc((size_t)(MAXB) * 4);
  u32*   binned = (u32*)  alloc((size_t)E * 4);

  CvtParams cp;
  float* fpar[NPARAM];
  int maxn = 0;
  for (int pi = 0; pi < NPARAM; pi++){
    int n = in_sizes[3 + pi];
    fpar[pi] = (float*)alloc((size_t)n * 4);
    cp.src[pi] = d_in[3 + pi];
    cp.dst[pi] = fpar[pi];
    cp.n[pi]   = n;
    if (n > maxn) maxn = n;
  }
  const size_t needed = (size_t)(p - (char*)d_ws);

  const float* emb    = fpar[0];
  const float* ln_g   = fpar[1];
  const float* ln_b   = fpar[2];
  const float* W1     = fpar[3];
  const float* a_src1 = fpar[4];
  const float* a_dst1 = fpar[5];
  const float* b1     = fpar[6];
  const float* W2     = fpar[7];
  const float* a_src2 = fpar[8];
  const float* a_dst2 = fpar[9];
  const float* b2     = fpar[10];
  const float* gw1    = fpar[11];
  const float* gb1    = fpar[12];
  const float* gw2    = fpar[13];
  const float* gb2    = fpar[14];
  (void)n_in;

  int ob = (out_size + 255) / 256;
  if (ws_size < needed){
    k_stamp<<<ob, 256, 0, stream>>>((float*)d_out, out_size, 9999.0f);
    return;
  }

  int*   counts = multi;
  int*   cursor = multi;
  float* gate   = (float*)multi;
  float* hbuf   = (float*)d_out;
  float* zbuf   = (float*)d_out + (size_t)N * 128;

  k_detect<<<1, 256, 0, stream>>>((const u32*)d_in[4], ei, flags, bcnt);
  dim3 cgrid((maxn + 255) / 256, NPARAM);
  k_convert<<<cgrid, 256, 0, stream>>>(cp, fflag);

  int eb = (E + 255) / 256;
  int nb = (N + 1023) / 1024;
  int nb256 = (N + 255) / 256;

  k_checks<<<nb256, 256, 0, stream>>>(batch, x, iflag, N, V, errflg);

  if (nbuck <= MAXB){
    k_bhist<<<256, 256, 0, stream>>>(ei, iflag, bcnt, E, N, nbuck);
    k_bscan<<<1, 64, 0, stream>>>(bcnt, boff, gcur, rowptr, nbuck, N, E);
    k_bbin<<<(E + BINB - 1) / BINB, BTH, 0, stream>>>(ei, iflag, gcur, binned, E, N, nbuck, errflg);
    k_bcsr<<<nbuck, 256, 0, stream>>>(binned, boff, rowptr, csr, N, nbuck);
  } else {
    k_check_edges<<<eb, 256, 0, stream>>>(ei, iflag, E, N, errflg);
    hipMemsetAsync(counts, 0, (size_t)N * 4, stream);
    hipMemsetAsync(csr, 0xFF, (size_t)E * 4, stream);
    k_hist<<<eb, 256, 0, stream>>>(ei, iflag, counts, E, N);
    k_scanA<<<nb, 1024, 0, stream>>>(counts, rowptr, bsums, N);
    k_scanB<<<1, 128, 0, stream>>>(bsums, boffs, nb);
    k_scanC<<<nb, 1024, 0, stream>>>(rowptr, boffs, cursor, N, E);
    k_scatter<<<eb, 256, 0, stream>>>(ei, iflag, cursor, csr, E, N);
    k_check_rows<<<nb256, 256, 0, stream>>>(rowptr, cursor, N, errflg);
    k_check_csr<<<eb, 256, 0, stream>>>(csr, E, N, errflg);
  }

  // fused tables: vocab prep + both weight packs
  k_tables<<<V + 48, 128, 0, stream>>>(emb, ln_g, ln_b, W1, a_src1, a_dst1,
                                       W2, gw1, V, xwv, alsv, aldv, pb2, pbg);

  // layer 1: LDS vocab-table GAT (round-3 proven)
  const int gwb = min(2048, (N + 3) / 4);
  const size_t smem1 = (size_t)V * 272 + 4096;
  if (smem1 <= 64 * 1024){
    k_gatw1<<<gwb, 256, smem1, stream>>>(rowptr, csr, x, iflag, alsv, aldv, xwv, b1, N, V, hbuf);
  } else {
    k_gatw1g<<<N, 64, 0, stream>>>(rowptr, csr, x, iflag, alsv, aldv, xwv, b1, V, hbuf);
  }

  const int gblk = (N + 63) / 64;
  k_node2m<<<gblk, 256, 0, stream>>>(hbuf, pb2, a_src2, a_dst2, N, xw, al_s, al_d);

  k_gatw2<<<N, 64, 0, stream>>>(rowptr, csr, al_s, al_d, xw, b2, 0, hbuf);

  k_gatem<<<gblk, 256, 0, stream>>>(hbuf, pbg, gb1, gw2, gb2, N, gate);
  k_graphsw<<<G, 256, 0, stream>>>(batch, iflag, gate, hbuf, zbuf, N);

  k_stamp_if<<<ob, 256, 0, stream>>>(errflg, (float*)d_out, out_size);
}

// Round 7
// 352.574 us; speedup vs baseline: 1.6506x; 1.0656x over previous
//
#include <hip/hip_runtime.h>
#include <hip/hip_bf16.h>
#include <stdint.h>

typedef unsigned short u16;
typedef unsigned int   u32;
typedef __attribute__((ext_vector_type(8))) short bf16x8;
typedef __attribute__((ext_vector_type(4))) float f32x4;

#define NEG_GAT 0.2f
#define NEG_ACT 0.05f
#define LN_EPS  1e-5f
#define NPARAM  15

__device__ __forceinline__ float bf2f(u32 bits16){
  union { u32 u; float f; } v; v.u = bits16 << 16; return v.f;
}
__device__ __forceinline__ u16 f2bf(float f){
  union { float f; u32 u; } v; v.f = f;
  u32 u = v.u;
  u32 r = (u + 0x7fffu + ((u >> 16) & 1u)) >> 16;
  return (u16)r;
}
// valid for slope in (0,1): max(x, s*x) == leaky_relu(x, s)
__device__ __forceinline__ float lrelu(float x, float s){ return fmaxf(x, s * x); }

__device__ __forceinline__ int geti(const int* __restrict__ p, int i, int enc){
  return p[enc ? (2 * i) : i];
}

// ---------------- dtype detection + zero scratch ----------------

struct CvtParams {
  const void* src[NPARAM];
  float*      dst[NPARAM];
  int         n[NPARAM];
};

#define MAXB  2048

__global__ void k_detect(const u32* __restrict__ ln_g_raw, const int* __restrict__ ei_raw,
                         int* __restrict__ flags, int* __restrict__ bcnt)
{
  const int t = threadIdx.x;
  for (int i = t; i < MAXB; i += 256) bcnt[i] = 0;
  if (t == 0){
    flags[0] = (ln_g_raw[0] == 0x3F800000u) ? 0 : 1;   // fflag
    int zeros = 0;
    for (int j = 0; j < 64; j++) if (ei_raw[2 * j + 1] == 0) zeros++;
    flags[1] = (zeros >= 60) ? 1 : 0;                  // iflag
    flags[2] = 0;                                      // errflag
    flags[3] = 0;                                      // (unused)
  }
}

__global__ void k_convert(CvtParams P, const int* __restrict__ flag)
{
  const int pi  = blockIdx.y;
  const int idx = blockIdx.x * 256 + threadIdx.x;
  if (idx >= P.n[pi]) return;
  if (*flag == 0) P.dst[pi][idx] = ((const float*)P.src[pi])[idx];
  else            P.dst[pi][idx] = bf2f(((const u16*)P.src[pi])[idx]);
}

// ---------------- validators ----------------

__global__ void k_checks(const int* __restrict__ batch, const int* __restrict__ x,
                         const int* __restrict__ iflag,
                         int n, int V, int* __restrict__ errflag)
{
  int i = blockIdx.x * 256 + threadIdx.x;
  const int enc = *iflag;
  if (i < n){
    int v = geti(x, i, enc);
    if ((unsigned)v >= (unsigned)V) atomicOr(errflag, 16);
    if (i < n - 1 && geti(batch, i, enc) > geti(batch, i + 1, enc)) atomicOr(errflag, 8);
  }
}

__global__ void k_check_edges(const int* __restrict__ ei, const int* __restrict__ iflag,
                              int E, int n, int* __restrict__ errflag)
{
  int e = blockIdx.x * 256 + threadIdx.x;
  if (e < E){
    int enc = *iflag;
    int s = geti(ei, e, enc);
    int d = geti(ei, E + e, enc);
    if ((unsigned)s >= (unsigned)n || (unsigned)d >= (unsigned)n) atomicOr(errflag, 32);
  }
}

// ---------------- CSR build: legacy path (fallback for huge N) ----------------

__global__ void k_hist(const int* __restrict__ ei, const int* __restrict__ iflag,
                       int* __restrict__ counts, int E, int n)
{
  int e = blockIdx.x * 256 + threadIdx.x;
  if (e < E){
    int d = geti(ei, E + e, *iflag);
    d = min(max(d, 0), n - 1);
    atomicAdd(&counts[d], 1);
  }
}

__global__ void k_scanA(const int* __restrict__ counts, int* __restrict__ rowptr,
                        int* __restrict__ bsums, int n)
{
  __shared__ int sd[1024];
  int tid = threadIdx.x;
  int gid = blockIdx.x * 1024 + tid;
  int v = (gid < n) ? counts[gid] : 0;
  sd[tid] = v;
  __syncthreads();
  for (int off = 1; off < 1024; off <<= 1){
    int t = 0;
    if (tid >= off) t = sd[tid - off];
    __syncthreads();
    if (tid >= off) sd[tid] += t;
    __syncthreads();
  }
  if (gid < n) rowptr[gid] = sd[tid] - v;
  if (tid == 1023) bsums[blockIdx.x] = sd[1023];
}

__global__ void k_scanB(const int* __restrict__ bsums, int* __restrict__ boffs, int nb)
{
  __shared__ int sd[128];
  int tid = threadIdx.x;
  int v = (tid < nb) ? bsums[tid] : 0;
  sd[tid] = v;
  __syncthreads();
  for (int off = 1; off < 128; off <<= 1){
    int t = 0;
    if (tid >= off) t = sd[tid - off];
    __syncthreads();
    if (tid >= off) sd[tid] += t;
    __syncthreads();
  }
  if (tid < nb) boffs[tid] = sd[tid] - v;
}

__global__ void k_scanC(int* __restrict__ rowptr, const int* __restrict__ boffs,
                        int* __restrict__ cursor, int n, int Etot)
{
  int gid = blockIdx.x * 1024 + threadIdx.x;
  if (gid < n){
    int v = rowptr[gid] + boffs[blockIdx.x];
    rowptr[gid] = v;
    cursor[gid] = v;
  }
  if (gid == 0) rowptr[n] = Etot;
}

__global__ void k_scatter(const int* __restrict__ ei, const int* __restrict__ iflag,
                          int* __restrict__ cursor, int* __restrict__ csr, int E, int n)
{
  int e = blockIdx.x * 256 + threadIdx.x;
  if (e < E){
    int enc = *iflag;
    int s = geti(ei, e, enc);
    int d = geti(ei, E + e, enc);
    d = min(max(d, 0), n - 1);
    int pos = atomicAdd(&cursor[d], 1);
    csr[pos] = s;
  }
}

__global__ void k_check_rows(const int* __restrict__ rowptr, const int* __restrict__ cursor,
                             int n, int* __restrict__ errflag)
{
  int i = blockIdx.x * 256 + threadIdx.x;
  if (i < n){
    if (cursor[i] != rowptr[i + 1]) atomicOr(errflag, 1);
    if (i == 0 && rowptr[0] != 0)   atomicOr(errflag, 4);
  }
}

__global__ void k_check_csr(const int* __restrict__ csr, int E, int n, int* __restrict__ errflag)
{
  int e = blockIdx.x * 256 + threadIdx.x;
  if (e < E && (unsigned)csr[e] >= (unsigned)n) atomicOr(errflag, 2);
}

// ---------------- CSR build: bucketed path (round-3 proven) ----------------

#define BSH   9
#define BSZ   512
#define BMSK  511
#define BINB  8192
#define BTH   512

__global__ void k_bhist(const int* __restrict__ ei, const int* __restrict__ iflag,
                        int* __restrict__ bcnt, int E, int N, int nbuck)
{
  __shared__ int h[MAXB];
  const int t = threadIdx.x;
  for (int i = t; i < nbuck; i += 256) h[i] = 0;
  __syncthreads();
  const int enc = *iflag;
  for (int e = blockIdx.x * 256 + t; e < E; e += gridDim.x * 256){
    int d = geti(ei, E + e, enc);
    d = min(max(d, 0), N - 1);
    atomicAdd(&h[d >> BSH], 1);
  }
  __syncthreads();
  for (int i = t; i < nbuck; i += 256){
    int c = h[i];
    if (c) atomicAdd(&bcnt[i], c);
  }
}

__global__ void k_bscan(const int* __restrict__ bcnt, int* __restrict__ boff,
                        int* __restrict__ gcur, int* __restrict__ rowptr,
                        int nbuck, int N, int E)
{
  __shared__ int sd[MAXB];
  const int lane = threadIdx.x;
  for (int i = lane; i < nbuck; i += 64) sd[i] = bcnt[i];
  __syncthreads();
  const int L = (nbuck + 63) >> 6;
  const int b0 = lane * L;
  int sum = 0;
  for (int j = 0; j < L; j++){ int idx = b0 + j; if (idx < nbuck) sum += sd[idx]; }
  int excl = sum;
  for (int off = 1; off < 64; off <<= 1){
    int x = __shfl_up(excl, off);
    if (lane >= off) excl += x;
  }
  excl -= sum;
  int run = excl;
  for (int j = 0; j < L; j++){
    int idx = b0 + j;
    if (idx < nbuck){ boff[idx] = run; gcur[idx] = run; run += sd[idx]; }
  }
  if (lane == 0){ boff[nbuck] = E; rowptr[N] = E; }
}

__global__ __launch_bounds__(BTH) void k_bbin(
    const int* __restrict__ ei, const int* __restrict__ iflag,
    int* __restrict__ gcur, u32* __restrict__ binned,
    int E, int N, int nbuck, int* __restrict__ errflag)
{
  __shared__ u32 stage[BINB];
  __shared__ u16 sbk[BINB];
  __shared__ int hist[MAXB];
  __shared__ int base[MAXB];
  __shared__ int gpos[MAXB];
  const int t   = threadIdx.x;
  const int e0  = blockIdx.x * BINB;
  const int cnt = min(BINB, E - e0);
  const int enc = *iflag;

  for (int i = t; i < nbuck; i += BTH) hist[i] = 0;
  __syncthreads();

  u32 pv[16]; int bk[16]; int rk[16];
  int bad = 0;
  #pragma unroll
  for (int k = 0; k < 16; k++){
    bk[k] = -1;
    int lo = k * BTH + t;
    if (lo < cnt){
      int e = e0 + lo;
      int s = geti(ei, e, enc);
      int d = geti(ei, E + e, enc);
      if ((unsigned)s >= (unsigned)N || (unsigned)d >= (unsigned)N) bad = 1;
      s = min(max(s, 0), N - 1);
      d = min(max(d, 0), N - 1);
      int b = d >> BSH;
      pv[k] = ((u32)s << BSH) | (u32)(d & BMSK);
      bk[k] = b;
      rk[k] = atomicAdd(&hist[b], 1);
    }
  }
  if (bad) atomicOr(errflag, 32);
  __syncthreads();

  if (t < 64){
    const int L = (nbuck + 63) >> 6;
    const int b0 = t * L;
    int sum = 0;
    for (int j = 0; j < L; j++){ int idx = b0 + j; if (idx < nbuck) sum += hist[idx]; }
    int excl = sum;
    for (int off = 1; off < 64; off <<= 1){
      int x = __shfl_up(excl, off);
      if (t >= off) excl += x;
    }
    excl -= sum;
    int run = excl;
    for (int j = 0; j < L; j++){
      int idx = b0 + j;
      if (idx < nbuck){ base[idx] = run; run += hist[idx]; }
    }
  }
  __syncthreads();

  for (int i = t; i < nbuck; i += BTH){
    int c = hist[i];
    gpos[i] = c ? atomicAdd(&gcur[i], c) : 0;
  }
  __syncthreads();

  #pragma unroll
  for (int k = 0; k < 16; k++){
    if (bk[k] >= 0){
      int slot = base[bk[k]] + rk[k];
      stage[slot] = pv[k];
      sbk[slot]   = (u16)bk[k];
    }
  }
  __syncthreads();

  for (int j = t; j < cnt; j += BTH){
    int b = sbk[j];
    binned[gpos[b] + (j - base[b])] = stage[j];
  }
}

__global__ __launch_bounds__(256) void k_bcsr(
    const u32* __restrict__ binned, const int* __restrict__ boff,
    int* __restrict__ rowptr, int* __restrict__ csr, int N, int nbuck)
{
  __shared__ int cnt[BSZ];
  __shared__ int rp[BSZ];
  __shared__ int cur[BSZ];
  const int b = blockIdx.x;
  const int t = threadIdx.x;
  const int lo = boff[b], hi = boff[b + 1];

  for (int i = t; i < BSZ; i += 256){ cnt[i] = 0; cur[i] = 0; }
  __syncthreads();

  for (int j = lo + t; j < hi; j += 256)
    atomicAdd(&cnt[binned[j] & BMSK], 1);
  __syncthreads();

  if (t < 64){
    const int b0 = t * 8;
    int sum = 0;
    #pragma unroll
    for (int j = 0; j < 8; j++) sum += cnt[b0 + j];
    int excl = sum;
    for (int off = 1; off < 64; off <<= 1){
      int x = __shfl_up(excl, off);
      if (t >= off) excl += x;
    }
    excl -= sum;
    int run = excl;
    #pragma unroll
    for (int j = 0; j < 8; j++){ rp[b0 + j] = run; run += cnt[b0 + j]; }
  }
  __syncthreads();

  const int node0 = b << BSH;
  for (int i = t; i < BSZ; i += 256){
    int node = node0 + i;
    if (node < N) rowptr[node] = lo + rp[i];
  }

  for (int j = lo + t; j < hi; j += 256){
    u32 pvv = binned[j];
    int dl  = pvv & BMSK;
    int pos = lo + rp[dl] + atomicAdd(&cur[dl], 1);
    csr[pos] = (int)(pvv >> BSH);
  }
}

// ---------------- stamps (grid-stride: cheap when no error) ----------------

__global__ void k_stamp_if(const int* __restrict__ errflag, float* __restrict__ out, int nel)
{
  int f = *errflag;
  if (f == 0) return;
  float s = 500.0f + 100.0f * (float)f;
  for (int i = blockIdx.x * 256 + threadIdx.x; i < nel; i += gridDim.x * 256) out[i] = s;
}

__global__ void k_stamp(float* __restrict__ out, int nel, float val)
{
  for (int i = blockIdx.x * 256 + threadIdx.x; i < nel; i += gridDim.x * 256) out[i] = val;
}

// ---------------- fused tables: vocab prep + MFMA weight packs ----------------

__global__ __launch_bounds__(128) void k_tables(
    const float* __restrict__ emb,
    const float* __restrict__ ln_g, const float* __restrict__ ln_b,
    const float* __restrict__ W1, const float* __restrict__ a_src,
    const float* __restrict__ a_dst,
    const float* __restrict__ W2, const float* __restrict__ gw1,
    int V,
    u16* __restrict__ xwv, float* __restrict__ alsv, float* __restrict__ aldv,
    u16* __restrict__ pb2, u16* __restrict__ pbg)
{
  const int bid = blockIdx.x;
  const int t   = threadIdx.x;

  if (bid >= V){
    if (t >= 64) return;
    int pw = bid - V;
    const float* W; int ncols, ntiles, blk; u16* pb;
    if (pw < 32){ W = W2; ncols = 128; ntiles = 8; blk = pw;      pb = pb2; }
    else        { W = gw1; ncols = 64;  ntiles = 4; blk = pw - 32; pb = pbg; }
    const int ktile = blk / ntiles;
    const int ntile = blk % ntiles;
    const int n  = ntile * 16 + (t & 15);
    const int k0 = ktile * 32 + (t >> 4) * 8;
    u16* dst = pb + ((size_t)blk * 64 + t) * 8;
    #pragma unroll
    for (int j = 0; j < 8; j++)
      dst[j] = f2bf(W[(k0 + j) * ncols + n]);
    return;
  }

  __shared__ float se[32];
  __shared__ float stats[2];
  __shared__ float sxw[128];
  const int v = bid;
  if (t < 32) se[t] = emb[v * 32 + t];
  __syncthreads();
  if (t == 0){
    float s1 = 0.f, s2 = 0.f;
    for (int k = 0; k < 32; k++){ s1 += se[k]; s2 += se[k] * se[k]; }
    float mu = s1 * (1.f / 32.f);
    float var = s2 * (1.f / 32.f) - mu * mu;
    stats[0] = mu; stats[1] = rsqrtf(var + LN_EPS);
  }
  __syncthreads();
  const float mu = stats[0], rs = stats[1];
  float o = 0.f;
  for (int k = 0; k < 32; k++){
    float xe = (se[k] - mu) * rs * ln_g[k] + ln_b[k];
    o += xe * W1[k * 128 + t];
  }
  sxw[t] = o;
  xwv[v * 128 + t] = f2bf(o);
  __syncthreads();
  if (t < 2){
    float ps = 0.f, pd = 0.f;
    for (int d = 0; d < 64; d++){
      float vv = sxw[t * 64 + d];
      ps += vv * a_src[t * 64 + d];
      pd += vv * a_dst[t * 64 + d];
    }
    alsv[2 * v + t] = ps;
    aldv[2 * v + t] = pd;
  }
}

// ---------------- GAT layer 1: LDS vocab table, multi-wave grid-stride ----------------
// Output h1 stored as bf16 (identical rounding to node2m's internal f2bf —
// h1's only consumer is node2m's MFMA A-operand).
// smem layout: [ xwv : V*128 u16 | alsv : V float2 | aldv : V float2 | stage : 4*64 float4 ]

__global__ __launch_bounds__(256, 4) void k_gatw1(
    const int* __restrict__ rowptr, const int* __restrict__ csr,
    const int* __restrict__ x, const int* __restrict__ iflag,
    const float* __restrict__ alsv, const float* __restrict__ aldv,
    const u16* __restrict__ xwv, const float* __restrict__ bias,
    int N, int V, u16* __restrict__ out)
{
  extern __shared__ char smem[];
  u16*    sxwv  = (u16*)smem;
  float2* sals  = (float2*)(smem + (size_t)V * 256);
  float2* sald  = sals + V;
  float4* sedge = (float4*)(smem + (size_t)V * 256 + (size_t)V * 16);

  const int tid = threadIdx.x;
  const int enc = *iflag;

  {
    const uint4* gx = (const uint4*)xwv;
    uint4* lx = (uint4*)sxwv;
    for (int idx = tid; idx < V * 16; idx += 256) lx[idx] = gx[idx];
    const float2* ga = (const float2*)alsv;
    const float2* gd = (const float2*)aldv;
    for (int idx = tid; idx < V; idx += 256){ sals[idx] = ga[idx]; sald[idx] = gd[idx]; }
  }
  __syncthreads();

  const int wave = tid >> 6;
  const int lane = tid & 63;
  const int sub  = lane >> 4;
  const int c16  = lane & 15;
  float4* mst = sedge + wave * 64;

  for (int i = blockIdx.x * 4 + wave; i < N; i += gridDim.x * 4){
    const int r0 = rowptr[i], deg = rowptr[i + 1] - r0, total = deg + 1;
    int vi = geti(x, i, enc); vi = min(max(vi, 0), V - 1);
    const float2 ad = sald[vi];

    float sum0 = 0.f, sum1 = 0.f;
    float acc[8];
    #pragma unroll
    for (int r = 0; r < 8; r++) acc[r] = 0.f;

    if (total <= 64){
      int vs = vi;
      float a0 = -3.0e38f, a1 = -3.0e38f;
      if (lane < total){
        int s = (lane < deg) ? csr[r0 + lane] : i;
        int v = geti(x, s, enc);
        vs = min(max(v, 0), V - 1);
        float2 as = sals[vs];
        a0 = lrelu(as.x + ad.x, NEG_GAT);
        a1 = lrelu(as.y + ad.y, NEG_GAT);
      }
      float m0 = a0, m1 = a1;
      #pragma unroll
      for (int off = 32; off; off >>= 1){
        m0 = fmaxf(m0, __shfl_xor(m0, off));
        m1 = fmaxf(m1, __shfl_xor(m1, off));
      }
      float ex0 = 0.f, ex1 = 0.f;
      if (lane < total){ ex0 = __expf(a0 - m0); ex1 = __expf(a1 - m1); }
      sum0 = ex0; sum1 = ex1;
      mst[lane] = make_float4(__int_as_float(vs), ex0, ex1, 0.f);
      int qmax = (total + 3) & ~3;
      for (int q = 0; q < qmax; q += 4){
        float4 md = mst[q + sub];
        int   vj = __float_as_int(md.x);
        float ej = (c16 < 8) ? md.y : md.z;
        uint4 w = *(const uint4*)(sxwv + vj * 128 + c16 * 8);
        acc[0] += ej * bf2f(w.x & 0xffffu); acc[1] += ej * bf2f(w.x >> 16);
        acc[2] += ej * bf2f(w.y & 0xffffu); acc[3] += ej * bf2f(w.y >> 16);
        acc[4] += ej * bf2f(w.z & 0xffffu); acc[5] += ej * bf2f(w.z >> 16);
        acc[6] += ej * bf2f(w.w & 0xffffu); acc[7] += ej * bf2f(w.w >> 16);
      }
    } else {
      float m0 = -3.0e38f, m1 = -3.0e38f;
      for (int k = lane; k < total; k += 64){
        int s = (k < deg) ? csr[r0 + k] : i;
        int v = geti(x, s, enc); v = min(max(v, 0), V - 1);
        float2 as = sals[v];
        m0 = fmaxf(m0, lrelu(as.x + ad.x, NEG_GAT));
        m1 = fmaxf(m1, lrelu(as.y + ad.y, NEG_GAT));
      }
      #pragma unroll
      for (int off = 32; off; off >>= 1){
        m0 = fmaxf(m0, __shfl_xor(m0, off));
        m1 = fmaxf(m1, __shfl_xor(m1, off));
      }
      for (int base = 0; base < total; base += 64){
        int k = base + lane;
        int vs = vi; float ex0 = 0.f, ex1 = 0.f;
        if (k < total){
          int s = (k < deg) ? csr[r0 + k] : i;
          int v = geti(x, s, enc); vs = min(max(v, 0), V - 1);
          float2 as = sals[vs];
          ex0 = __expf(lrelu(as.x + ad.x, NEG_GAT) - m0);
          ex1 = __expf(lrelu(as.y + ad.y, NEG_GAT) - m1);
        }
        sum0 += ex0; sum1 += ex1;
        mst[lane] = make_float4(__int_as_float(vs), ex0, ex1, 0.f);
        int cnt = min(64, total - base);
        int qmax = (cnt + 3) & ~3;
        for (int q = 0; q < qmax; q += 4){
          float4 md = mst[q + sub];
          int   vj = __float_as_int(md.x);
          float ej = (c16 < 8) ? md.y : md.z;
          uint4 w = *(const uint4*)(sxwv + vj * 128 + c16 * 8);
          acc[0] += ej * bf2f(w.x & 0xffffu); acc[1] += ej * bf2f(w.x >> 16);
          acc[2] += ej * bf2f(w.y & 0xffffu); acc[3] += ej * bf2f(w.y >> 16);
          acc[4] += ej * bf2f(w.z & 0xffffu); acc[5] += ej * bf2f(w.z >> 16);
          acc[6] += ej * bf2f(w.w & 0xffffu); acc[7] += ej * bf2f(w.w >> 16);
        }
      }
    }

    #pragma unroll
    for (int off = 32; off; off >>= 1){
      sum0 += __shfl_xor(sum0, off);
      sum1 += __shfl_xor(sum1, off);
    }
    #pragma unroll
    for (int r = 0; r < 8; r++){
      acc[r] += __shfl_xor(acc[r], 16);
      acc[r] += __shfl_xor(acc[r], 32);
    }

    if (sub == 0){
      float inv = 1.f / ((c16 < 8) ? sum0 : sum1);
      const float4* bp = (const float4*)(bias + c16 * 8);
      float4 b0 = bp[0], b1 = bp[1];
      float o[8];
      o[0] = lrelu(acc[0] * inv + b0.x, NEG_ACT); o[1] = lrelu(acc[1] * inv + b0.y, NEG_ACT);
      o[2] = lrelu(acc[2] * inv + b0.z, NEG_ACT); o[3] = lrelu(acc[3] * inv + b0.w, NEG_ACT);
      o[4] = lrelu(acc[4] * inv + b1.x, NEG_ACT); o[5] = lrelu(acc[5] * inv + b1.y, NEG_ACT);
      o[6] = lrelu(acc[6] * inv + b1.z, NEG_ACT); o[7] = lrelu(acc[7] * inv + b1.w, NEG_ACT);
      uint4 pk;
      pk.x = (u32)f2bf(o[0]) | ((u32)f2bf(o[1]) << 16);
      pk.y = (u32)f2bf(o[2]) | ((u32)f2bf(o[3]) << 16);
      pk.z = (u32)f2bf(o[4]) | ((u32)f2bf(o[5]) << 16);
      pk.w = (u32)f2bf(o[6]) | ((u32)f2bf(o[7]) << 16);
      *(uint4*)(out + (size_t)i * 128 + c16 * 8) = pk;
    }
  }
}

// fallback (large V): single-wave global-table version (bf16 out)
__global__ __launch_bounds__(64, 8) void k_gatw1g(
    const int* __restrict__ rowptr, const int* __restrict__ csr,
    const int* __restrict__ x, const int* __restrict__ iflag,
    const float* __restrict__ alsv, const float* __restrict__ aldv,
    const u16* __restrict__ xwv, const float* __restrict__ bias,
    int V, u16* __restrict__ out)
{
  const int i    = blockIdx.x;
  const int lane = threadIdx.x;
  const int sub  = lane >> 4;
  const int c16  = lane & 15;
  const int enc  = *iflag;
  const int r0 = rowptr[i], deg = rowptr[i + 1] - r0, total = deg + 1;
  int vi = geti(x, i, enc); vi = min(max(vi, 0), V - 1);
  const float ad0 = aldv[2 * vi], ad1 = aldv[2 * vi + 1];

  float sum0 = 0.f, sum1 = 0.f;
  float acc[8];
  #pragma unroll
  for (int r = 0; r < 8; r++) acc[r] = 0.f;

  float m0 = -3.0e38f, m1 = -3.0e38f;
  for (int k = lane; k < total; k += 64){
    int s = (k < deg) ? csr[r0 + k] : i;
    int v = geti(x, s, enc); v = min(max(v, 0), V - 1);
    float2 as = *(const float2*)(alsv + 2 * v);
    m0 = fmaxf(m0, lrelu(as.x + ad0, NEG_GAT));
    m1 = fmaxf(m1, lrelu(as.y + ad1, NEG_GAT));
  }
  #pragma unroll
  for (int off = 32; off; off >>= 1){
    m0 = fmaxf(m0, __shfl_xor(m0, off));
    m1 = fmaxf(m1, __shfl_xor(m1, off));
  }
  for (int base = 0; base < total; base += 64){
    int k = base + lane;
    int vs = vi; float ex0 = 0.f, ex1 = 0.f;
    if (k < total){
      int s = (k < deg) ? csr[r0 + k] : i;
      int v = geti(x, s, enc); vs = min(max(v, 0), V - 1);
      float2 as = *(const float2*)(alsv + 2 * vs);
      ex0 = __expf(lrelu(as.x + ad0, NEG_GAT) - m0);
      ex1 = __expf(lrelu(as.y + ad1, NEG_GAT) - m1);
    }
    sum0 += ex0; sum1 += ex1;
    int cnt = min(64, total - base);
    int qmax = (cnt + 3) & ~3;
    for (int q = 0; q < qmax; q += 4){
      int   j  = q + sub;
      int   vj = __shfl(vs, j);
      float e0 = __shfl(ex0, j);
      float e1 = __shfl(ex1, j);
      float ej = (c16 < 8) ? e0 : e1;
      uint4 w = *(const uint4*)(xwv + (size_t)vj * 128 + c16 * 8);
      acc[0] += ej * bf2f(w.x & 0xffffu); acc[1] += ej * bf2f(w.x >> 16);
      acc[2] += ej * bf2f(w.y & 0xffffu); acc[3] += ej * bf2f(w.y >> 16);
      acc[4] += ej * bf2f(w.z & 0xffffu); acc[5] += ej * bf2f(w.z >> 16);
      acc[6] += ej * bf2f(w.w & 0xffffu); acc[7] += ej * bf2f(w.w >> 16);
    }
  }

  #pragma unroll
  for (int off = 32; off; off >>= 1){
    sum0 += __shfl_xor(sum0, off);
    sum1 += __shfl_xor(sum1, off);
  }
  #pragma unroll
  for (int r = 0; r < 8; r++){
    acc[r] += __shfl_xor(acc[r], 16);
    acc[r] += __shfl_xor(acc[r], 32);
  }

  if (sub == 0){
    float inv = 1.f / ((c16 < 8) ? sum0 : sum1);
    const float4* bp = (const float4*)(bias + c16 * 8);
    float4 b0 = bp[0], b1 = bp[1];
    float o[8];
    o[0] = lrelu(acc[0] * inv + b0.x, NEG_ACT); o[1] = lrelu(acc[1] * inv + b0.y, NEG_ACT);
    o[2] = lrelu(acc[2] * inv + b0.z, NEG_ACT); o[3] = lrelu(acc[3] * inv + b0.w, NEG_ACT);
    o[4] = lrelu(acc[4] * inv + b1.x, NEG_ACT); o[5] = lrelu(acc[5] * inv + b1.y, NEG_ACT);
    o[6] = lrelu(acc[6] * inv + b1.z, NEG_ACT); o[7] = lrelu(acc[7] * inv + b1.w, NEG_ACT);
    uint4 pk;
    pk.x = (u32)f2bf(o[0]) | ((u32)f2bf(o[1]) << 16);
    pk.y = (u32)f2bf(o[2]) | ((u32)f2bf(o[3]) << 16);
    pk.z = (u32)f2bf(o[4]) | ((u32)f2bf(o[5]) << 16);
    pk.w = (u32)f2bf(o[6]) | ((u32)f2bf(o[7]) << 16);
    *(uint4*)(out + (size_t)i * 128 + c16 * 8) = pk;
  }
}

// ---------------- GAT layer 2: single-wave per dst (round-2 proven, fastest) ----------------

__global__ __launch_bounds__(64, 8) void k_gatw2(
    const int* __restrict__ rowptr, const int* __restrict__ csr,
    const float* __restrict__ al_s, const float* __restrict__ al_d,
    const u16* __restrict__ xw, const float* __restrict__ bias,
    int apply_act, float* __restrict__ out)
{
  const int i    = blockIdx.x;
  const int lane = threadIdx.x;
  const int sub  = lane >> 4;
  const int c16  = lane & 15;
  const int r0 = rowptr[i], deg = rowptr[i + 1] - r0, total = deg + 1;
  const float2 ad = *(const float2*)(al_d + 2 * i);

  float sum0 = 0.f, sum1 = 0.f;
  float acc[8];
  #pragma unroll
  for (int r = 0; r < 8; r++) acc[r] = 0.f;

  if (total <= 64){
    int s = i;
    float a0 = -3.0e38f, a1 = -3.0e38f;
    if (lane < total){
      s = (lane < deg) ? csr[r0 + lane] : i;
      float2 as = *(const float2*)(al_s + 2 * s);
      a0 = lrelu(as.x + ad.x, NEG_GAT);
      a1 = lrelu(as.y + ad.y, NEG_GAT);
    }
    float m0 = a0, m1 = a1;
    #pragma unroll
    for (int off = 32; off; off >>= 1){
      m0 = fmaxf(m0, __shfl_xor(m0, off));
      m1 = fmaxf(m1, __shfl_xor(m1, off));
    }
    float ex0 = 0.f, ex1 = 0.f;
    if (lane < total){ ex0 = __expf(a0 - m0); ex1 = __expf(a1 - m1); }
    sum0 = ex0; sum1 = ex1;
    int qmax = (total + 3) & ~3;
    for (int q = 0; q < qmax; q += 4){
      int   j  = q + sub;
      int   sj = __shfl(s, j);
      float e0 = __shfl(ex0, j);
      float e1 = __shfl(ex1, j);
      float ej = (c16 < 8) ? e0 : e1;
      uint4 w = *(const uint4*)(xw + (size_t)sj * 128 + c16 * 8);
      acc[0] += ej * bf2f(w.x & 0xffffu); acc[1] += ej * bf2f(w.x >> 16);
      acc[2] += ej * bf2f(w.y & 0xffffu); acc[3] += ej * bf2f(w.y >> 16);
      acc[4] += ej * bf2f(w.z & 0xffffu); acc[5] += ej * bf2f(w.z >> 16);
      acc[6] += ej * bf2f(w.w & 0xffffu); acc[7] += ej * bf2f(w.w >> 16);
    }
  } else {
    float m0 = -3.0e38f, m1 = -3.0e38f;
    for (int k = lane; k < total; k += 64){
      int s = (k < deg) ? csr[r0 + k] : i;
      float2 as = *(const float2*)(al_s + 2 * s);
      m0 = fmaxf(m0, lrelu(as.x + ad.x, NEG_GAT));
      m1 = fmaxf(m1, lrelu(as.y + ad.y, NEG_GAT));
    }
    #pragma unroll
    for (int off = 32; off; off >>= 1){
      m0 = fmaxf(m0, __shfl_xor(m0, off));
      m1 = fmaxf(m1, __shfl_xor(m1, off));
    }
    for (int base = 0; base < total; base += 64){
      int k = base + lane;
      int s = i; float ex0 = 0.f, ex1 = 0.f;
      if (k < total){
        s = (k < deg) ? csr[r0 + k] : i;
        float2 as = *(const float2*)(al_s + 2 * s);
        ex0 = __expf(lrelu(as.x + ad.x, NEG_GAT) - m0);
        ex1 = __expf(lrelu(as.y + ad.y, NEG_GAT) - m1);
      }
      sum0 += ex0; sum1 += ex1;
      int cnt = min(64, total - base);
      int qmax = (cnt + 3) & ~3;
      for (int q = 0; q < qmax; q += 4){
        int   j  = q + sub;
        int   sj = __shfl(s, j);
        float e0 = __shfl(ex0, j);
        float e1 = __shfl(ex1, j);
        float ej = (c16 < 8) ? e0 : e1;
        uint4 w = *(const uint4*)(xw + (size_t)sj * 128 + c16 * 8);
        acc[0] += ej * bf2f(w.x & 0xffffu); acc[1] += ej * bf2f(w.x >> 16);
        acc[2] += ej * bf2f(w.y & 0xffffu); acc[3] += ej * bf2f(w.y >> 16);
        acc[4] += ej * bf2f(w.z & 0xffffu); acc[5] += ej * bf2f(w.z >> 16);
        acc[6] += ej * bf2f(w.w & 0xffffu); acc[7] += ej * bf2f(w.w >> 16);
      }
    }
  }

  #pragma unroll
  for (int off = 32; off; off >>= 1){
    sum0 += __shfl_xor(sum0, off);
    sum1 += __shfl_xor(sum1, off);
  }
  #pragma unroll
  for (int r = 0; r < 8; r++){
    acc[r] += __shfl_xor(acc[r], 16);
    acc[r] += __shfl_xor(acc[r], 32);
  }

  if (sub == 0){
    float inv = 1.f / ((c16 < 8) ? sum0 : sum1);
    const float4* bp = (const float4*)(bias + c16 * 8);
    float4 b0 = bp[0], b1 = bp[1];
    float4 o0, o1;
    o0.x = acc[0] * inv + b0.x; o0.y = acc[1] * inv + b0.y;
    o0.z = acc[2] * inv + b0.z; o0.w = acc[3] * inv + b0.w;
    o1.x = acc[4] * inv + b1.x; o1.y = acc[5] * inv + b1.y;
    o1.z = acc[6] * inv + b1.z; o1.w = acc[7] * inv + b1.w;
    if (apply_act){
      o0.x = lrelu(o0.x, NEG_ACT); o0.y = lrelu(o0.y, NEG_ACT);
      o0.z = lrelu(o0.z, NEG_ACT); o0.w = lrelu(o0.w, NEG_ACT);
      o1.x = lrelu(o1.x, NEG_ACT); o1.y = lrelu(o1.y, NEG_ACT);
      o1.z = lrelu(o1.z, NEG_ACT); o1.w = lrelu(o1.w, NEG_ACT);
    }
    float* op = out + (size_t)i * 128 + c16 * 8;
    *(float4*)op       = o0;
    *(float4*)(op + 4) = o1;
  }
}

// ---------------- layer-2 node prep: MFMA GEMM xw2 = h1 @ W2 (+ al epilogue) ----------------
// h1 now arrives as bf16 (written by gatw1) — direct MFMA A-fragment loads.

__global__ __launch_bounds__(256, 2) void k_node2m(
    const u16* __restrict__ h1b, const u16* __restrict__ pb2,
    const float* __restrict__ a_src, const float* __restrict__ a_dst,
    int N, u16* __restrict__ xw, float* __restrict__ al_s, float* __restrict__ al_d)
{
  const int wave = threadIdx.x >> 6;
  const int lane = threadIdx.x & 63;
  const int rowbase = blockIdx.x * 64 + wave * 16;
  const int m    = lane & 15;
  const int quad = lane >> 4;

  int arow = rowbase + m; if (arow >= N) arow = N - 1;
  const u16* aptr = h1b + (size_t)arow * 128 + quad * 8;

  f32x4 acc[8];
  #pragma unroll
  for (int nt = 0; nt < 8; nt++) acc[nt] = (f32x4){0.f, 0.f, 0.f, 0.f};

  #pragma unroll
  for (int kt = 0; kt < 4; kt++){
    bf16x8 af = *(const bf16x8*)(aptr + kt * 32);
    const u16* bbase = pb2 + (((size_t)kt * 8) * 64 + lane) * 8;
    #pragma unroll
    for (int nt = 0; nt < 8; nt++){
      bf16x8 bf = *(const bf16x8*)(bbase + (size_t)nt * 64 * 8);
      acc[nt] = __builtin_amdgcn_mfma_f32_16x16x32_bf16(af, bf, acc[nt], 0, 0, 0);
    }
  }

  float asv[8], adv[8];
  #pragma unroll
  for (int nt = 0; nt < 8; nt++){
    asv[nt] = a_src[nt * 16 + m];
    adv[nt] = a_dst[nt * 16 + m];
  }
  #pragma unroll
  for (int r = 0; r < 4; r++){
    int row = rowbase + quad * 4 + r;
    bool ok = row < N;
    float s0 = 0.f, s1 = 0.f, d0 = 0.f, d1 = 0.f;
    #pragma unroll
    for (int nt = 0; nt < 8; nt++){
      float v = acc[nt][r];
      if (ok) xw[(size_t)row * 128 + nt * 16 + m] = f2bf(v);
      if (nt < 4){ s0 += v * asv[nt]; d0 += v * adv[nt]; }
      else       { s1 += v * asv[nt]; d1 += v * adv[nt]; }
    }
    #pragma unroll
    for (int off = 1; off < 16; off <<= 1){
      s0 += __shfl_xor(s0, off); s1 += __shfl_xor(s1, off);
      d0 += __shfl_xor(d0, off); d1 += __shfl_xor(d1, off);
    }
    if (ok && m == 0){
      al_s[2 * row] = s0; al_s[2 * row + 1] = s1;
      al_d[2 * row] = d0; al_d[2 * row + 1] = d1;
    }
  }
}

// ---------------- gate: MFMA GEMM t = h @ gw1, fused lrelu + dot(gw2) ----------------

__global__ __launch_bounds__(256, 2) void k_gatem(
    const float* __restrict__ h, const u16* __restrict__ pbg,
    const float* __restrict__ gb1, const float* __restrict__ gw2,
    const float* __restrict__ gb2, int N, float* __restrict__ gate)
{
  const int wave = threadIdx.x >> 6;
  const int lane = threadIdx.x & 63;
  const int rowbase = blockIdx.x * 64 + wave * 16;
  const int m    = lane & 15;
  const int quad = lane >> 4;

  int arow = rowbase + m; if (arow >= N) arow = N - 1;
  const float* aptr = h + (size_t)arow * 128 + quad * 8;

  f32x4 acc[4];
  #pragma unroll
  for (int nt = 0; nt < 4; nt++) acc[nt] = (f32x4){0.f, 0.f, 0.f, 0.f};

  #pragma unroll
  for (int kt = 0; kt < 4; kt++){
    float4 a0 = *(const float4*)(aptr + kt * 32);
    float4 a1 = *(const float4*)(aptr + kt * 32 + 4);
    bf16x8 af;
    af[0] = (short)f2bf(a0.x); af[1] = (short)f2bf(a0.y);
    af[2] = (short)f2bf(a0.z); af[3] = (short)f2bf(a0.w);
    af[4] = (short)f2bf(a1.x); af[5] = (short)f2bf(a1.y);
    af[6] = (short)f2bf(a1.z); af[7] = (short)f2bf(a1.w);
    const u16* bbase = pbg + (((size_t)kt * 4) * 64 + lane) * 8;
    #pragma unroll
    for (int nt = 0; nt < 4; nt++){
      bf16x8 bf = *(const bf16x8*)(bbase + (size_t)nt * 64 * 8);
      acc[nt] = __builtin_amdgcn_mfma_f32_16x16x32_bf16(af, bf, acc[nt], 0, 0, 0);
    }
  }

  float gbv[4], g2v[4];
  #pragma unroll
  for (int nt = 0; nt < 4; nt++){
    gbv[nt] = gb1[nt * 16 + m];
    g2v[nt] = gw2[nt * 16 + m];
  }
  const float g2b = gb2[0];
  #pragma unroll
  for (int r = 0; r < 4; r++){
    int row = rowbase + quad * 4 + r;
    float q = 0.f;
    #pragma unroll
    for (int nt = 0; nt < 4; nt++)
      q += lrelu(acc[nt][r] + gbv[nt], NEG_ACT) * g2v[nt];
    #pragma unroll
    for (int off = 1; off < 16; off <<= 1) q += __shfl_xor(q, off);
    if (row < N && m == 0) gate[row] = q + g2b;
  }
}

// ---------------- per-graph softmax pooling (512 threads, 4-way k-parallel) ----------------

__global__ __launch_bounds__(512) void k_graphsw(
    const int* __restrict__ batch, const int* __restrict__ iflag,
    const float* __restrict__ gate,
    const float* __restrict__ h, float* __restrict__ zout, int N)
{
  __shared__ int   range[2];
  __shared__ float red[16];
  __shared__ float sz[3][128];
  const int g = blockIdx.x, t = threadIdx.x;
  const int wave = t >> 6, lane = t & 63;
  if (t == 0){
    const int enc = *iflag;
    int lo = 0, hi = N;
    while (lo < hi){ int mid = (lo + hi) >> 1; if (geti(batch, mid, enc) < g) lo = mid + 1; else hi = mid; }
    range[0] = lo;
    hi = N;
    while (lo < hi){ int mid = (lo + hi) >> 1; if (geti(batch, mid, enc) < g + 1) lo = mid + 1; else hi = mid; }
    range[1] = lo;
  }
  __syncthreads();
  const int st = range[0], en = range[1];

  float m = -3.0e38f;
  for (int k = st + t; k < en; k += 512) m = fmaxf(m, gate[k]);
  #pragma unroll
  for (int off = 32; off; off >>= 1) m = fmaxf(m, __shfl_xor(m, off));
  if (lane == 0) red[wave] = m;
  __syncthreads();
  m = red[0];
  #pragma unroll
  for (int w = 1; w < 8; w++) m = fmaxf(m, red[w]);

  float s = 0.f;
  for (int k = st + t; k < en; k += 512) s += __expf(gate[k] - m);
  #pragma unroll
  for (int off = 32; off; off >>= 1) s += __shfl_xor(s, off);
  if (lane == 0) red[8 + wave] = s;
  __syncthreads();
  s = red[8];
  #pragma unroll
  for (int w = 9; w < 16; w++) s += red[w];

  const float inv = 1.f / s;
  const int quarter = t >> 7, t2 = t & 127;
  float z = 0.f;
  for (int k = st + quarter; k < en; k += 4){
    float wk = __expf(gate[k] - m) * inv;
    z += wk * h[(size_t)k * 128 + t2];
  }
  if (quarter) sz[quarter - 1][t2] = z;
  __syncthreads();
  if (quarter == 0) zout[(size_t)g * 128 + t2] = z + sz[0][t2] + sz[1][t2] + sz[2][t2];
}

// ---------------- launch ----------------

extern "C" void kernel_launch(void* const* d_in, const int* in_sizes, int n_in,
                              void* d_out, int out_size, void* d_ws, size_t ws_size,
                              hipStream_t stream)
{
  const int* x      = (const int*)d_in[0];
  const int* ei     = (const int*)d_in[1];
  const int* batch  = (const int*)d_in[2];

  const int N = in_sizes[0];
  const int E = in_sizes[1] / 2;
  const int V = in_sizes[3] / 32;
  const int G = out_size / 128 - N;

  char* p = (char*)d_ws;
  auto alloc = [&](size_t bytes) -> char* {
    char* r = p; p += (bytes + 255) & ~(size_t)255; return r;
  };
  int*   multi  = (int*)  alloc((size_t)N * 4);       // counts -> cursor -> gate
  int*   rowptr = (int*)  alloc((size_t)(N + 1) * 4);
  int*   csr    = (int*)  alloc((size_t)E * 4);
  int*   bsums  = (int*)  alloc(4096);
  int*   boffs  = (int*)  alloc(4096);
  int*   flags  = (int*)  alloc(256);
  int*   fflag  = flags;
  int*   iflag  = flags + 1;
  int*   errflg = flags + 2;
  float* al_s   = (float*)alloc((size_t)N * 2 * 4);
  float* al_d   = (float*)alloc((size_t)N * 2 * 4);
  u16*   xw     = (u16*)  alloc((size_t)N * 128 * 2);
  u16*   h1b    = (u16*)  alloc((size_t)N * 128 * 2);   // layer-1 output, bf16
  u16*   xwv    = (u16*)  alloc((size_t)V * 128 * 2);
  float* alsv   = (float*)alloc((size_t)V * 2 * 4);
  float* aldv   = (float*)alloc((size_t)V * 2 * 4);
  u16*   pb2    = (u16*)  alloc((size_t)128 * 128 * 2);  // W2 packed
  u16*   pbg    = (u16*)  alloc((size_t)128 * 64 * 2);   // gw1 packed

  const int nbuck = (N + BSZ - 1) >> BSH;
  int*   bcnt   = (int*)  alloc((size_t)(MAXB) * 4);
  int*   boff   = (int*)  alloc((size_t)(MAXB + 1) * 4);
  int*   gcur   = (int*)  alloc((size_t)(MAXB) * 4);
  u32*   binned = (u32*)  alloc((size_t)E * 4);

  CvtParams cp;
  float* fpar[NPARAM];
  int maxn = 0;
  for (int pi = 0; pi < NPARAM; pi++){
    int n = in_sizes[3 + pi];
    fpar[pi] = (float*)alloc((size_t)n * 4);
    cp.src[pi] = d_in[3 + pi];
    cp.dst[pi] = fpar[pi];
    cp.n[pi]   = n;
    if (n > maxn) maxn = n;
  }
  const size_t needed = (size_t)(p - (char*)d_ws);

  const float* emb    = fpar[0];
  const float* ln_g   = fpar[1];
  const float* ln_b   = fpar[2];
  const float* W1     = fpar[3];
  const float* a_src1 = fpar[4];
  const float* a_dst1 = fpar[5];
  const float* b1     = fpar[6];
  const float* W2     = fpar[7];
  const float* a_src2 = fpar[8];
  const float* a_dst2 = fpar[9];
  const float* b2     = fpar[10];
  const float* gw1    = fpar[11];
  const float* gb1    = fpar[12];
  const float* gw2    = fpar[13];
  const float* gb2    = fpar[14];
  (void)n_in;

  if (ws_size < needed){
    k_stamp<<<512, 256, 0, stream>>>((float*)d_out, out_size, 9999.0f);
    return;
  }

  int*   counts = multi;
  int*   cursor = multi;
  float* gate   = (float*)multi;
  float* hbuf   = (float*)d_out;
  float* zbuf   = (float*)d_out + (size_t)N * 128;

  k_detect<<<1, 256, 0, stream>>>((const u32*)d_in[4], ei, flags, bcnt);
  dim3 cgrid((maxn + 255) / 256, NPARAM);
  k_convert<<<cgrid, 256, 0, stream>>>(cp, fflag);

  int eb = (E + 255) / 256;
  int nb = (N + 1023) / 1024;
  int nb256 = (N + 255) / 256;

  k_checks<<<nb256, 256, 0, stream>>>(batch, x, iflag, N, V, errflg);

  if (nbuck <= MAXB){
    k_bhist<<<256, 256, 0, stream>>>(ei, iflag, bcnt, E, N, nbuck);
    k_bscan<<<1, 64, 0, stream>>>(bcnt, boff, gcur, rowptr, nbuck, N, E);
    k_bbin<<<(E + BINB - 1) / BINB, BTH, 0, stream>>>(ei, iflag, gcur, binned, E, N, nbuck, errflg);
    k_bcsr<<<nbuck, 256, 0, stream>>>(binned, boff, rowptr, csr, N, nbuck);
  } else {
    k_check_edges<<<eb, 256, 0, stream>>>(ei, iflag, E, N, errflg);
    hipMemsetAsync(counts, 0, (size_t)N * 4, stream);
    hipMemsetAsync(csr, 0xFF, (size_t)E * 4, stream);
    k_hist<<<eb, 256, 0, stream>>>(ei, iflag, counts, E, N);
    k_scanA<<<nb, 1024, 0, stream>>>(counts, rowptr, bsums, N);
    k_scanB<<<1, 128, 0, stream>>>(bsums, boffs, nb);
    k_scanC<<<nb, 1024, 0, stream>>>(rowptr, boffs, cursor, N, E);
    k_scatter<<<eb, 256, 0, stream>>>(ei, iflag, cursor, csr, E, N);
    k_check_rows<<<nb256, 256, 0, stream>>>(rowptr, cursor, N, errflg);
    k_check_csr<<<eb, 256, 0, stream>>>(csr, E, N, errflg);
  }

  // fused tables: vocab prep + both weight packs
  k_tables<<<V + 48, 128, 0, stream>>>(emb, ln_g, ln_b, W1, a_src1, a_dst1,
                                       W2, gw1, V, xwv, alsv, aldv, pb2, pbg);

  // layer 1: LDS vocab-table GAT -> bf16 h1
  const int gwb = min(2048, (N + 3) / 4);
  const size_t smem1 = (size_t)V * 272 + 4096;
  if (smem1 <= 64 * 1024){
    k_gatw1<<<gwb, 256, smem1, stream>>>(rowptr, csr, x, iflag, alsv, aldv, xwv, b1, N, V, h1b);
  } else {
    k_gatw1g<<<N, 64, 0, stream>>>(rowptr, csr, x, iflag, alsv, aldv, xwv, b1, V, h1b);
  }

  const int gblk = (N + 63) / 64;
  k_node2m<<<gblk, 256, 0, stream>>>(h1b, pb2, a_src2, a_dst2, N, xw, al_s, al_d);

  k_gatw2<<<N, 64, 0, stream>>>(rowptr, csr, al_s, al_d, xw, b2, 0, hbuf);

  k_gatem<<<gblk, 256, 0, stream>>>(hbuf, pbg, gb1, gw2, gb2, N, gate);
  k_graphsw<<<G, 512, 0, stream>>>(batch, iflag, gate, hbuf, zbuf, N);

  k_stamp_if<<<512, 256, 0, stream>>>(errflg, (float*)d_out, out_size);
}